// Round 1
// baseline (1598.919 us; speedup 1.0000x reference)
//
#include <hip/hip_runtime.h>
#include <hip/hip_bf16.h>

using bf16 = __hip_bfloat16;

constexpr int BB = 8;
constexpr int NN = 2048;
constexpr int CC = 256;
constexpr int HH = 4;
constexpr int NTOK = BB * NN;  // 16384
constexpr float TWO_PI = 6.283185307179586f;
constexpr float LOG2_1E4 = 13.287712379549449f;  // log2(10000)

__device__ __forceinline__ float gelu_f(float x) {
  return 0.5f * x * (1.0f + erff(x * 0.7071067811865475f));
}
__device__ __forceinline__ float us2f(unsigned short u) {
  return __uint_as_float(((unsigned)u) << 16);
}

// Per-token mean / rsqrt(var+eps) for T<=4 tokens resident in LDS buf[T][256].
// blockDim=256; wave w reduces token w. Biased variance (matches jnp.mean((x-mu)^2)).
template <int T>
__device__ __forceinline__ void stats_rows(const float (*buf)[CC], float* mu, float* rs, float eps) {
  __syncthreads();
  int w = threadIdx.x >> 6, l = threadIdx.x & 63;
  if (w < T) {
    float s = 0.f, s2 = 0.f;
#pragma unroll
    for (int j = 0; j < 4; ++j) { float v = buf[w][l + 64 * j]; s += v; s2 += v * v; }
#pragma unroll
    for (int o = 32; o; o >>= 1) { s += __shfl_down(s, o); s2 += __shfl_down(s2, o); }
    if (l == 0) {
      float m = s * (1.f / 256.f);
      float var = fmaxf(s2 * (1.f / 256.f) - m * m, 0.f);
      mu[w] = m; rs[w] = rsqrtf(var + eps);
    }
  }
  __syncthreads();
}

// ---------------- Stage 1: coord projection + rotary cos/sin table ----------
// x = gelu([sin(xp), cos(xp)]) @ W_coord ;  cs[tok] = {cos(f_i)}_{128}, {sin(f_i)}_{128}
__global__ void __launch_bounds__(256) k_coord(
    const float* __restrict__ pos, const float* __restrict__ Bf,
    const float* __restrict__ Wc, float* __restrict__ x, float* __restrict__ cs) {
  __shared__ float gf[4][512];
  int tid = threadIdx.x;
  long tok0 = (long)blockIdx.x * 4;
  float p[4];
#pragma unroll
  for (int t = 0; t < 4; ++t) p[t] = pos[tok0 + t];
  float bfc = Bf[tid];
#pragma unroll
  for (int t = 0; t < 4; ++t) {
    float xp = TWO_PI * (p[t] * 0.0625f) * bfc;
    float s, c; sincosf(xp, &s, &c);
    gf[t][tid] = gelu_f(s);
    gf[t][256 + tid] = gelu_f(c);
  }
  if (tid < 128) {
    float inv = exp2f(-((float)tid * (1.f / 128.f)) * LOG2_1E4);
#pragma unroll
    for (int t = 0; t < 4; ++t) {
      float fh = p[t] * 2048.f * inv;
      float s, c; sincosf(fh, &s, &c);
      cs[(tok0 + t) * 256 + tid] = c;
      cs[(tok0 + t) * 256 + 128 + tid] = s;
    }
  }
  __syncthreads();
  float acc[4] = {0.f, 0.f, 0.f, 0.f};
#pragma unroll 4
  for (int k = 0; k < 512; ++k) {
    float w = Wc[k * 256 + tid];
#pragma unroll
    for (int t = 0; t < 4; ++t) acc[t] = fmaf(gf[t][k], w, acc[t]);
  }
#pragma unroll
  for (int t = 0; t < 4; ++t) x[(tok0 + t) * 256 + tid] = acc[t];
}

// ---------------- Stage 2a: kv = z @ W_kv  (bf16 out, split-head layout) ----
__device__ __forceinline__ void store_kv(bf16* Kp, bf16* Vv, long tok, int c, float v) {
  int b = (int)(tok >> 11), n = (int)(tok & 2047);
  int d = c & 255;
  if (c < 1024) {
    int h = c >> 8;
    Kp[(((long)(b * 4 + h)) * 2048 + n) * 256 + d] = __float2bfloat16(v);
  } else {
    int h = (c - 1024) >> 8;
    Vv[(((long)(b * 4 + h)) * 2048 + n) * 256 + d] = __float2bfloat16(v);
  }
}

__global__ void __launch_bounds__(256) k_kv_gemm(
    const float* __restrict__ z, const float* __restrict__ Wkv,
    bf16* __restrict__ Kp, bf16* __restrict__ Vv) {
  __shared__ float zr[8][256];
  int tid = threadIdx.x;
  long tok0 = (long)blockIdx.y * 8;
#pragma unroll
  for (int t = 0; t < 8; ++t) zr[t][tid] = z[(tok0 + t) * 256 + tid];
  __syncthreads();
  int c0 = blockIdx.x * 512 + tid;
  float a0[8] = {}, a1[8] = {};
#pragma unroll 4
  for (int k = 0; k < 256; ++k) {
    float w0 = Wkv[(long)k * 2048 + c0];
    float w1 = Wkv[(long)k * 2048 + c0 + 256];
#pragma unroll
    for (int t = 0; t < 8; ++t) {
      float zv = zr[t][k];
      a0[t] = fmaf(zv, w0, a0[t]);
      a1[t] = fmaf(zv, w1, a1[t]);
    }
  }
#pragma unroll
  for (int t = 0; t < 8; ++t) {
    store_kv(Kp, Vv, tok0 + t, c0, a0[t]);
    store_kv(Kp, Vv, tok0 + t, c0 + 256, a1[t]);
  }
}

// ---------------- Stage 2b: instnorm + rotary on K (in place, bf16) ---------
// blockDim=256: wave = head. Lane l holds c = l + 64j, partner c^128 is j^2 (in-lane).
__global__ void __launch_bounds__(256) k_kv_norm(bf16* __restrict__ Kp, const float* __restrict__ cs) {
  long tok = blockIdx.x;
  int b = (int)(tok >> 11), n = (int)(tok & 2047);
  int h = threadIdx.x >> 6, l = threadIdx.x & 63;
  bf16* base = Kp + (((long)(b * 4 + h)) * 2048 + n) * 256;
  float v[4];
#pragma unroll
  for (int j = 0; j < 4; ++j) v[j] = __bfloat162float(base[l + 64 * j]);
  float s = v[0] + v[1] + v[2] + v[3];
  float s2 = v[0] * v[0] + v[1] * v[1] + v[2] * v[2] + v[3] * v[3];
#pragma unroll
  for (int o = 32; o; o >>= 1) { s += __shfl_down(s, o); s2 += __shfl_down(s2, o); }
  s = __shfl(s, 0); s2 = __shfl(s2, 0);
  float m = s * (1.f / 256.f);
  float rs = rsqrtf(fmaxf(s2 * (1.f / 256.f) - m * m, 0.f) + 1e-5f);
  float nn[4];
#pragma unroll
  for (int j = 0; j < 4; ++j) nn[j] = (v[j] - m) * rs;
  const float* csb = cs + (long)tok * 256;
#pragma unroll
  for (int j = 0; j < 4; ++j) {
    int c = l + 64 * j;
    int i = c & 127;
    float co = csb[i], si = csb[128 + i];
    float pr = nn[j ^ 2];
    float out = (c < 128) ? (v[j] * 0.f + nn[j] * co - pr * si) : (nn[j] * co + pr * si);
    base[c] = __float2bfloat16(out);
  }
}

// ---------------- A^T B GEMM: D[256x256] = sum_n A[n][:] outer B[n][:] ------
__global__ void __launch_bounds__(256) k_atb(
    const bf16* __restrict__ A0, long sA, int lda,
    const bf16* __restrict__ B0, long sB, int ldb,
    float* __restrict__ D0, long sD, float scale) {
  __shared__ float As[64][68], Bs[64][68];
  int mat = blockIdx.y;
  const bf16* A = A0 + (long)mat * sA;
  const bf16* Bm = B0 + (long)mat * sB;
  float* D = D0 + (long)mat * sD;
  int d0 = (blockIdx.x & 3) * 64, e0 = (blockIdx.x >> 2) * 64;
  int tid = threadIdx.x, tx = tid & 15, ty = tid >> 4;
  int lr = tid >> 2, lc = (tid & 3) * 16;
  float acc[4][4] = {};
  for (int n0 = 0; n0 < 2048; n0 += 64) {
    const ushort4* ap = (const ushort4*)((const ushort*)A + (long)(n0 + lr) * lda + d0 + lc);
    const ushort4* bp = (const ushort4*)((const ushort*)Bm + (long)(n0 + lr) * ldb + e0 + lc);
#pragma unroll
    for (int q = 0; q < 4; ++q) {
      ushort4 av = ap[q]; ushort4 bv = bp[q];
      *(float4*)&As[lr][lc + q * 4] = make_float4(us2f(av.x), us2f(av.y), us2f(av.z), us2f(av.w));
      *(float4*)&Bs[lr][lc + q * 4] = make_float4(us2f(bv.x), us2f(bv.y), us2f(bv.z), us2f(bv.w));
    }
    __syncthreads();
#pragma unroll 8
    for (int n = 0; n < 64; ++n) {
      float4 a4 = *(const float4*)&As[n][ty * 4];
      float4 b4 = *(const float4*)&Bs[n][tx * 4];
      float av[4] = {a4.x, a4.y, a4.z, a4.w};
      float bv[4] = {b4.x, b4.y, b4.z, b4.w};
#pragma unroll
      for (int i = 0; i < 4; ++i)
#pragma unroll
        for (int j = 0; j < 4; ++j) acc[i][j] = fmaf(av[i], bv[j], acc[i][j]);
    }
    __syncthreads();
  }
#pragma unroll
  for (int i = 0; i < 4; ++i) {
    float4 o = make_float4(acc[i][0] * scale, acc[i][1] * scale, acc[i][2] * scale, acc[i][3] * scale);
    *(float4*)&D[(long)(d0 + ty * 4 + i) * 256 + e0 + tx * 4] = o;
  }
}

// ---------------- Stage 2c: q-norm+rot, q@dots, merge, Wo_ca, residual ------
__global__ void __launch_bounds__(256) k_attn_out(
    float* __restrict__ x, const float* __restrict__ cs,
    const float* __restrict__ dots, const float* __restrict__ Wo,
    const float* __restrict__ bo) {
  __shared__ float xr[4][CC], qq[4][CC], a[4][1024];
  __shared__ float mu[4], rs[4];
  int tid = threadIdx.x;
  long tok0 = (long)blockIdx.x * 4;
  int b = (int)(tok0 >> 11);
#pragma unroll
  for (int t = 0; t < 4; ++t) xr[t][tid] = x[(tok0 + t) * 256 + tid];
  stats_rows<4>(xr, mu, rs, 1e-5f);
  int i = tid & 127;
#pragma unroll
  for (int t = 0; t < 4; ++t) {
    float co = cs[(tok0 + t) * 256 + i], si = cs[(tok0 + t) * 256 + 128 + i];
    float n0 = (xr[t][tid] - mu[t]) * rs[t];
    float n1 = (xr[t][tid ^ 128] - mu[t]) * rs[t];
    qq[t][tid] = (tid < 128) ? (n0 * co - n1 * si) : (n0 * co + n1 * si);
  }
  __syncthreads();
  for (int j = 0; j < 4; ++j) {
    float acc[4] = {};
    const float* dp = dots + ((long)(b * 4 + j)) * 65536 + tid;
#pragma unroll 4
    for (int d = 0; d < 256; ++d) {
      float dv = dp[(long)d * 256];
#pragma unroll
      for (int t = 0; t < 4; ++t) acc[t] = fmaf(qq[t][d], dv, acc[t]);
    }
#pragma unroll
    for (int t = 0; t < 4; ++t) a[t][j * 256 + tid] = acc[t];
  }
  __syncthreads();
  float acc2[4] = {};
#pragma unroll 4
  for (int k = 0; k < 1024; ++k) {
    float wv = Wo[(long)k * 256 + tid];
#pragma unroll
    for (int t = 0; t < 4; ++t) acc2[t] = fmaf(a[t][k], wv, acc2[t]);
  }
  float bv = bo[tid];
#pragma unroll
  for (int t = 0; t < 4; ++t) x[(tok0 + t) * 256 + tid] = acc2[t] + bv + xr[t][tid];
}

// ---------------- Stage 3: FFN + residual (in place) ------------------------
__global__ void __launch_bounds__(256) k_ffn(
    float* __restrict__ x, const float* __restrict__ W1, const float* __restrict__ b1,
    const float* __restrict__ W2, const float* __restrict__ b2) {
  __shared__ float xr[4][CC], t1[4][CC];
  int tid = threadIdx.x;
  long tok0 = (long)blockIdx.x * 4;
#pragma unroll
  for (int t = 0; t < 4; ++t) xr[t][tid] = x[(tok0 + t) * 256 + tid];
  __syncthreads();
  float acc[4] = {};
#pragma unroll 4
  for (int k = 0; k < 256; ++k) {
    float w = W1[k * 256 + tid];
#pragma unroll
    for (int t = 0; t < 4; ++t) acc[t] = fmaf(xr[t][k], w, acc[t]);
  }
  float b1v = b1[tid];
#pragma unroll
  for (int t = 0; t < 4; ++t) t1[t][tid] = gelu_f(acc[t] + b1v);
  __syncthreads();
  float acc2[4] = {};
#pragma unroll 4
  for (int k = 0; k < 256; ++k) {
    float w = W2[k * 256 + tid];
#pragma unroll
    for (int t = 0; t < 4; ++t) acc2[t] = fmaf(t1[t][k], w, acc2[t]);
  }
  float b2v = b2[tid];
#pragma unroll
  for (int t = 0; t < 4; ++t) x[(tok0 + t) * 256 + tid] = acc2[t] + b2v + xr[t][tid];
}

// ---------------- Stage 4: propagator (LN, concat pos/16, 3-layer MLP) ------
__global__ void __launch_bounds__(256) k_prop(
    const float* __restrict__ x, const float* __restrict__ pos,
    const float* __restrict__ lg, const float* __restrict__ lb,
    const float* __restrict__ P1, const float* __restrict__ P2,
    const float* __restrict__ P3, float* __restrict__ zp) {
  __shared__ float xr[4][CC], hr[4][260], t1[4][CC], t2[4][CC];
  __shared__ float mu[4], rs[4];
  int tid = threadIdx.x;
  long tok0 = (long)blockIdx.x * 4;
#pragma unroll
  for (int t = 0; t < 4; ++t) xr[t][tid] = x[(tok0 + t) * 256 + tid];
  stats_rows<4>(xr, mu, rs, 1e-5f);
  float gv = lg[tid], bv = lb[tid];
#pragma unroll
  for (int t = 0; t < 4; ++t) hr[t][tid] = (xr[t][tid] - mu[t]) * rs[t] * gv + bv;
  if (tid < 4) hr[tid][256] = pos[tok0 + tid] * 0.0625f;
  __syncthreads();
  float acc[4] = {};
#pragma unroll 4
  for (int k = 0; k < 257; ++k) {
    float w = P1[k * 256 + tid];
#pragma unroll
    for (int t = 0; t < 4; ++t) acc[t] = fmaf(hr[t][k], w, acc[t]);
  }
#pragma unroll
  for (int t = 0; t < 4; ++t) t1[t][tid] = gelu_f(acc[t]);
  __syncthreads();
  float acc2[4] = {};
#pragma unroll 4
  for (int k = 0; k < 256; ++k) {
    float w = P2[k * 256 + tid];
#pragma unroll
    for (int t = 0; t < 4; ++t) acc2[t] = fmaf(t1[t][k], w, acc2[t]);
  }
#pragma unroll
  for (int t = 0; t < 4; ++t) t2[t][tid] = gelu_f(acc2[t]);
  __syncthreads();
  float acc3[4] = {};
#pragma unroll 4
  for (int k = 0; k < 256; ++k) {
    float w = P3[k * 256 + tid];
#pragma unroll
    for (int t = 0; t < 4; ++t) acc3[t] = fmaf(t2[t][k], w, acc3[t]);
  }
#pragma unroll
  for (int t = 0; t < 4; ++t) zp[(tok0 + t) * 256 + tid] = acc3[t] + xr[t][tid];
}

// ---------------- Stage 5a: qkv = zp @ W_qkv (bf16) -------------------------
__global__ void __launch_bounds__(256) k_qkv_gemm(
    const float* __restrict__ zp, const float* __restrict__ Wq, bf16* __restrict__ qkv) {
  __shared__ float zr[8][256];
  int tid = threadIdx.x;
  long tok0 = (long)blockIdx.x * 8;
#pragma unroll
  for (int t = 0; t < 8; ++t) zr[t][tid] = zp[(tok0 + t) * 256 + tid];
  __syncthreads();
  float a0[8] = {}, a1[8] = {}, a2[8] = {};
#pragma unroll 4
  for (int k = 0; k < 256; ++k) {
    float w0 = Wq[(long)k * 768 + tid];
    float w1 = Wq[(long)k * 768 + 256 + tid];
    float w2 = Wq[(long)k * 768 + 512 + tid];
#pragma unroll
    for (int t = 0; t < 8; ++t) {
      float zv = zr[t][k];
      a0[t] = fmaf(zv, w0, a0[t]);
      a1[t] = fmaf(zv, w1, a1[t]);
      a2[t] = fmaf(zv, w2, a2[t]);
    }
  }
#pragma unroll
  for (int t = 0; t < 8; ++t) {
    long o = (tok0 + t) * 768;
    qkv[o + tid] = __float2bfloat16(a0[t]);
    qkv[o + 256 + tid] = __float2bfloat16(a1[t]);
    qkv[o + 512 + tid] = __float2bfloat16(a2[t]);
  }
}

// ---------------- Stage 5b: instnorm + rotary on q2,k2 (in place) -----------
__global__ void __launch_bounds__(128) k_qkv_norm(bf16* __restrict__ qkv, const float* __restrict__ cs) {
  long tok = blockIdx.x;
  int part = threadIdx.x >> 6, l = threadIdx.x & 63;
  bf16* base = qkv + tok * 768 + part * 256;
  float v[4];
#pragma unroll
  for (int j = 0; j < 4; ++j) v[j] = __bfloat162float(base[l + 64 * j]);
  float s = v[0] + v[1] + v[2] + v[3];
  float s2 = v[0] * v[0] + v[1] * v[1] + v[2] * v[2] + v[3] * v[3];
#pragma unroll
  for (int o = 32; o; o >>= 1) { s += __shfl_down(s, o); s2 += __shfl_down(s2, o); }
  s = __shfl(s, 0); s2 = __shfl(s2, 0);
  float m = s * (1.f / 256.f);
  float rs = rsqrtf(fmaxf(s2 * (1.f / 256.f) - m * m, 0.f) + 1e-5f);
  float nn[4];
#pragma unroll
  for (int j = 0; j < 4; ++j) nn[j] = (v[j] - m) * rs;
  const float* csb = cs + (long)tok * 256;
#pragma unroll
  for (int j = 0; j < 4; ++j) {
    int c = l + 64 * j;
    int i = c & 127;
    float co = csb[i], si = csb[128 + i];
    float pr = nn[j ^ 2];
    float out = (c < 128) ? (nn[j] * co - pr * si) : (nn[j] * co + pr * si);
    base[c] = __float2bfloat16(out);
  }
}

// ---------------- Stage 6: decode attention out + LN + MLP -> u -------------
__global__ void __launch_bounds__(256) k_decode(
    const float* __restrict__ zp, const bf16* __restrict__ qkv,
    const float* __restrict__ dots2, const float* __restrict__ Wo,
    const float* __restrict__ bo, const float* __restrict__ lg,
    const float* __restrict__ lb, const float* __restrict__ D1,
    const float* __restrict__ D2, const float* __restrict__ D3,
    const float* __restrict__ b3, float* __restrict__ uout) {
  __shared__ float zpr[4][CC], q2s[4][CC], att[4][CC], zd[4][CC], h2[4][CC], g1[4][CC], g2[4][128];
  __shared__ float mu[4], rs[4];
  int tid = threadIdx.x;
  long tok0 = (long)blockIdx.x * 4;
  int b = (int)(tok0 >> 11);
#pragma unroll
  for (int t = 0; t < 4; ++t) {
    zpr[t][tid] = zp[(tok0 + t) * 256 + tid];
    q2s[t][tid] = __bfloat162float(qkv[(tok0 + t) * 768 + tid]);
  }
  __syncthreads();
  float acc[4] = {};
  const float* dp = dots2 + (long)b * 65536 + tid;
#pragma unroll 4
  for (int d = 0; d < 256; ++d) {
    float dv = dp[(long)d * 256];
#pragma unroll
    for (int t = 0; t < 4; ++t) acc[t] = fmaf(q2s[t][d], dv, acc[t]);
  }
#pragma unroll
  for (int t = 0; t < 4; ++t) att[t][tid] = acc[t];
  __syncthreads();
  float acc2[4] = {};
#pragma unroll 4
  for (int k = 0; k < 256; ++k) {
    float w = Wo[k * 256 + tid];
#pragma unroll
    for (int t = 0; t < 4; ++t) acc2[t] = fmaf(att[t][k], w, acc2[t]);
  }
  float bv = bo[tid];
#pragma unroll
  for (int t = 0; t < 4; ++t) zd[t][tid] = acc2[t] + bv + zpr[t][tid];
  stats_rows<4>(zd, mu, rs, 1e-5f);
  float gv = lg[tid], lbv = lb[tid];
#pragma unroll
  for (int t = 0; t < 4; ++t) h2[t][tid] = (zd[t][tid] - mu[t]) * rs[t] * gv + lbv;
  __syncthreads();
  float acc3[4] = {};
#pragma unroll 4
  for (int k = 0; k < 256; ++k) {
    float w = D1[k * 256 + tid];
#pragma unroll
    for (int t = 0; t < 4; ++t) acc3[t] = fmaf(h2[t][k], w, acc3[t]);
  }
#pragma unroll
  for (int t = 0; t < 4; ++t) g1[t][tid] = gelu_f(acc3[t]);
  __syncthreads();
  if (tid < 128) {
    float acc4[4] = {};
#pragma unroll 4
    for (int k = 0; k < 256; ++k) {
      float w = D2[k * 128 + tid];
#pragma unroll
      for (int t = 0; t < 4; ++t) acc4[t] = fmaf(g1[t][k], w, acc4[t]);
    }
#pragma unroll
    for (int t = 0; t < 4; ++t) g2[t][tid] = gelu_f(acc4[t]);
  }
  __syncthreads();
  int wv = tid >> 6, l = tid & 63;
  float sv = g2[wv][l] * D3[l] + g2[wv][l + 64] * D3[l + 64];
#pragma unroll
  for (int o = 32; o; o >>= 1) sv += __shfl_down(sv, o);
  if (l == 0) uout[(long)b * 2048 + (int)((tok0 + wv) & 2047)] = sv + b3[0];
}

extern "C" void kernel_launch(void* const* d_in, const int* in_sizes, int n_in,
                              void* d_out, int out_size, void* d_ws, size_t ws_size,
                              hipStream_t stream) {
  const float* z    = (const float*)d_in[0];
  const float* pos  = (const float*)d_in[1];
  const float* Bf   = (const float*)d_in[2];
  const float* Wc   = (const float*)d_in[3];
  const float* Wkv  = (const float*)d_in[4];
  const float* Woca = (const float*)d_in[5];
  const float* boca = (const float*)d_in[6];
  const float* Wf1  = (const float*)d_in[7];
  const float* bf1  = (const float*)d_in[8];
  const float* Wf2  = (const float*)d_in[9];
  const float* bf2  = (const float*)d_in[10];
  const float* lng  = (const float*)d_in[11];
  const float* lnb  = (const float*)d_in[12];
  const float* P1   = (const float*)d_in[13];
  const float* P2   = (const float*)d_in[14];
  const float* P3   = (const float*)d_in[15];
  const float* Wqkv = (const float*)d_in[16];
  const float* Woda = (const float*)d_in[17];
  const float* boda = (const float*)d_in[18];
  const float* ln2g = (const float*)d_in[19];
  const float* ln2b = (const float*)d_in[20];
  const float* D1   = (const float*)d_in[21];
  const float* D2   = (const float*)d_in[22];
  const float* D3   = (const float*)d_in[23];
  const float* b3   = (const float*)d_in[24];

  float* u  = (float*)d_out;          // [B,1,N] = 16384 floats
  float* zp = (float*)d_out + NTOK;   // [B,N,C]

  // Workspace layout (bytes):
  //  cs   @ 0          : 16,777,216  (f32 rotary cos/sin per token)
  //  x    @ 16,777,216 : 16,777,216  (f32)
  //  Kp   @ 33,554,432 : 33,554,432  (bf16 [B,H,N,C]) -- later reused as qkv [NT,768] bf16
  //  Vv   @ 67,108,864 : 33,554,432  (bf16 [B,H,N,C])
  //  dots @100,663,296 :  8,388,608  (f32 [B,H,C,C])  -- later reused as dots2 [B,C,C]
  // total 109,051,904 B
  char* ws = (char*)d_ws;
  float* cs   = (float*)(ws);
  float* x    = (float*)(ws + 16777216L);
  bf16*  Kp   = (bf16*) (ws + 33554432L);
  bf16*  Vv   = (bf16*) (ws + 67108864L);
  float* dots = (float*)(ws + 100663296L);
  bf16*  qkv  = Kp;     // reuse after cross-attn dots are computed
  float* dots2 = dots;  // reuse after k_attn_out consumed dots

  k_coord<<<NTOK / 4, 256, 0, stream>>>(pos, Bf, Wc, x, cs);
  k_kv_gemm<<<dim3(4, NTOK / 8), 256, 0, stream>>>(z, Wkv, Kp, Vv);
  k_kv_norm<<<NTOK, 256, 0, stream>>>(Kp, cs);
  k_atb<<<dim3(16, BB * HH), 256, 0, stream>>>(Kp, (long)NN * CC, CC, Vv, (long)NN * CC, CC,
                                               dots, (long)CC * CC, 1.f / 2048.f);
  k_attn_out<<<NTOK / 4, 256, 0, stream>>>(x, cs, dots, Woca, boca);
  k_ffn<<<NTOK / 4, 256, 0, stream>>>(x, Wf1, bf1, Wf2, bf2);
  k_prop<<<NTOK / 4, 256, 0, stream>>>(x, pos, lng, lnb, P1, P2, P3, zp);
  k_qkv_gemm<<<NTOK / 8, 256, 0, stream>>>(zp, Wqkv, qkv);
  k_qkv_norm<<<NTOK, 128, 0, stream>>>(qkv, cs);
  k_atb<<<dim3(16, BB), 256, 0, stream>>>(qkv + 256, (long)NN * 768, 768, qkv + 512, (long)NN * 768, 768,
                                          dots2, (long)CC * CC, 1.f / 2048.f);
  k_decode<<<NTOK / 4, 256, 0, stream>>>(zp, qkv, dots2, Woda, boda, ln2g, ln2b, D1, D2, D3, b3, u);
}

// Round 2
// 567.974 us; speedup vs baseline: 2.8151x; 2.8151x over previous
//
#include <hip/hip_runtime.h>
#include <hip/hip_bf16.h>

using bf16 = __hip_bfloat16;
typedef __attribute__((ext_vector_type(8))) short short8;
typedef __attribute__((ext_vector_type(4))) float f32x4;

constexpr int BB = 8;
constexpr int NN = 2048;
constexpr int CC = 256;
constexpr int NTOK = BB * NN;  // 16384
constexpr float TWO_PI = 6.283185307179586f;
constexpr float LOG2_1E4 = 13.287712379549449f;

__device__ __forceinline__ float gelu_f(float x) {
  return 0.5f * x * (1.0f + erff(x * 0.7071067811865475f));
}

template <int T>
__device__ __forceinline__ void stats_rows(const float (*buf)[CC], float* mu, float* rs, float eps) {
  __syncthreads();
  int w = threadIdx.x >> 6, l = threadIdx.x & 63;
  if (w < T) {
    float s = 0.f, s2 = 0.f;
#pragma unroll
    for (int j = 0; j < 4; ++j) { float v = buf[w][l + 64 * j]; s += v; s2 += v * v; }
#pragma unroll
    for (int o = 32; o; o >>= 1) { s += __shfl_down(s, o); s2 += __shfl_down(s2, o); }
    if (l == 0) {
      float m = s * (1.f / 256.f);
      float var = fmaxf(s2 * (1.f / 256.f) - m * m, 0.f);
      mu[w] = m; rs[w] = rsqrtf(var + eps);
    }
  }
  __syncthreads();
}

// ======================= MFMA GEMM (A[M,K] bf16, Bt[N,K] bf16) ==============
// BM=128, BN=64, BK=64, 256 threads (4 waves, 2x2), each wave 64x32 out.
enum { E_F32 = 0, E_BF16, E_BIAS_RES_BOTH, E_BIAS_GELU, E_BIAS_RES_F32,
       E_RANK1_GELU, E_GELU, E_RES_BOTH };

template <int K, int EPI>
__global__ void __launch_bounds__(256) k_gemm(
    const bf16* __restrict__ A, int lda, const bf16* __restrict__ Bt,
    long bstride, long zstride, int nOffZ,
    const float* __restrict__ bias, const float* __restrict__ res,
    const float* __restrict__ rank1, const float* __restrict__ pvec,
    float* __restrict__ outF, bf16* __restrict__ outB, int ldo) {
  __shared__ bf16 As[128 * 64];
  __shared__ bf16 Bs[64 * 64];
  const int tid = threadIdx.x;
  const int w = tid >> 6, l = tid & 63;
  const int m0 = blockIdx.y * 128, n0 = blockIdx.x * 64;
  const int bidx = m0 >> 11;
  const bf16* Ap = A + (long)m0 * lda;
  const bf16* Bp = Bt + (long)bidx * bstride + (long)blockIdx.z * zstride + (long)n0 * K;
  const int srow = l >> 3;        // 0..7
  const int scol = (l & 7) * 8;   // element col of 16B chunk
  const int wm = w >> 1, wn = w & 1;
  f32x4 acc[4][2] = {};

  for (int kt = 0; kt < K; kt += 64) {
#pragma unroll
    for (int i = 0; i < 4; ++i) {
      int r = (w * 4 + i) * 8 + srow;
      __builtin_amdgcn_global_load_lds(
          (const __attribute__((address_space(1))) void*)(Ap + (long)r * lda + kt + scol),
          (__attribute__((address_space(3))) void*)(&As[(w * 4 + i) * 512 + l * 8]), 16, 0, 0);
    }
#pragma unroll
    for (int i = 0; i < 2; ++i) {
      int r = (w * 2 + i) * 8 + srow;
      __builtin_amdgcn_global_load_lds(
          (const __attribute__((address_space(1))) void*)(Bp + (long)r * K + kt + scol),
          (__attribute__((address_space(3))) void*)(&Bs[(w * 2 + i) * 512 + l * 8]), 16, 0, 0);
    }
    __syncthreads();
    short8 bfr[2][2];
#pragma unroll
    for (int ni = 0; ni < 2; ++ni)
#pragma unroll
      for (int ks = 0; ks < 2; ++ks)
        bfr[ni][ks] = *(const short8*)&Bs[(wn * 32 + ni * 16 + (l & 15)) * 64 + ks * 32 + (l >> 4) * 8];
#pragma unroll
    for (int mi = 0; mi < 4; ++mi) {
#pragma unroll
      for (int ks = 0; ks < 2; ++ks) {
        short8 afr = *(const short8*)&As[(wm * 64 + mi * 16 + (l & 15)) * 64 + ks * 32 + (l >> 4) * 8];
#pragma unroll
        for (int ni = 0; ni < 2; ++ni)
          acc[mi][ni] = __builtin_amdgcn_mfma_f32_16x16x32_bf16(afr, bfr[ni][ks], acc[mi][ni], 0, 0, 0);
      }
    }
    __syncthreads();
  }
  const int zoff = blockIdx.z * nOffZ;
#pragma unroll
  for (int mi = 0; mi < 4; ++mi) {
#pragma unroll
    for (int ni = 0; ni < 2; ++ni) {
      const int bcol = n0 + wn * 32 + ni * 16 + (l & 15);
      const int ocol = bcol + zoff;
#pragma unroll
      for (int r = 0; r < 4; ++r) {
        const int row = m0 + wm * 64 + mi * 16 + (l >> 4) * 4 + r;
        float v = acc[mi][ni][r];
        const long oidx = (long)row * ldo + ocol;
        if constexpr (EPI == E_F32) { outF[oidx] = v; }
        else if constexpr (EPI == E_BF16) { outB[oidx] = __float2bfloat16(v); }
        else if constexpr (EPI == E_BIAS_RES_BOTH) {
          v += bias[bcol] + res[oidx]; outF[oidx] = v; outB[oidx] = __float2bfloat16(v);
        } else if constexpr (EPI == E_BIAS_GELU) {
          v = gelu_f(v + bias[bcol]); outB[oidx] = __float2bfloat16(v);
        } else if constexpr (EPI == E_BIAS_RES_F32) {
          v += bias[bcol] + res[oidx]; outF[oidx] = v;
        } else if constexpr (EPI == E_RANK1_GELU) {
          v = gelu_f(v + pvec[row] * rank1[bcol]); outB[oidx] = __float2bfloat16(v);
        } else if constexpr (EPI == E_GELU) {
          v = gelu_f(v); outB[oidx] = __float2bfloat16(v);
        } else {  // E_RES_BOTH
          v += res[oidx]; outF[oidx] = v; outB[oidx] = __float2bfloat16(v);
        }
      }
    }
  }
}

// ======================= A^T B (fp32 VALU) -> bf16 D[256x256] ===============
__device__ __forceinline__ float us2f(unsigned short u) {
  return __uint_as_float(((unsigned)u) << 16);
}
__global__ void __launch_bounds__(256) k_atb(
    const bf16* __restrict__ A0, const bf16* __restrict__ B0,
    int ld, long bstride, int hshift, bf16* __restrict__ D0, float scale) {
  __shared__ float As[64][68], Bs[64][68];
  int mat = blockIdx.y;
  int b = mat >> hshift, h = mat & ((1 << hshift) - 1);
  const bf16* A = A0 + (long)b * bstride + h * 256;
  const bf16* Bm = B0 + (long)b * bstride + h * 256;
  bf16* D = D0 + (long)mat * 65536;
  int d0 = (blockIdx.x & 3) * 64, e0 = (blockIdx.x >> 2) * 64;
  int tid = threadIdx.x, tx = tid & 15, ty = tid >> 4;
  int lr = tid >> 2, lc = (tid & 3) * 16;
  float acc[4][4] = {};
  for (int n0 = 0; n0 < 2048; n0 += 64) {
    const ushort4* ap = (const ushort4*)((const ushort*)A + (long)(n0 + lr) * ld + d0 + lc);
    const ushort4* bp = (const ushort4*)((const ushort*)Bm + (long)(n0 + lr) * ld + e0 + lc);
#pragma unroll
    for (int q = 0; q < 4; ++q) {
      ushort4 av = ap[q]; ushort4 bv = bp[q];
      *(float4*)&As[lr][lc + q * 4] = make_float4(us2f(av.x), us2f(av.y), us2f(av.z), us2f(av.w));
      *(float4*)&Bs[lr][lc + q * 4] = make_float4(us2f(bv.x), us2f(bv.y), us2f(bv.z), us2f(bv.w));
    }
    __syncthreads();
#pragma unroll 8
    for (int n = 0; n < 64; ++n) {
      float4 a4 = *(const float4*)&As[n][ty * 4];
      float4 b4 = *(const float4*)&Bs[n][tx * 4];
      float av[4] = {a4.x, a4.y, a4.z, a4.w};
      float bv[4] = {b4.x, b4.y, b4.z, b4.w};
#pragma unroll
      for (int i = 0; i < 4; ++i)
#pragma unroll
        for (int j = 0; j < 4; ++j) acc[i][j] = fmaf(av[i], bv[j], acc[i][j]);
    }
    __syncthreads();
  }
#pragma unroll
  for (int i = 0; i < 4; ++i)
#pragma unroll
    for (int j = 0; j < 4; ++j)
      D[(long)(d0 + ty * 4 + i) * 256 + e0 + tx * 4 + j] = __float2bfloat16(acc[i][j] * scale);
}

// ======================= small kernels ======================================
__global__ void __launch_bounds__(256) k_pre(
    const float* __restrict__ pos, const float* __restrict__ Bf,
    bf16* __restrict__ gf, bf16* __restrict__ cs, float* __restrict__ pvec) {
  int tid = threadIdx.x;
  long tok0 = (long)blockIdx.x * 4;
  float p[4];
#pragma unroll
  for (int t = 0; t < 4; ++t) p[t] = pos[tok0 + t];
  if (tid < 4) pvec[tok0 + tid] = pos[tok0 + tid] * 0.0625f;
  float bfc = Bf[tid];
#pragma unroll
  for (int t = 0; t < 4; ++t) {
    float xp = TWO_PI * (p[t] * 0.0625f) * bfc;
    float s, c; sincosf(xp, &s, &c);
    gf[(tok0 + t) * 512 + tid] = __float2bfloat16(gelu_f(s));
    gf[(tok0 + t) * 512 + 256 + tid] = __float2bfloat16(gelu_f(c));
  }
  if (tid < 128) {
    float inv = exp2f(-((float)tid * (1.f / 128.f)) * LOG2_1E4);
#pragma unroll
    for (int t = 0; t < 4; ++t) {
      float fh = p[t] * 2048.f * inv;
      float s, c; sincosf(fh, &s, &c);
      cs[(tok0 + t) * 256 + tid] = __float2bfloat16(c);
      cs[(tok0 + t) * 256 + 128 + tid] = __float2bfloat16(s);
    }
  }
}

__global__ void k_f2b(const float* __restrict__ s, bf16* __restrict__ d) {
  long i = (long)blockIdx.x * 256 + threadIdx.x;
  d[i] = __float2bfloat16(s[i]);
}

__global__ void __launch_bounds__(256) k_transpose(
    const float* __restrict__ src, bf16* __restrict__ dst, int K, int N) {
  int idx = blockIdx.x * 256 + threadIdx.x;
  if (idx < K * N) {
    int n = idx / K, k = idx - n * K;
    dst[idx] = __float2bfloat16(src[(long)k * N + n]);
  }
}

__global__ void k_copylast(const float* __restrict__ P1, float* __restrict__ P1L) {
  P1L[threadIdx.x] = P1[65536 + threadIdx.x];
}

// instnorm + rotary on K-part of kv [M,2048] (cols 0..1023, per head), in place
__global__ void __launch_bounds__(256) k_kv_norm(bf16* __restrict__ kv, const bf16* __restrict__ cs) {
  long tok = blockIdx.x;
  int h = threadIdx.x >> 6, l = threadIdx.x & 63;
  bf16* base = kv + tok * 2048 + h * 256;
  float v[4];
#pragma unroll
  for (int j = 0; j < 4; ++j) v[j] = __bfloat162float(base[l + 64 * j]);
  float s = v[0] + v[1] + v[2] + v[3];
  float s2 = v[0] * v[0] + v[1] * v[1] + v[2] * v[2] + v[3] * v[3];
#pragma unroll
  for (int o = 32; o; o >>= 1) { s += __shfl_down(s, o); s2 += __shfl_down(s2, o); }
  s = __shfl(s, 0); s2 = __shfl(s2, 0);
  float m = s * (1.f / 256.f);
  float rs = rsqrtf(fmaxf(s2 * (1.f / 256.f) - m * m, 0.f) + 1e-5f);
  float nn[4];
#pragma unroll
  for (int j = 0; j < 4; ++j) nn[j] = (v[j] - m) * rs;
  const bf16* csb = cs + tok * 256;
#pragma unroll
  for (int j = 0; j < 4; ++j) {
    int c = l + 64 * j;
    int i = c & 127;
    float co = __bfloat162float(csb[i]), si = __bfloat162float(csb[128 + i]);
    float pr = nn[j ^ 2];
    float out = (c < 128) ? (nn[j] * co - pr * si) : (nn[j] * co + pr * si);
    base[c] = __float2bfloat16(out);
  }
}

// instnorm + rotary on q2,k2 of qkv [M,768] (parts 0,1), in place
__global__ void __launch_bounds__(128) k_qkv_norm(bf16* __restrict__ qkv, const bf16* __restrict__ cs) {
  long tok = blockIdx.x;
  int part = threadIdx.x >> 6, l = threadIdx.x & 63;
  bf16* base = qkv + tok * 768 + part * 256;
  float v[4];
#pragma unroll
  for (int j = 0; j < 4; ++j) v[j] = __bfloat162float(base[l + 64 * j]);
  float s = v[0] + v[1] + v[2] + v[3];
  float s2 = v[0] * v[0] + v[1] * v[1] + v[2] * v[2] + v[3] * v[3];
#pragma unroll
  for (int o = 32; o; o >>= 1) { s += __shfl_down(s, o); s2 += __shfl_down(s2, o); }
  s = __shfl(s, 0); s2 = __shfl(s2, 0);
  float m = s * (1.f / 256.f);
  float rs = rsqrtf(fmaxf(s2 * (1.f / 256.f) - m * m, 0.f) + 1e-5f);
  float nn[4];
#pragma unroll
  for (int j = 0; j < 4; ++j) nn[j] = (v[j] - m) * rs;
  const bf16* csb = cs + tok * 256;
#pragma unroll
  for (int j = 0; j < 4; ++j) {
    int c = l + 64 * j;
    int i = c & 127;
    float co = __bfloat162float(csb[i]), si = __bfloat162float(csb[128 + i]);
    float pr = nn[j ^ 2];
    float out = (c < 128) ? (nn[j] * co - pr * si) : (nn[j] * co + pr * si);
    base[c] = __float2bfloat16(out);
  }
}

// instnorm + rotary on x (f32) -> qrot bf16
__global__ void __launch_bounds__(256) k_qrot(
    const float* __restrict__ x, const bf16* __restrict__ cs, bf16* __restrict__ qrot) {
  __shared__ float xr[4][CC];
  __shared__ float mu[4], rs[4];
  int tid = threadIdx.x;
  long tok0 = (long)blockIdx.x * 4;
#pragma unroll
  for (int t = 0; t < 4; ++t) xr[t][tid] = x[(tok0 + t) * 256 + tid];
  stats_rows<4>(xr, mu, rs, 1e-5f);
  int i = tid & 127;
#pragma unroll
  for (int t = 0; t < 4; ++t) {
    float co = __bfloat162float(cs[(tok0 + t) * 256 + i]);
    float si = __bfloat162float(cs[(tok0 + t) * 256 + 128 + i]);
    float n0 = (xr[t][tid] - mu[t]) * rs[t];
    float n1 = (xr[t][tid ^ 128] - mu[t]) * rs[t];
    float o = (tid < 128) ? (n0 * co - n1 * si) : (n0 * co + n1 * si);
    qrot[(tok0 + t) * 256 + tid] = __float2bfloat16(o);
  }
}

// LayerNorm (gamma, beta) f32 in -> bf16 out
__global__ void __launch_bounds__(256) k_ln(
    const float* __restrict__ xin, const float* __restrict__ g,
    const float* __restrict__ b, bf16* __restrict__ hout) {
  __shared__ float xr[4][CC];
  __shared__ float mu[4], rs[4];
  int tid = threadIdx.x;
  long tok0 = (long)blockIdx.x * 4;
#pragma unroll
  for (int t = 0; t < 4; ++t) xr[t][tid] = xin[(tok0 + t) * 256 + tid];
  stats_rows<4>(xr, mu, rs, 1e-5f);
  float gv = g[tid], bv = b[tid];
#pragma unroll
  for (int t = 0; t < 4; ++t)
    hout[(tok0 + t) * 256 + tid] = __float2bfloat16((xr[t][tid] - mu[t]) * rs[t] * gv + bv);
}

__global__ void __launch_bounds__(256) k_final(
    const bf16* __restrict__ g2, const float* __restrict__ D3,
    const float* __restrict__ b3, float* __restrict__ u) {
  int w = threadIdx.x >> 6, l = threadIdx.x & 63;
  long tok = (long)blockIdx.x * 4 + w;
  float s = __bfloat162float(g2[tok * 128 + l]) * D3[l]
          + __bfloat162float(g2[tok * 128 + 64 + l]) * D3[64 + l];
#pragma unroll
  for (int o = 32; o; o >>= 1) s += __shfl_down(s, o);
  if (l == 0) u[tok] = s + b3[0];
}

// ======================= launcher ===========================================
extern "C" void kernel_launch(void* const* d_in, const int* in_sizes, int n_in,
                              void* d_out, int out_size, void* d_ws, size_t ws_size,
                              hipStream_t stream) {
  const float* z    = (const float*)d_in[0];
  const float* pos  = (const float*)d_in[1];
  const float* Bf   = (const float*)d_in[2];
  const float* Wc   = (const float*)d_in[3];
  const float* Wkv  = (const float*)d_in[4];
  const float* Woca = (const float*)d_in[5];
  const float* boca = (const float*)d_in[6];
  const float* Wf1  = (const float*)d_in[7];
  const float* bf1  = (const float*)d_in[8];
  const float* Wf2  = (const float*)d_in[9];
  const float* bf2  = (const float*)d_in[10];
  const float* lng  = (const float*)d_in[11];
  const float* lnb  = (const float*)d_in[12];
  const float* P1   = (const float*)d_in[13];
  const float* P2   = (const float*)d_in[14];
  const float* P3   = (const float*)d_in[15];
  const float* Wqkv = (const float*)d_in[16];
  const float* Woda = (const float*)d_in[17];
  const float* boda = (const float*)d_in[18];
  const float* ln2g = (const float*)d_in[19];
  const float* ln2b = (const float*)d_in[20];
  const float* D1   = (const float*)d_in[21];
  const float* D2   = (const float*)d_in[22];
  const float* D3   = (const float*)d_in[23];
  const float* b3   = (const float*)d_in[24];

  float* u  = (float*)d_out;
  float* zp = (float*)d_out + NTOK;

  // ---- workspace layout (104 MB total, same as round 1) ----
  char* ws = (char*)d_ws;
  bf16*  cs   = (bf16*)(ws);                      // 8 MB
  float* pvec = (float*)(ws + 8388608L);          // 64 KB
  // weight arena (bf16 transposed weights, [N][K])
  long wo = 8454144L;
  bf16* WcT   = (bf16*)(ws + wo);                 // [256][512]
  bf16* WkvT  = (bf16*)(ws + wo + 262144);        // [2048][256]
  bf16* WocaT = (bf16*)(ws + wo + 1310720);       // [256][1024]
  bf16* Wf1T  = (bf16*)(ws + wo + 1835008);
  bf16* Wf2T  = (bf16*)(ws + wo + 1966080);
  bf16* P1T   = (bf16*)(ws + wo + 2097152);
  bf16* P2T   = (bf16*)(ws + wo + 2228224);
  bf16* P3T   = (bf16*)(ws + wo + 2359296);
  bf16* WqkvT = (bf16*)(ws + wo + 2490368);       // [768][256]
  bf16* WodaT = (bf16*)(ws + wo + 2883584);
  bf16* D1T   = (bf16*)(ws + wo + 3014656);
  bf16* D2T   = (bf16*)(ws + wo + 3145728);       // [128][256]
  float* P1L  = (float*)(ws + wo + 3211264);      // [256] f32
  float* x    = (float*)(ws + 12582912L);         // 16 MB (x, later x3)
  float* x3   = x;
  bf16*  zb   = (bf16*)(ws + 29360128L);          // 8 MB slot: zb -> qrot -> g2
  bf16*  qrot = zb;
  bf16*  g2   = zb;
  char*  BA   = ws + 37748736L;                   // 64 MB arena
  bf16*  gf   = (bf16*)BA;                        // 16 MB [M,512]
  bf16*  kv   = (bf16*)BA;                        // 64 MB [M,2048]
  bf16*  merged = (bf16*)BA;                      // 32 MB [M,1024]
  float* x2   = (float*)(BA + 33554432L);         // 16 MB
  bf16*  x2b  = (bf16*)(BA + 50331648L);          // 8 MB
  bf16*  t1   = (bf16*)(BA + 58720256L);          // 8 MB
  bf16*  h    = (bf16*)BA;                        // 8 MB
  bf16*  p1o  = (bf16*)(BA + 8388608L);
  bf16*  p2o  = (bf16*)(BA + 16777216L);
  bf16*  zpb  = (bf16*)(BA + 25165824L);
  bf16*  qkvb = (bf16*)(BA + 33554432L);          // 24 MB [M,768]
  bf16*  att  = (bf16*)(BA + 58720256L);          // 8 MB
  float* zd   = (float*)BA;                       // 16 MB
  bf16*  h2   = (bf16*)(BA + 16777216L);          // 8 MB
  bf16*  g1   = (bf16*)(BA + 25165824L);          // 8 MB
  bf16*  dotsT  = (bf16*)(ws + 104857600L);       // 4 MB (32 x [256][256])
  bf16*  dots2T = dotsT;                          // 1 MB (8 x [256][256])

  auto TR = [&](const float* s, bf16* d, int K_, int N_) {
    k_transpose<<<(K_ * N_ + 255) / 256, 256, 0, stream>>>(s, d, K_, N_);
  };
  TR(Wc, WcT, 512, 256);     TR(Wkv, WkvT, 256, 2048);
  TR(Woca, WocaT, 1024, 256); TR(Wf1, Wf1T, 256, 256);
  TR(Wf2, Wf2T, 256, 256);   TR(P1, P1T, 256, 256);
  TR(P2, P2T, 256, 256);     TR(P3, P3T, 256, 256);
  TR(Wqkv, WqkvT, 256, 768); TR(Woda, WodaT, 256, 256);
  TR(D1, D1T, 256, 256);     TR(D2, D2T, 256, 128);
  k_copylast<<<1, 256, 0, stream>>>(P1, P1L);

  k_pre<<<NTOK / 4, 256, 0, stream>>>(pos, Bf, gf, cs, pvec);
  // x = gf @ WcT
  k_gemm<512, E_F32><<<dim3(4, 128, 1), 256, 0, stream>>>(
      gf, 512, WcT, 0, 0, 0, nullptr, nullptr, nullptr, nullptr, x, nullptr, 256);
  k_f2b<<<NTOK * 256 / 256, 256, 0, stream>>>(z, zb);
  // kv = zb @ WkvT
  k_gemm<256, E_BF16><<<dim3(32, 128, 1), 256, 0, stream>>>(
      zb, 256, WkvT, 0, 0, 0, nullptr, nullptr, nullptr, nullptr, nullptr, kv, 2048);
  k_kv_norm<<<NTOK, 256, 0, stream>>>(kv, cs);
  // dotsT[b,h] = V^T K'  (scale folded)
  k_atb<<<dim3(16, 32), 256, 0, stream>>>(kv + 1024, kv, 2048, 2048L * 2048, 2, dotsT, 1.f / 2048.f);
  k_qrot<<<NTOK / 4, 256, 0, stream>>>(x, cs, qrot);
  // merged[:, h*256:] = qrot @ dotsT[b,h]
  k_gemm<256, E_BF16><<<dim3(4, 128, 4), 256, 0, stream>>>(
      qrot, 256, dotsT, 262144L, 65536L, 256, nullptr, nullptr, nullptr, nullptr, nullptr, merged, 1024);
  // x2 = merged @ WocaT + boca + x
  k_gemm<1024, E_BIAS_RES_BOTH><<<dim3(4, 128, 1), 256, 0, stream>>>(
      merged, 1024, WocaT, 0, 0, 0, boca, x, nullptr, nullptr, x2, x2b, 256);
  // t1 = gelu(x2 @ Wf1 + bf1)
  k_gemm<256, E_BIAS_GELU><<<dim3(4, 128, 1), 256, 0, stream>>>(
      x2b, 256, Wf1T, 0, 0, 0, bf1, nullptr, nullptr, nullptr, nullptr, t1, 256);
  // x3 = t1 @ Wf2 + bf2 + x2
  k_gemm<256, E_BIAS_RES_F32><<<dim3(4, 128, 1), 256, 0, stream>>>(
      t1, 256, Wf2T, 0, 0, 0, bf2, x2, nullptr, nullptr, x3, nullptr, 256);
  k_ln<<<NTOK / 4, 256, 0, stream>>>(x3, lng, lnb, h);
  // p1o = gelu(h @ P1T + pvec*P1L)
  k_gemm<256, E_RANK1_GELU><<<dim3(4, 128, 1), 256, 0, stream>>>(
      h, 256, P1T, 0, 0, 0, nullptr, nullptr, P1L, pvec, nullptr, p1o, 256);
  k_gemm<256, E_GELU><<<dim3(4, 128, 1), 256, 0, stream>>>(
      p1o, 256, P2T, 0, 0, 0, nullptr, nullptr, nullptr, nullptr, nullptr, p2o, 256);
  // zp = p2o @ P3T + x3  (to d_out) + bf16 copy
  k_gemm<256, E_RES_BOTH><<<dim3(4, 128, 1), 256, 0, stream>>>(
      p2o, 256, P3T, 0, 0, 0, nullptr, x3, nullptr, nullptr, zp, zpb, 256);
  // qkv = zpb @ WqkvT
  k_gemm<256, E_BF16><<<dim3(12, 128, 1), 256, 0, stream>>>(
      zpb, 256, WqkvT, 0, 0, 0, nullptr, nullptr, nullptr, nullptr, nullptr, qkvb, 768);
  k_qkv_norm<<<NTOK, 128, 0, stream>>>(qkvb, cs);
  // dots2T[b] = v2^T k2'
  k_atb<<<dim3(16, 8), 256, 0, stream>>>(qkvb + 512, qkvb + 256, 768, 2048L * 768, 0, dots2T, 1.f / 2048.f);
  // att = q2' @ dots2T[b]
  k_gemm<256, E_BF16><<<dim3(4, 128, 1), 256, 0, stream>>>(
      qkvb, 768, dots2T, 65536L, 0, 0, nullptr, nullptr, nullptr, nullptr, nullptr, att, 256);
  // zd = att @ WodaT + boda + zp
  k_gemm<256, E_BIAS_RES_F32><<<dim3(4, 128, 1), 256, 0, stream>>>(
      att, 256, WodaT, 0, 0, 0, boda, zp, nullptr, nullptr, zd, nullptr, 256);
  k_ln<<<NTOK / 4, 256, 0, stream>>>(zd, ln2g, ln2b, h2);
  k_gemm<256, E_GELU><<<dim3(4, 128, 1), 256, 0, stream>>>(
      h2, 256, D1T, 0, 0, 0, nullptr, nullptr, nullptr, nullptr, nullptr, g1, 256);
  k_gemm<256, E_GELU><<<dim3(2, 128, 1), 256, 0, stream>>>(
      g1, 256, D2T, 0, 0, 0, nullptr, nullptr, nullptr, nullptr, nullptr, g2, 128);
  k_final<<<NTOK / 4, 256, 0, stream>>>(g2, D3, b3, u);
}

// Round 3
// 513.470 us; speedup vs baseline: 3.1139x; 1.1061x over previous
//
#include <hip/hip_runtime.h>
#include <hip/hip_bf16.h>

using bf16 = __hip_bfloat16;
typedef __attribute__((ext_vector_type(8))) short short8;
typedef __attribute__((ext_vector_type(4))) float f32x4;

constexpr int BB = 8;
constexpr int NN = 2048;
constexpr int CC = 256;
constexpr int NTOK = BB * NN;  // 16384
constexpr float TWO_PI = 6.283185307179586f;
constexpr float LOG2_1E4 = 13.287712379549449f;

__device__ __forceinline__ float gelu_f(float x) {
  return 0.5f * x * (1.0f + erff(x * 0.7071067811865475f));
}

template <int T>
__device__ __forceinline__ void stats_rows(const float (*buf)[CC], float* mu, float* rs, float eps) {
  __syncthreads();
  int w = threadIdx.x >> 6, l = threadIdx.x & 63;
  if (w < T) {
    float s = 0.f, s2 = 0.f;
#pragma unroll
    for (int j = 0; j < 4; ++j) { float v = buf[w][l + 64 * j]; s += v; s2 += v * v; }
#pragma unroll
    for (int o = 32; o; o >>= 1) { s += __shfl_down(s, o); s2 += __shfl_down(s2, o); }
    if (l == 0) {
      float m = s * (1.f / 256.f);
      float var = fmaxf(s2 * (1.f / 256.f) - m * m, 0.f);
      mu[w] = m; rs[w] = rsqrtf(var + eps);
    }
  }
  __syncthreads();
}

// ---------------- shared MFMA GEMM core: out += A[BMx64] * Bt[64x64]^T ------
// BM = MI*32. 256 threads = 4 waves (2x2). Per wave: (MI*16) x 32 output.
#define GLD16(src, dst)                                                       \
  __builtin_amdgcn_global_load_lds(                                           \
      (const __attribute__((address_space(1))) void*)(src),                   \
      (__attribute__((address_space(3))) void*)(dst), 16, 0, 0)

template <int K, int MI>
__device__ __forceinline__ void gemm_core(
    const bf16* __restrict__ Ap, int lda, const bf16* __restrict__ Bp,
    bf16 (&As)[MI * 32 * 64], bf16 (&Bs)[64 * 64], f32x4 (&acc)[MI][2]) {
  const int tid = threadIdx.x;
  const int w = tid >> 6, l = tid & 63;
  const int srow = l >> 3, scol = (l & 7) * 8;
  const int wm = w >> 1, wn = w & 1;
  for (int kt = 0; kt < K; kt += 64) {
#pragma unroll
    for (int i = 0; i < MI; ++i) {
      int r = (w * MI + i) * 8 + srow;
      GLD16(Ap + (long)r * lda + kt + scol, &As[(w * MI + i) * 512 + l * 8]);
    }
#pragma unroll
    for (int i = 0; i < 2; ++i) {
      int r = (w * 2 + i) * 8 + srow;
      GLD16(Bp + (long)r * K + kt + scol, &Bs[(w * 2 + i) * 512 + l * 8]);
    }
    __syncthreads();
    short8 bfr[2][2];
#pragma unroll
    for (int ni = 0; ni < 2; ++ni)
#pragma unroll
      for (int ks = 0; ks < 2; ++ks)
        bfr[ni][ks] = *(const short8*)&Bs[(wn * 32 + ni * 16 + (l & 15)) * 64 + ks * 32 + (l >> 4) * 8];
#pragma unroll
    for (int mi = 0; mi < MI; ++mi) {
#pragma unroll
      for (int ks = 0; ks < 2; ++ks) {
        short8 afr = *(const short8*)&As[(wm * (MI * 16) + mi * 16 + (l & 15)) * 64 + ks * 32 + (l >> 4) * 8];
#pragma unroll
        for (int ni = 0; ni < 2; ++ni)
          acc[mi][ni] = __builtin_amdgcn_mfma_f32_16x16x32_bf16(afr, bfr[ni][ks], acc[mi][ni], 0, 0, 0);
      }
    }
    __syncthreads();
  }
}

// ---------------- k_gemm with fused epilogues (BM=128, BN=64) ---------------
enum { E_BF16 = 0, E_BIAS_RESB_BOTH, E_BIAS_GELU, E_BIAS_RES_F32,
       E_RANK1_GELU, E_GELU, E_RES_BOTH };

template <int K, int EPI>
__global__ void __launch_bounds__(256) k_gemm(
    const bf16* __restrict__ A, int lda, const bf16* __restrict__ Bt,
    long bstride, long zstride, int nOffZ,
    const float* __restrict__ bias, const float* __restrict__ res,
    const bf16* __restrict__ resB, const float* __restrict__ rank1,
    const float* __restrict__ pvec,
    float* __restrict__ outF, bf16* __restrict__ outB, int ldo) {
  __shared__ bf16 As[128 * 64];
  __shared__ bf16 Bs[64 * 64];
  const int tid = threadIdx.x;
  const int w = tid >> 6, l = tid & 63;
  const int m0 = blockIdx.y * 128, n0 = blockIdx.x * 64;
  const int bidx = m0 >> 11;
  const bf16* Bp = Bt + (long)bidx * bstride + (long)blockIdx.z * zstride + (long)n0 * K;
  f32x4 acc[4][2] = {};
  gemm_core<K, 4>(A + (long)m0 * lda, lda, Bp, As, Bs, acc);
  const int wm = w >> 1, wn = w & 1;
  const int zoff = blockIdx.z * nOffZ;
#pragma unroll
  for (int mi = 0; mi < 4; ++mi) {
#pragma unroll
    for (int ni = 0; ni < 2; ++ni) {
      const int bcol = n0 + wn * 32 + ni * 16 + (l & 15);
      const int ocol = bcol + zoff;
#pragma unroll
      for (int r = 0; r < 4; ++r) {
        const int row = m0 + wm * 64 + mi * 16 + (l >> 4) * 4 + r;
        float v = acc[mi][ni][r];
        const long oidx = (long)row * ldo + ocol;
        if constexpr (EPI == E_BF16) { outB[oidx] = __float2bfloat16(v); }
        else if constexpr (EPI == E_BIAS_RESB_BOTH) {
          v += bias[bcol] + __bfloat162float(resB[oidx]);
          outF[oidx] = v; outB[oidx] = __float2bfloat16(v);
        } else if constexpr (EPI == E_BIAS_GELU) {
          v = gelu_f(v + bias[bcol]); outB[oidx] = __float2bfloat16(v);
        } else if constexpr (EPI == E_BIAS_RES_F32) {
          v += bias[bcol] + res[oidx]; outF[oidx] = v;
        } else if constexpr (EPI == E_RANK1_GELU) {
          v = gelu_f(v + pvec[row] * rank1[bcol]); outB[oidx] = __float2bfloat16(v);
        } else if constexpr (EPI == E_GELU) {
          v = gelu_f(v); outB[oidx] = __float2bfloat16(v);
        } else {  // E_RES_BOTH
          v += res[oidx]; outF[oidx] = v; outB[oidx] = __float2bfloat16(v);
        }
      }
    }
  }
}

// ---------------- k_gemmT: GEMM with TRANSPOSED per-matrix output -----------
// Writes out[mat][chan][n] where mat/chan derive from the output column and
// n is the token within batch. T0 = cols < thresh, T1 = cols >= thresh.
template <int K>
__global__ void __launch_bounds__(256) k_gemmT(
    const bf16* __restrict__ A, int lda, const bf16* __restrict__ Bt,
    bf16* __restrict__ T0, bf16* __restrict__ T1, int thresh, int matsPerB) {
  __shared__ union {
    struct { bf16 A[128 * 64]; bf16 B[64 * 64]; } ab;
    bf16 stage[64 * 136];
  } sm;
  const int tid = threadIdx.x;
  const int w = tid >> 6, l = tid & 63;
  const int m0 = blockIdx.y * 128, n0 = blockIdx.x * 64;
  f32x4 acc[4][2] = {};
  gemm_core<K, 4>(A + (long)m0 * lda, lda, Bt + (long)n0 * K, sm.ab.A, sm.ab.B, acc);
  const int wm = w >> 1, wn = w & 1;
  // stage acc tile transposed into LDS: stage[c_local][row_local]
#pragma unroll
  for (int mi = 0; mi < 4; ++mi)
#pragma unroll
    for (int ni = 0; ni < 2; ++ni) {
      int c = wn * 32 + ni * 16 + (l & 15);
#pragma unroll
      for (int r = 0; r < 4; ++r)
        sm.stage[c * 136 + wm * 64 + mi * 16 + (l >> 4) * 4 + r] = __float2bfloat16(acc[mi][ni][r]);
    }
  __syncthreads();
  const int b = m0 >> 11, nbase = m0 & 2047;
  const int part = (n0 >= thresh) ? 1 : 0;
  const int cT0 = n0 - (part ? thresh : 0);
  bf16* dst = (part ? T1 : T0) + ((long)(b * matsPerB + (cT0 >> 8))) * 524288
            + (long)(cT0 & 255) * 2048;
  const int c = tid >> 2, ns = tid & 3;
  bf16* rowp = dst + (long)c * 2048 + nbase + ns * 32;
#pragma unroll
  for (int j = 0; j < 4; ++j)
    *(short8*)&rowp[j * 8] = *(const short8*)&sm.stage[c * 136 + ns * 32 + j * 8];
}

// ---------------- k_atb2: D[mat] = A[mat] * B[mat]^T (both [256][2048]) -----
template <int MI>
__global__ void __launch_bounds__(256) k_atb2(
    const bf16* __restrict__ A0, const bf16* __restrict__ B0,
    bf16* __restrict__ D0, float scale) {
  __shared__ bf16 As[MI * 32 * 64];
  __shared__ bf16 Bs[64 * 64];
  const int tid = threadIdx.x;
  const int w = tid >> 6, l = tid & 63;
  const int mat = blockIdx.z;
  const int m0 = blockIdx.y * (MI * 32), n0 = blockIdx.x * 64;
  const bf16* Ap = A0 + (long)mat * 524288 + (long)m0 * 2048;
  const bf16* Bp = B0 + (long)mat * 524288 + (long)n0 * 2048;
  f32x4 acc[MI][2] = {};
  gemm_core<2048, MI>(Ap, 2048, Bp, As, Bs, acc);
  bf16* D = D0 + (long)mat * 65536;
  const int wm = w >> 1, wn = w & 1;
#pragma unroll
  for (int mi = 0; mi < MI; ++mi)
#pragma unroll
    for (int ni = 0; ni < 2; ++ni) {
      int col = n0 + wn * 32 + ni * 16 + (l & 15);
#pragma unroll
      for (int r = 0; r < 4; ++r) {
        int row = m0 + wm * (MI * 16) + mi * 16 + (l >> 4) * 4 + r;
        D[(long)row * 256 + col] = __float2bfloat16(acc[mi][ni][r] * scale);
      }
    }
}

// ---------------- stats over channels of transposed tiles -------------------
// Kt[mat][256][2048]; per (mat, n): mean/rsqrt-var over the 256 channels.
__global__ void __launch_bounds__(256) k_stats(
    const bf16* __restrict__ Kt, float* __restrict__ mu, float* __restrict__ rs) {
  const int mat = blockIdx.y;
  const int n = blockIdx.x * 256 + threadIdx.x;
  const bf16* base = Kt + (long)mat * 524288 + n;
  float s = 0.f, s2 = 0.f;
#pragma unroll 4
  for (int c = 0; c < 256; ++c) {
    float v = __bfloat162float(base[(long)c * 2048]);
    s += v; s2 += v * v;
  }
  float m = s * (1.f / 256.f);
  mu[mat * 2048 + n] = m;
  rs[mat * 2048 + n] = rsqrtf(fmaxf(s2 * (1.f / 256.f) - m * m, 0.f) + 1e-5f);
}

// norm + rotary in place on row pair (c, c+128) of Kt[mat]
__global__ void __launch_bounds__(256) k_rotnorm(
    bf16* __restrict__ Kt, const float* __restrict__ mu, const float* __restrict__ rs,
    const bf16* __restrict__ csT, int hshift) {
  const int mat = blockIdx.y, c = blockIdx.x;  // c in 0..127
  const int n = threadIdx.x * 8;
  bf16* r0 = Kt + (long)mat * 524288 + (long)c * 2048 + n;
  bf16* r1 = r0 + 128 * 2048;
  const long tok = ((long)(mat >> hshift)) * 2048 + n;
  const bf16* cop = csT + ((long)c * 2) * 16384 + tok;
  const bf16* sip = cop + 16384;
  short8 v0 = *(const short8*)r0, v1 = *(const short8*)r1;
  short8 co8 = *(const short8*)cop, si8 = *(const short8*)sip;
  const float* mup = mu + mat * 2048 + n;
  const float* rsp = rs + mat * 2048 + n;
  short8 o0, o1;
#pragma unroll
  for (int e = 0; e < 8; ++e) {
    float m = mup[e], r = rsp[e];
    float a = (__uint_as_float(((unsigned)(unsigned short)v0[e]) << 16) - m) * r;
    float b = (__uint_as_float(((unsigned)(unsigned short)v1[e]) << 16) - m) * r;
    float co = __uint_as_float(((unsigned)(unsigned short)co8[e]) << 16);
    float si = __uint_as_float(((unsigned)(unsigned short)si8[e]) << 16);
    bf16 t0 = __float2bfloat16(a * co - b * si);
    bf16 t1 = __float2bfloat16(b * co + a * si);
    o0[e] = *(short*)&t0; o1[e] = *(short*)&t1;
  }
  *(short8*)r0 = o0;
  *(short8*)r1 = o1;
}

// token-major instnorm + rotary (4 tokens/block); in may equal out
__global__ void __launch_bounds__(256) k_rotq(
    const bf16* __restrict__ in, bf16* __restrict__ out, const bf16* __restrict__ cs) {
  __shared__ float xr[4][CC];
  __shared__ float mu[4], rs[4];
  int tid = threadIdx.x;
  long tok0 = (long)blockIdx.x * 4;
#pragma unroll
  for (int t = 0; t < 4; ++t) xr[t][tid] = __bfloat162float(in[(tok0 + t) * 256 + tid]);
  stats_rows<4>(xr, mu, rs, 1e-5f);
  int i = tid & 127;
#pragma unroll
  for (int t = 0; t < 4; ++t) {
    float co = __bfloat162float(cs[(tok0 + t) * 256 + i]);
    float si = __bfloat162float(cs[(tok0 + t) * 256 + 128 + i]);
    float n0 = (xr[t][tid] - mu[t]) * rs[t];
    float n1 = (xr[t][tid ^ 128] - mu[t]) * rs[t];
    float o = (tid < 128) ? (n0 * co - n1 * si) : (n0 * co + n1 * si);
    out[(tok0 + t) * 256 + tid] = __float2bfloat16(o);
  }
}

// ---------------- small kernels ---------------------------------------------
__global__ void __launch_bounds__(256) k_pre(
    const float* __restrict__ pos, const float* __restrict__ Bf,
    bf16* __restrict__ gf, bf16* __restrict__ cs, bf16* __restrict__ csT,
    float* __restrict__ pvec) {
  int tid = threadIdx.x;
  long tok0 = (long)blockIdx.x * 4;
  float p[4];
#pragma unroll
  for (int t = 0; t < 4; ++t) p[t] = pos[tok0 + t];
  if (tid < 4) pvec[tok0 + tid] = p[tid] * 0.0625f;
  float bfc = Bf[tid];
#pragma unroll
  for (int t = 0; t < 4; ++t) {
    float xp = TWO_PI * (p[t] * 0.0625f) * bfc;
    float s, c; sincosf(xp, &s, &c);
    gf[(tok0 + t) * 512 + tid] = __float2bfloat16(gelu_f(s));
    gf[(tok0 + t) * 512 + 256 + tid] = __float2bfloat16(gelu_f(c));
  }
  if (tid < 128) {
    float inv = exp2f(-((float)tid * (1.f / 128.f)) * LOG2_1E4);
#pragma unroll
    for (int t = 0; t < 4; ++t) {
      float fh = p[t] * 2048.f * inv;
      float s, c; sincosf(fh, &s, &c);
      bf16 cb = __float2bfloat16(c), sb = __float2bfloat16(s);
      cs[(tok0 + t) * 256 + tid] = cb;
      cs[(tok0 + t) * 256 + 128 + tid] = sb;
      csT[(long)(tid * 2) * 16384 + tok0 + t] = cb;
      csT[(long)(tid * 2 + 1) * 16384 + tok0 + t] = sb;
    }
  }
}

__global__ void k_f2b(const float* __restrict__ s, bf16* __restrict__ d) {
  long i = (long)blockIdx.x * 256 + threadIdx.x;
  d[i] = __float2bfloat16(s[i]);
}

__global__ void __launch_bounds__(256) k_transpose(
    const float* __restrict__ src, bf16* __restrict__ dst, int K, int N) {
  int idx = blockIdx.x * 256 + threadIdx.x;
  if (idx < K * N) {
    int n = idx / K, k = idx - n * K;
    dst[idx] = __float2bfloat16(src[(long)k * N + n]);
  }
}

__global__ void k_copylast(const float* __restrict__ P1, float* __restrict__ P1L) {
  P1L[threadIdx.x] = P1[65536 + threadIdx.x];
}

__global__ void __launch_bounds__(256) k_ln(
    const float* __restrict__ xin, const float* __restrict__ g,
    const float* __restrict__ b, bf16* __restrict__ hout) {
  __shared__ float xr[4][CC];
  __shared__ float mu[4], rs[4];
  int tid = threadIdx.x;
  long tok0 = (long)blockIdx.x * 4;
#pragma unroll
  for (int t = 0; t < 4; ++t) xr[t][tid] = xin[(tok0 + t) * 256 + tid];
  stats_rows<4>(xr, mu, rs, 1e-5f);
  float gv = g[tid], bv = b[tid];
#pragma unroll
  for (int t = 0; t < 4; ++t)
    hout[(tok0 + t) * 256 + tid] = __float2bfloat16((xr[t][tid] - mu[t]) * rs[t] * gv + bv);
}

__global__ void __launch_bounds__(256) k_final(
    const bf16* __restrict__ g2, const float* __restrict__ D3,
    const float* __restrict__ b3, float* __restrict__ u) {
  int w = threadIdx.x >> 6, l = threadIdx.x & 63;
  long tok = (long)blockIdx.x * 4 + w;
  float s = __bfloat162float(g2[tok * 128 + l]) * D3[l]
          + __bfloat162float(g2[tok * 128 + 64 + l]) * D3[64 + l];
#pragma unroll
  for (int o = 32; o; o >>= 1) s += __shfl_down(s, o);
  if (l == 0) u[tok] = s + b3[0];
}

// ======================= launcher ===========================================
extern "C" void kernel_launch(void* const* d_in, const int* in_sizes, int n_in,
                              void* d_out, int out_size, void* d_ws, size_t ws_size,
                              hipStream_t stream) {
  const float* z    = (const float*)d_in[0];
  const float* pos  = (const float*)d_in[1];
  const float* Bf   = (const float*)d_in[2];
  const float* Wc   = (const float*)d_in[3];
  const float* Wkv  = (const float*)d_in[4];
  const float* Woca = (const float*)d_in[5];
  const float* boca = (const float*)d_in[6];
  const float* Wf1  = (const float*)d_in[7];
  const float* bf1  = (const float*)d_in[8];
  const float* Wf2  = (const float*)d_in[9];
  const float* bf2  = (const float*)d_in[10];
  const float* lng  = (const float*)d_in[11];
  const float* lnb  = (const float*)d_in[12];
  const float* P1   = (const float*)d_in[13];
  const float* P2   = (const float*)d_in[14];
  const float* P3   = (const float*)d_in[15];
  const float* Wqkv = (const float*)d_in[16];
  const float* Woda = (const float*)d_in[17];
  const float* boda = (const float*)d_in[18];
  const float* ln2g = (const float*)d_in[19];
  const float* ln2b = (const float*)d_in[20];
  const float* D1   = (const float*)d_in[21];
  const float* D2   = (const float*)d_in[22];
  const float* D3   = (const float*)d_in[23];
  const float* b3   = (const float*)d_in[24];

  float* u  = (float*)d_out;
  float* zp = (float*)d_out + NTOK;

  const long MB = 1048576L;
  char* ws = (char*)d_ws;
  // ---- static region [0,20MB) ----
  bf16*  cs   = (bf16*)(ws);                    // 8 MB token-major cos/sin
  bf16*  csT  = (bf16*)(ws + 8 * MB);           // 8 MB [128][2][16384]
  float* pvec = (float*)(ws + 16 * MB);         // 64 KB
  long wo = 16 * MB + 65536;
  bf16* WcT   = (bf16*)(ws + wo);               wo += 262144;
  bf16* WkvT  = (bf16*)(ws + wo);               wo += 1048576;
  bf16* WocaT = (bf16*)(ws + wo);               wo += 524288;
  bf16* Wf1T  = (bf16*)(ws + wo);               wo += 131072;
  bf16* Wf2T  = (bf16*)(ws + wo);               wo += 131072;
  bf16* P1T   = (bf16*)(ws + wo);               wo += 131072;
  bf16* P2T   = (bf16*)(ws + wo);               wo += 131072;
  bf16* P3T   = (bf16*)(ws + wo);               wo += 131072;
  bf16* WqkvT = (bf16*)(ws + wo);               wo += 393216;
  bf16* WodaT = (bf16*)(ws + wo);               wo += 131072;
  bf16* D1T   = (bf16*)(ws + wo);               wo += 131072;
  bf16* D2T   = (bf16*)(ws + wo);               wo += 65536;
  float* P1L  = (float*)(ws + wo);              wo += 1024;
  float* mu   = (float*)(ws + wo);              wo += 262144;
  float* rsb  = (float*)(ws + wo);              wo += 262144;
  // ---- dynamic arena (offsets in MB) ----
  bf16*  xb     = (bf16*)(ws + 20 * MB);   // [20,28)  x bf16
  bf16*  gf     = (bf16*)(ws + 28 * MB);   // [28,44)  fourier features
  bf16*  zb     = (bf16*)(ws + 28 * MB);   // [28,36)  (after gf dead)
  bf16*  Kt     = (bf16*)(ws + 36 * MB);   // [36,68)  32 x [256][2048]
  bf16*  Vt     = (bf16*)(ws + 68 * MB);   // [68,100)
  bf16*  dotsT  = (bf16*)(ws + 28 * MB);   // [28,32)  32 x [256][256]
  bf16*  qrot   = (bf16*)(ws + 36 * MB);   // [36,44)
  bf16*  merged = (bf16*)(ws + 44 * MB);   // [44,76)  [M,1024]
  float* x2     = (float*)(ws + 76 * MB);  // [76,92)  f32
  bf16*  x2b    = (bf16*)(ws + 92 * MB);   // [92,100)
  bf16*  t1     = (bf16*)(ws + 28 * MB);   // [28,36)
  float* x3     = (float*)(ws + 36 * MB);  // [36,52)  f32
  bf16*  h      = (bf16*)(ws + 52 * MB);   // [52,60)
  bf16*  p1o    = (bf16*)(ws + 60 * MB);   // [60,68)
  bf16*  p2o    = (bf16*)(ws + 68 * MB);   // [68,76)
  bf16*  zpb    = (bf16*)(ws + 76 * MB);   // [76,84)
  bf16*  q2b    = (bf16*)(ws + 84 * MB);   // [84,92)
  bf16*  k2t    = (bf16*)(ws + 92 * MB);   // [92,100) 8 x [256][2048]
  bf16*  v2t    = (bf16*)(ws + 28 * MB);   // [28,36)
  bf16*  dots2T = (bf16*)(ws + 36 * MB);   // [36,37)  8 x [256][256]
  bf16*  att    = (bf16*)(ws + 44 * MB);   // [44,52)
  float* zd     = (float*)(ws + 52 * MB);  // [52,68)  f32
  bf16*  h2     = (bf16*)(ws + 28 * MB);   // [28,36)
  bf16*  g1     = (bf16*)(ws + 36 * MB);   // [36,44)
  bf16*  g2     = (bf16*)(ws + 44 * MB);   // [44,48)

  auto TR = [&](const float* s, bf16* d, int K_, int N_) {
    k_transpose<<<(K_ * N_ + 255) / 256, 256, 0, stream>>>(s, d, K_, N_);
  };
  TR(Wc, WcT, 512, 256);      TR(Wkv, WkvT, 256, 2048);
  TR(Woca, WocaT, 1024, 256); TR(Wf1, Wf1T, 256, 256);
  TR(Wf2, Wf2T, 256, 256);    TR(P1, P1T, 256, 256);
  TR(P2, P2T, 256, 256);      TR(P3, P3T, 256, 256);
  TR(Wqkv, WqkvT, 256, 768);  TR(Woda, WodaT, 256, 256);
  TR(D1, D1T, 256, 256);      TR(D2, D2T, 256, 128);
  k_copylast<<<1, 256, 0, stream>>>(P1, P1L);

  k_pre<<<NTOK / 4, 256, 0, stream>>>(pos, Bf, gf, cs, csT, pvec);
  // x = gelu(fourier) @ WcT  (bf16)
  k_gemm<512, E_BF16><<<dim3(4, 128, 1), 256, 0, stream>>>(
      gf, 512, WcT, 0, 0, 0, nullptr, nullptr, nullptr, nullptr, nullptr, nullptr, xb, 256);
  k_f2b<<<NTOK * 256 / 256, 256, 0, stream>>>(z, zb);
  // Kt/Vt = (z @ Wkv) written transposed per (b,h)
  k_gemmT<256><<<dim3(32, 128), 256, 0, stream>>>(zb, 256, WkvT, Kt, Vt, 1024, 4);
  k_stats<<<dim3(8, 32), 256, 0, stream>>>(Kt, mu, rsb);
  k_rotnorm<<<dim3(128, 32), 256, 0, stream>>>(Kt, mu, rsb, csT, 2);
  // dotsT[mat] = Vt[mat] * Kt[mat]^T / n
  k_atb2<4><<<dim3(4, 2, 32), 256, 0, stream>>>(Vt, Kt, dotsT, 1.f / 2048.f);
  k_rotq<<<NTOK / 4, 256, 0, stream>>>(xb, qrot, cs);
  // merged[:, h*256:] = qrot @ dotsT[b,h]
  k_gemm<256, E_BF16><<<dim3(4, 128, 4), 256, 0, stream>>>(
      qrot, 256, dotsT, 262144L, 65536L, 256, nullptr, nullptr, nullptr, nullptr, nullptr,
      nullptr, merged, 1024);
  // x2 = merged @ WocaT + boca + x
  k_gemm<1024, E_BIAS_RESB_BOTH><<<dim3(4, 128, 1), 256, 0, stream>>>(
      merged, 1024, WocaT, 0, 0, 0, boca, nullptr, xb, nullptr, nullptr, x2, x2b, 256);
  // t1 = gelu(x2 @ Wf1 + bf1)
  k_gemm<256, E_BIAS_GELU><<<dim3(4, 128, 1), 256, 0, stream>>>(
      x2b, 256, Wf1T, 0, 0, 0, bf1, nullptr, nullptr, nullptr, nullptr, nullptr, t1, 256);
  // x3 = t1 @ Wf2 + bf2 + x2
  k_gemm<256, E_BIAS_RES_F32><<<dim3(4, 128, 1), 256, 0, stream>>>(
      t1, 256, Wf2T, 0, 0, 0, bf2, x2, nullptr, nullptr, nullptr, x3, nullptr, 256);
  k_ln<<<NTOK / 4, 256, 0, stream>>>(x3, lng, lnb, h);
  // p1o = gelu(h @ P1T + pvec*P1L)
  k_gemm<256, E_RANK1_GELU><<<dim3(4, 128, 1), 256, 0, stream>>>(
      h, 256, P1T, 0, 0, 0, nullptr, nullptr, nullptr, P1L, pvec, nullptr, p1o, 256);
  k_gemm<256, E_GELU><<<dim3(4, 128, 1), 256, 0, stream>>>(
      p1o, 256, P2T, 0, 0, 0, nullptr, nullptr, nullptr, nullptr, nullptr, nullptr, p2o, 256);
  // zp = p2o @ P3T + x3
  k_gemm<256, E_RES_BOTH><<<dim3(4, 128, 1), 256, 0, stream>>>(
      p2o, 256, P3T, 0, 0, 0, nullptr, x3, nullptr, nullptr, nullptr, zp, zpb, 256);
  // q2 token-major; k2/v2 transposed
  k_gemm<256, E_BF16><<<dim3(4, 128, 1), 256, 0, stream>>>(
      zpb, 256, WqkvT, 0, 0, 0, nullptr, nullptr, nullptr, nullptr, nullptr, nullptr, q2b, 256);
  k_gemmT<256><<<dim3(8, 128), 256, 0, stream>>>(zpb, 256, WqkvT + 65536, k2t, v2t, 256, 1);
  k_rotq<<<NTOK / 4, 256, 0, stream>>>(q2b, q2b, cs);
  k_stats<<<dim3(8, 8), 256, 0, stream>>>(k2t, mu, rsb);
  k_rotnorm<<<dim3(128, 8), 256, 0, stream>>>(k2t, mu, rsb, csT, 0);
  k_atb2<2><<<dim3(4, 4, 8), 256, 0, stream>>>(v2t, k2t, dots2T, 1.f / 2048.f);
  // att = q2' @ dots2T[b]
  k_gemm<256, E_BF16><<<dim3(4, 128, 1), 256, 0, stream>>>(
      q2b, 256, dots2T, 65536L, 0, 0, nullptr, nullptr, nullptr, nullptr, nullptr,
      nullptr, att, 256);
  // zd = att @ WodaT + boda + zp
  k_gemm<256, E_BIAS_RES_F32><<<dim3(4, 128, 1), 256, 0, stream>>>(
      att, 256, WodaT, 0, 0, 0, boda, zp, nullptr, nullptr, nullptr, zd, nullptr, 256);
  k_ln<<<NTOK / 4, 256, 0, stream>>>(zd, ln2g, ln2b, h2);
  k_gemm<256, E_GELU><<<dim3(4, 128, 1), 256, 0, stream>>>(
      h2, 256, D1T, 0, 0, 0, nullptr, nullptr, nullptr, nullptr, nullptr, nullptr, g1, 256);
  k_gemm<256, E_GELU><<<dim3(2, 128, 1), 256, 0, stream>>>(
      g1, 256, D2T, 0, 0, 0, nullptr, nullptr, nullptr, nullptr, nullptr, nullptr, g2, 128);
  k_final<<<NTOK / 4, 256, 0, stream>>>(g2, D3, b3, u);
}

// Round 5
// 477.128 us; speedup vs baseline: 3.3511x; 1.0762x over previous
//
#include <hip/hip_runtime.h>
#include <hip/hip_bf16.h>

using bf16 = __hip_bfloat16;
typedef __attribute__((ext_vector_type(8))) short short8;
typedef __attribute__((ext_vector_type(4))) short short4v;
typedef __attribute__((ext_vector_type(4))) float f32x4;

constexpr int BB = 8;
constexpr int NN = 2048;
constexpr int CC = 256;
constexpr int NTOK = BB * NN;  // 16384
constexpr float TWO_PI = 6.283185307179586f;
constexpr float LOG2_1E4 = 13.287712379549449f;

__device__ __forceinline__ float gelu_f(float x) {
  return 0.5f * x * (1.0f + erff(x * 0.7071067811865475f));
}

template <int T>
__device__ __forceinline__ void stats_rows(const float (*buf)[CC], float* mu, float* rs, float eps) {
  __syncthreads();
  int w = threadIdx.x >> 6, l = threadIdx.x & 63;
  if (w < T) {
    float s = 0.f, s2 = 0.f;
#pragma unroll
    for (int j = 0; j < 4; ++j) { float v = buf[w][l + 64 * j]; s += v; s2 += v * v; }
#pragma unroll
    for (int o = 32; o; o >>= 1) { s += __shfl_down(s, o); s2 += __shfl_down(s2, o); }
    if (l == 0) {
      float m = s * (1.f / 256.f);
      float var = fmaxf(s2 * (1.f / 256.f) - m * m, 0.f);
      mu[w] = m; rs[w] = rsqrtf(var + eps);
    }
  }
  __syncthreads();
}

// ---------------- shared MFMA GEMM core: out += A[BMx64] * Bt[64x64]^T ------
#define GLD16(src, dst)                                                       \
  __builtin_amdgcn_global_load_lds(                                           \
      (const __attribute__((address_space(1))) void*)(src),                   \
      (__attribute__((address_space(3))) void*)(dst), 16, 0, 0)

template <int K, int MI>
__device__ __forceinline__ void gemm_core(
    const bf16* __restrict__ Ap, int lda, const bf16* __restrict__ Bp,
    bf16 (&As)[MI * 32 * 64], bf16 (&Bs)[64 * 64], f32x4 (&acc)[MI][2]) {
  const int tid = threadIdx.x;
  const int w = tid >> 6, l = tid & 63;
  const int srow = l >> 3, scol = (l & 7) * 8;
  const int wm = w >> 1, wn = w & 1;
  for (int kt = 0; kt < K; kt += 64) {
#pragma unroll
    for (int i = 0; i < MI; ++i) {
      int r = (w * MI + i) * 8 + srow;
      GLD16(Ap + (long)r * lda + kt + scol, &As[(w * MI + i) * 512 + l * 8]);
    }
#pragma unroll
    for (int i = 0; i < 2; ++i) {
      int r = (w * 2 + i) * 8 + srow;
      GLD16(Bp + (long)r * K + kt + scol, &Bs[(w * 2 + i) * 512 + l * 8]);
    }
    __syncthreads();
    short8 bfr[2][2];
#pragma unroll
    for (int ni = 0; ni < 2; ++ni)
#pragma unroll
      for (int ks = 0; ks < 2; ++ks)
        bfr[ni][ks] = *(const short8*)&Bs[(wn * 32 + ni * 16 + (l & 15)) * 64 + ks * 32 + (l >> 4) * 8];
#pragma unroll
    for (int mi = 0; mi < MI; ++mi) {
#pragma unroll
      for (int ks = 0; ks < 2; ++ks) {
        short8 afr = *(const short8*)&As[(wm * (MI * 16) + mi * 16 + (l & 15)) * 64 + ks * 32 + (l >> 4) * 8];
#pragma unroll
        for (int ni = 0; ni < 2; ++ni)
          acc[mi][ni] = __builtin_amdgcn_mfma_f32_16x16x32_bf16(afr, bfr[ni][ks], acc[mi][ni], 0, 0, 0);
      }
    }
    __syncthreads();
  }
}

// ---------------- k_gemm with fused epilogues (BM=128, BN=64) ---------------
enum { E_BF16 = 0, E_BIAS_RESB_BOTH, E_BIAS_GELU, E_BIAS_RES_F32,
       E_RANK1_GELU, E_GELU, E_RES_BOTH };

template <int K, int EPI>
__global__ void __launch_bounds__(256) k_gemm(
    const bf16* __restrict__ A, int lda, const bf16* __restrict__ Bt,
    long bstride, long zstride, int nOffZ,
    const float* __restrict__ bias, const float* __restrict__ res,
    const bf16* __restrict__ resB, const float* __restrict__ rank1,
    const float* __restrict__ pvec,
    float* __restrict__ outF, bf16* __restrict__ outB, int ldo) {
  __shared__ bf16 As[128 * 64];
  __shared__ bf16 Bs[64 * 64];
  const int tid = threadIdx.x;
  const int w = tid >> 6, l = tid & 63;
  const int m0 = blockIdx.y * 128, n0 = blockIdx.x * 64;
  const int bidx = m0 >> 11;
  const bf16* Bp = Bt + (long)bidx * bstride + (long)blockIdx.z * zstride + (long)n0 * K;
  f32x4 acc[4][2] = {};
  gemm_core<K, 4>(A + (long)m0 * lda, lda, Bp, As, Bs, acc);
  const int wm = w >> 1, wn = w & 1;
  const int zoff = blockIdx.z * nOffZ;
#pragma unroll
  for (int mi = 0; mi < 4; ++mi) {
#pragma unroll
    for (int ni = 0; ni < 2; ++ni) {
      const int bcol = n0 + wn * 32 + ni * 16 + (l & 15);
      const int ocol = bcol + zoff;
#pragma unroll
      for (int r = 0; r < 4; ++r) {
        const int row = m0 + wm * 64 + mi * 16 + (l >> 4) * 4 + r;
        float v = acc[mi][ni][r];
        const long oidx = (long)row * ldo + ocol;
        if constexpr (EPI == E_BF16) { outB[oidx] = __float2bfloat16(v); }
        else if constexpr (EPI == E_BIAS_RESB_BOTH) {
          v += bias[bcol] + __bfloat162float(resB[oidx]);
          outF[oidx] = v; outB[oidx] = __float2bfloat16(v);
        } else if constexpr (EPI == E_BIAS_GELU) {
          v = gelu_f(v + bias[bcol]); outB[oidx] = __float2bfloat16(v);
        } else if constexpr (EPI == E_BIAS_RES_F32) {
          v += bias[bcol] + res[oidx]; outF[oidx] = v;
        } else if constexpr (EPI == E_RANK1_GELU) {
          v = gelu_f(v + pvec[row] * rank1[bcol]); outB[oidx] = __float2bfloat16(v);
        } else if constexpr (EPI == E_GELU) {
          v = gelu_f(v); outB[oidx] = __float2bfloat16(v);
        } else {  // E_RES_BOTH
          v += res[oidx]; outF[oidx] = v; outB[oidx] = __float2bfloat16(v);
        }
      }
    }
  }
}

// ---------------- k_gemmT: GEMM with TRANSPOSED per-matrix output ----------
// Also accumulates per-(token, head) instnorm stats (sum, sumsq) for the
// K-part columns (n0 < thresh) via f32 atomics, computed from f32 acc.
template <int K>
__global__ void __launch_bounds__(256) k_gemmT(
    const bf16* __restrict__ A, int lda, const bf16* __restrict__ Bt,
    bf16* __restrict__ T0, bf16* __restrict__ T1, int thresh, int matsPerB,
    float* __restrict__ sS, float* __restrict__ sS2) {
  __shared__ union {
    struct { bf16 A[128 * 64]; bf16 B[64 * 64]; } ab;
    bf16 stage[64 * 132];  // stride 132: u32-packed writes conflict-free,
                           // b64 reads 2-way (free)
  } sm;
  const int tid = threadIdx.x;
  const int w = tid >> 6, l = tid & 63;
  const int m0 = blockIdx.y * 128, n0 = blockIdx.x * 64;
  f32x4 acc[4][2] = {};
  gemm_core<K, 4>(A + (long)m0 * lda, lda, Bt + (long)n0 * K, sm.ab.A, sm.ab.B, acc);
  const int wm = w >> 1, wn = w & 1;

  // ---- fused instnorm stats for K-part blocks ----
  if (n0 < thresh) {
    float sr[16], s2r[16];
#pragma unroll
    for (int mi = 0; mi < 4; ++mi)
#pragma unroll
      for (int r = 0; r < 4; ++r) {
        float v0 = acc[mi][0][r], v1 = acc[mi][1][r];
        sr[mi * 4 + r] = v0 + v1;
        s2r[mi * 4 + r] = v0 * v0 + v1 * v1;
      }
#pragma unroll
    for (int o = 1; o < 16; o <<= 1) {
#pragma unroll
      for (int i = 0; i < 16; ++i) {
        sr[i] += __shfl_xor(sr[i], o);
        s2r[i] += __shfl_xor(s2r[i], o);
      }
    }
    if ((l & 15) == 0) {
      const int head = n0 >> 8;
      const long base = (long)head * 16384 + m0 + wm * 64 + (l >> 4) * 4;
#pragma unroll
      for (int mi = 0; mi < 4; ++mi)
#pragma unroll
        for (int r = 0; r < 4; ++r) {
          atomicAdd(&sS[base + mi * 16 + r], sr[mi * 4 + r]);
          atomicAdd(&sS2[base + mi * 16 + r], s2r[mi * 4 + r]);
        }
    }
  }

  // ---- stage acc tile transposed into LDS (packed u32 writes) ----
#pragma unroll
  for (int mi = 0; mi < 4; ++mi)
#pragma unroll
    for (int ni = 0; ni < 2; ++ni) {
      int c = wn * 32 + ni * 16 + (l & 15);
      int row0 = wm * 64 + mi * 16 + (l >> 4) * 4;
#pragma unroll
      for (int q = 0; q < 2; ++q) {
        bf16 b0 = __float2bfloat16(acc[mi][ni][2 * q]);
        bf16 b1 = __float2bfloat16(acc[mi][ni][2 * q + 1]);
        unsigned u = (unsigned)*(unsigned short*)&b0 |
                     ((unsigned)*(unsigned short*)&b1 << 16);
        *(unsigned*)&sm.stage[c * 132 + row0 + 2 * q] = u;
      }
    }
  __syncthreads();
  const int b = m0 >> 11, nbase = m0 & 2047;
  const int part = (n0 >= thresh) ? 1 : 0;
  const int cT0 = n0 - (part ? thresh : 0);
  bf16* dst = (part ? T1 : T0) + ((long)(b * matsPerB + (cT0 >> 8))) * 524288
            + (long)(cT0 & 255) * 2048;
  const int c = tid >> 2, ns = tid & 3;
  bf16* rowp = dst + (long)c * 2048 + nbase + ns * 32;
#pragma unroll
  for (int j = 0; j < 4; ++j) {
    short4v lo = *(const short4v*)&sm.stage[c * 132 + ns * 32 + j * 8];
    short4v hi = *(const short4v*)&sm.stage[c * 132 + ns * 32 + j * 8 + 4];
    short8 v;
    v[0] = lo[0]; v[1] = lo[1]; v[2] = lo[2]; v[3] = lo[3];
    v[4] = hi[0]; v[5] = hi[1]; v[6] = hi[2]; v[7] = hi[3];
    *(short8*)&rowp[j * 8] = v;
  }
}

// ---------------- k_atb2: D[mat] = A[mat] * B[mat]^T (both [256][2048]) -----
template <int MI>
__global__ void __launch_bounds__(256) k_atb2(
    const bf16* __restrict__ A0, const bf16* __restrict__ B0,
    bf16* __restrict__ D0, float scale) {
  __shared__ bf16 As[MI * 32 * 64];
  __shared__ bf16 Bs[64 * 64];
  const int tid = threadIdx.x;
  const int w = tid >> 6, l = tid & 63;
  const int mat = blockIdx.z;
  const int m0 = blockIdx.y * (MI * 32), n0 = blockIdx.x * 64;
  const bf16* Ap = A0 + (long)mat * 524288 + (long)m0 * 2048;
  const bf16* Bp = B0 + (long)mat * 524288 + (long)n0 * 2048;
  f32x4 acc[MI][2] = {};
  gemm_core<2048, MI>(Ap, 2048, Bp, As, Bs, acc);
  bf16* D = D0 + (long)mat * 65536;
  const int wm = w >> 1, wn = w & 1;
#pragma unroll
  for (int mi = 0; mi < MI; ++mi)
#pragma unroll
    for (int ni = 0; ni < 2; ++ni) {
      int col = n0 + wn * 32 + ni * 16 + (l & 15);
#pragma unroll
      for (int r = 0; r < 4; ++r) {
        int row = m0 + wm * (MI * 16) + mi * 16 + (l >> 4) * 4 + r;
        D[(long)row * 256 + col] = __float2bfloat16(acc[mi][ni][r] * scale);
      }
    }
}

// norm + rotary in place on row pair (c, c+128) of Kt[mat]; stats from s/s2
__global__ void __launch_bounds__(256) k_rotnorm(
    bf16* __restrict__ Kt, const float* __restrict__ sS, const float* __restrict__ sS2,
    const bf16* __restrict__ csT, int hshift) {
  const int mat = blockIdx.y, c = blockIdx.x;  // c in 0..127
  const int n = threadIdx.x * 8;
  const int b = mat >> hshift, h = mat & ((1 << hshift) - 1);
  bf16* r0 = Kt + (long)mat * 524288 + (long)c * 2048 + n;
  bf16* r1 = r0 + 128 * 2048;
  const long tok = (long)b * 2048 + n;
  const bf16* cop = csT + ((long)c * 2) * 16384 + tok;
  const bf16* sip = cop + 16384;
  const float* sp = sS + (long)h * 16384 + tok;
  const float* s2p = sS2 + (long)h * 16384 + tok;
  short8 v0 = *(const short8*)r0, v1 = *(const short8*)r1;
  short8 co8 = *(const short8*)cop, si8 = *(const short8*)sip;
  short8 o0, o1;
#pragma unroll
  for (int e = 0; e < 8; ++e) {
    float s = sp[e], s2 = s2p[e];
    float m = s * (1.f / 256.f);
    float r = rsqrtf(fmaxf(s2 * (1.f / 256.f) - m * m, 0.f) + 1e-5f);
    float a = (__uint_as_float(((unsigned)(unsigned short)v0[e]) << 16) - m) * r;
    float bb = (__uint_as_float(((unsigned)(unsigned short)v1[e]) << 16) - m) * r;
    float co = __uint_as_float(((unsigned)(unsigned short)co8[e]) << 16);
    float si = __uint_as_float(((unsigned)(unsigned short)si8[e]) << 16);
    bf16 t0 = __float2bfloat16(a * co - bb * si);
    bf16 t1 = __float2bfloat16(bb * co + a * si);
    o0[e] = *(short*)&t0; o1[e] = *(short*)&t1;
  }
  *(short8*)r0 = o0;
  *(short8*)r1 = o1;
}

// token-major instnorm + rotary (4 tokens/block); in may equal out
__global__ void __launch_bounds__(256) k_rotq(
    const bf16* __restrict__ in, bf16* __restrict__ out, const bf16* __restrict__ cs) {
  __shared__ float xr[4][CC];
  __shared__ float mu[4], rs[4];
  int tid = threadIdx.x;
  long tok0 = (long)blockIdx.x * 4;
#pragma unroll
  for (int t = 0; t < 4; ++t) xr[t][tid] = __bfloat162float(in[(tok0 + t) * 256 + tid]);
  stats_rows<4>(xr, mu, rs, 1e-5f);
  int i = tid & 127;
#pragma unroll
  for (int t = 0; t < 4; ++t) {
    float co = __bfloat162float(cs[(tok0 + t) * 256 + i]);
    float si = __bfloat162float(cs[(tok0 + t) * 256 + 128 + i]);
    float n0 = (xr[t][tid] - mu[t]) * rs[t];
    float n1 = (xr[t][tid ^ 128] - mu[t]) * rs[t];
    float o = (tid < 128) ? (n0 * co - n1 * si) : (n0 * co + n1 * si);
    out[(tok0 + t) * 256 + tid] = __float2bfloat16(o);
  }
}

// ---------------- weight prep: 12 transposes + stats zeroing, one kernel ----
struct WEnt { const float* s; bf16* d; int K; int N; int blk0; };
struct WTab { WEnt e[12]; };

__global__ void __launch_bounds__(256) k_wprep(WTab t, int nblk_tr,
                                               float* __restrict__ zbuf, int zcnt) {
  int bid = blockIdx.x;
  if (bid >= nblk_tr) {
    int idx = (bid - nblk_tr) * 256 + threadIdx.x;
    if (idx < zcnt) zbuf[idx] = 0.f;
    return;
  }
  int ei = 0;
#pragma unroll
  for (int i = 1; i < 12; ++i)
    if (bid >= t.e[i].blk0) ei = i;
  WEnt e = t.e[ei];
  int local = (bid - e.blk0) * 256 + threadIdx.x;
  if (local < e.K * e.N) {
    int n = local / e.K, k = local - n * e.K;
    e.d[local] = __float2bfloat16(e.s[(long)k * e.N + n]);
  }
}

// ---------------- k_pre: fourier feats, cos/sin tables, pvec, z->bf16, P1L --
__global__ void __launch_bounds__(256) k_pre(
    const float* __restrict__ pos, const float* __restrict__ Bf,
    const float* __restrict__ z, const float* __restrict__ P1,
    bf16* __restrict__ gf, bf16* __restrict__ cs, bf16* __restrict__ csT,
    float* __restrict__ pvec, bf16* __restrict__ zb, float* __restrict__ P1L) {
  int tid = threadIdx.x;
  long tok0 = (long)blockIdx.x * 4;
  if (blockIdx.x == 0) P1L[tid] = P1[65536 + tid];
  float p[4];
#pragma unroll
  for (int t = 0; t < 4; ++t) p[t] = pos[tok0 + t];
  if (tid < 4) pvec[tok0 + tid] = p[tid] * 0.0625f;
  float bfc = Bf[tid];
#pragma unroll
  for (int t = 0; t < 4; ++t) {
    float xp = TWO_PI * (p[t] * 0.0625f) * bfc;
    float s, c; sincosf(xp, &s, &c);
    gf[(tok0 + t) * 512 + tid] = __float2bfloat16(gelu_f(s));
    gf[(tok0 + t) * 512 + 256 + tid] = __float2bfloat16(gelu_f(c));
    zb[(tok0 + t) * 256 + tid] = __float2bfloat16(z[(tok0 + t) * 256 + tid]);
  }
  if (tid < 128) {
    float inv = exp2f(-((float)tid * (1.f / 128.f)) * LOG2_1E4);
#pragma unroll
    for (int t = 0; t < 4; ++t) {
      float fh = p[t] * 2048.f * inv;
      float s, c; sincosf(fh, &s, &c);
      bf16 cb = __float2bfloat16(c), sb = __float2bfloat16(s);
      cs[(tok0 + t) * 256 + tid] = cb;
      cs[(tok0 + t) * 256 + 128 + tid] = sb;
      csT[(long)(tid * 2) * 16384 + tok0 + t] = cb;
      csT[(long)(tid * 2 + 1) * 16384 + tok0 + t] = sb;
    }
  }
}

__global__ void __launch_bounds__(256) k_ln(
    const float* __restrict__ xin, const float* __restrict__ g,
    const float* __restrict__ b, bf16* __restrict__ hout) {
  __shared__ float xr[4][CC];
  __shared__ float mu[4], rs[4];
  int tid = threadIdx.x;
  long tok0 = (long)blockIdx.x * 4;
#pragma unroll
  for (int t = 0; t < 4; ++t) xr[t][tid] = xin[(tok0 + t) * 256 + tid];
  stats_rows<4>(xr, mu, rs, 1e-5f);
  float gv = g[tid], bv = b[tid];
#pragma unroll
  for (int t = 0; t < 4; ++t)
    hout[(tok0 + t) * 256 + tid] = __float2bfloat16((xr[t][tid] - mu[t]) * rs[t] * gv + bv);
}

__global__ void __launch_bounds__(256) k_final(
    const bf16* __restrict__ g2, const float* __restrict__ D3,
    const float* __restrict__ b3, float* __restrict__ u) {
  int w = threadIdx.x >> 6, l = threadIdx.x & 63;
  long tok = (long)blockIdx.x * 4 + w;
  float s = __bfloat162float(g2[tok * 128 + l]) * D3[l]
          + __bfloat162float(g2[tok * 128 + 64 + l]) * D3[64 + l];
#pragma unroll
  for (int o = 32; o; o >>= 1) s += __shfl_down(s, o);
  if (l == 0) u[tok] = s + b3[0];
}

// ======================= launcher ===========================================
extern "C" void kernel_launch(void* const* d_in, const int* in_sizes, int n_in,
                              void* d_out, int out_size, void* d_ws, size_t ws_size,
                              hipStream_t stream) {
  const float* z    = (const float*)d_in[0];
  const float* pos  = (const float*)d_in[1];
  const float* Bf   = (const float*)d_in[2];
  const float* Wc   = (const float*)d_in[3];
  const float* Wkv  = (const float*)d_in[4];
  const float* Woca = (const float*)d_in[5];
  const float* boca = (const float*)d_in[6];
  const float* Wf1  = (const float*)d_in[7];
  const float* bf1  = (const float*)d_in[8];
  const float* Wf2  = (const float*)d_in[9];
  const float* bf2  = (const float*)d_in[10];
  const float* lng  = (const float*)d_in[11];
  const float* lnb  = (const float*)d_in[12];
  const float* P1   = (const float*)d_in[13];
  const float* P2   = (const float*)d_in[14];
  const float* P3   = (const float*)d_in[15];
  const float* Wqkv = (const float*)d_in[16];
  const float* Woda = (const float*)d_in[17];
  const float* boda = (const float*)d_in[18];
  const float* ln2g = (const float*)d_in[19];
  const float* ln2b = (const float*)d_in[20];
  const float* D1   = (const float*)d_in[21];
  const float* D2   = (const float*)d_in[22];
  const float* D3   = (const float*)d_in[23];
  const float* b3   = (const float*)d_in[24];

  float* u  = (float*)d_out;
  float* zp = (float*)d_out + NTOK;

  const long MB = 1048576L;
  char* ws = (char*)d_ws;
  // ---- static region [0, 24MB) ----
  bf16*  cs   = (bf16*)(ws);                    // 8 MB token-major cos/sin
  bf16*  csT  = (bf16*)(ws + 8 * MB);           // 8 MB [128][2][16384]
  float* pvec = (float*)(ws + 16 * MB);         // 64 KB
  long wo = 16 * MB + 65536;
  bf16* WcT   = (bf16*)(ws + wo);               wo += 262144;
  bf16* WkvT  = (bf16*)(ws + wo);               wo += 1048576;
  bf16* WocaT = (bf16*)(ws + wo);               wo += 524288;
  bf16* Wf1T  = (bf16*)(ws + wo);               wo += 131072;
  bf16* Wf2T  = (bf16*)(ws + wo);               wo += 131072;
  bf16* P1T   = (bf16*)(ws + wo);               wo += 131072;
  bf16* P2T   = (bf16*)(ws + wo);               wo += 131072;
  bf16* P3T   = (bf16*)(ws + wo);               wo += 131072;
  bf16* WqkvT = (bf16*)(ws + wo);               wo += 393216;
  bf16* WodaT = (bf16*)(ws + wo);               wo += 131072;
  bf16* D1T   = (bf16*)(ws + wo);               wo += 131072;
  bf16* D2T   = (bf16*)(ws + wo);               wo += 65536;
  float* P1L  = (float*)(ws + wo);              wo += 1024;
  float* sS   = (float*)(ws + wo);              wo += 5 * 16384 * 4;  // [5][16384]
  float* sS2  = (float*)(ws + wo);              wo += 5 * 16384 * 4;
  // ---- dynamic arena at 24 MB (lifetime-audited; zb/Vt overlap was the
  //      round-4 bug: kv gemmT read zb while writing Vt into same range) ----
  char* AR = ws + 24 * MB;
  bf16*  xb     = (bf16*)(AR);             // [0,8)   W3  -> R9
  bf16*  zb     = (bf16*)(AR + 8 * MB);    // [8,16)  W2  -> R4
  bf16*  gf     = (bf16*)(AR + 48 * MB);   // [48,64) W2  -> R3 (Vt overwrites after)
  bf16*  Kt     = (bf16*)(AR + 16 * MB);   // [16,48) W4/5 -> R6
  bf16*  Vt     = (bf16*)(AR + 48 * MB);   // [48,80) W4  -> R6
  bf16*  dotsT  = (bf16*)(AR + 8 * MB);    // [8,12)  W6  -> R8
  bf16*  qrot   = (bf16*)(AR + 16 * MB);   // [16,24) W7  -> R8
  bf16*  merged = (bf16*)(AR + 24 * MB);   // [24,56) W8  -> R9
  float* x2     = (float*)(AR + 56 * MB);  // [56,72) W9  -> R11 (f32)
  bf16*  x2b    = (bf16*)(AR + 72 * MB);   // [72,80) W9  -> R10
  bf16*  t1     = (bf16*)(AR + 8 * MB);    // [8,16)  W10 -> R11
  float* x3     = (float*)(AR + 16 * MB);  // [16,32) W11 -> R15 (f32)
  bf16*  h      = (bf16*)(AR + 32 * MB);   // [32,40) W12 -> R13
  bf16*  p1o    = (bf16*)(AR + 40 * MB);   // [40,48) W13 -> R14
  bf16*  p2o    = (bf16*)(AR + 48 * MB);   // [48,56) W14 -> R15
  bf16*  zpb    = (bf16*)(AR + 56 * MB);   // [56,64) W15 -> R17
  bf16*  q2b    = (bf16*)(AR + 64 * MB);   // [64,72) W16/18 -> R21
  bf16*  k2t    = (bf16*)(AR + 72 * MB);   // [72,80) W17/19 -> R20
  bf16*  v2t    = (bf16*)(AR + 8 * MB);    // [8,16)  W17 -> R20
  bf16*  dots2T = (bf16*)(AR + 16 * MB);   // [16,17) W20 -> R21
  bf16*  att    = (bf16*)(AR + 24 * MB);   // [24,32) W21 -> R22
  float* zd     = (float*)(AR + 32 * MB);  // [32,48) W22 -> R23 (f32)
  bf16*  h2     = (bf16*)(AR + 8 * MB);    // [8,16)  W23 -> R24
  bf16*  g1     = (bf16*)(AR + 16 * MB);   // [16,24) W24 -> R25
  bf16*  g2     = (bf16*)(AR + 24 * MB);   // [24,28) W25 -> R26

  // ---- weight-prep table ----
  WTab tab;
  int nb = 0;
  auto add = [&](int i, const float* s, bf16* d, int K_, int N_) {
    tab.e[i].s = s; tab.e[i].d = d; tab.e[i].K = K_; tab.e[i].N = N_;
    tab.e[i].blk0 = nb; nb += (K_ * N_) / 256;
  };
  add(0, Wc, WcT, 512, 256);
  add(1, Wkv, WkvT, 256, 2048);
  add(2, Woca, WocaT, 1024, 256);
  add(3, Wf1, Wf1T, 256, 256);
  add(4, Wf2, Wf2T, 256, 256);
  add(5, P1, P1T, 256, 256);
  add(6, P2, P2T, 256, 256);
  add(7, P3, P3T, 256, 256);
  add(8, Wqkv, WqkvT, 256, 768);
  add(9, Woda, WodaT, 256, 256);
  add(10, D1, D1T, 256, 256);
  add(11, D2, D2T, 256, 128);
  const int zcnt = 2 * 5 * 16384;                   // sS ++ sS2 contiguous
  const int zblk = (zcnt + 255) / 256;
  k_wprep<<<nb + zblk, 256, 0, stream>>>(tab, nb, sS, zcnt);

  k_pre<<<NTOK / 4, 256, 0, stream>>>(pos, Bf, z, P1, gf, cs, csT, pvec, zb, P1L);
  // x = gelu(fourier) @ WcT
  k_gemm<512, E_BF16><<<dim3(4, 128, 1), 256, 0, stream>>>(
      gf, 512, WcT, 0, 0, 0, nullptr, nullptr, nullptr, nullptr, nullptr, nullptr, xb, 256);
  // Kt/Vt = (z @ Wkv) transposed per (b,h); K-part stats fused
  k_gemmT<256><<<dim3(32, 128), 256, 0, stream>>>(zb, 256, WkvT, Kt, Vt, 1024, 4, sS, sS2);
  k_rotnorm<<<dim3(128, 32), 256, 0, stream>>>(Kt, sS, sS2, csT, 2);
  // dotsT[mat] = Vt[mat] * Kt[mat]^T / n
  k_atb2<4><<<dim3(4, 2, 32), 256, 0, stream>>>(Vt, Kt, dotsT, 1.f / 2048.f);
  k_rotq<<<NTOK / 4, 256, 0, stream>>>(xb, qrot, cs);
  // merged[:, h*256:] = qrot @ dotsT[b,h]
  k_gemm<256, E_BF16><<<dim3(4, 128, 4), 256, 0, stream>>>(
      qrot, 256, dotsT, 262144L, 65536L, 256, nullptr, nullptr, nullptr, nullptr, nullptr,
      nullptr, merged, 1024);
  // x2 = merged @ WocaT + boca + x
  k_gemm<1024, E_BIAS_RESB_BOTH><<<dim3(4, 128, 1), 256, 0, stream>>>(
      merged, 1024, WocaT, 0, 0, 0, boca, nullptr, xb, nullptr, nullptr, x2, x2b, 256);
  // t1 = gelu(x2 @ Wf1 + bf1)
  k_gemm<256, E_BIAS_GELU><<<dim3(4, 128, 1), 256, 0, stream>>>(
      x2b, 256, Wf1T, 0, 0, 0, bf1, nullptr, nullptr, nullptr, nullptr, nullptr, t1, 256);
  // x3 = t1 @ Wf2 + bf2 + x2
  k_gemm<256, E_BIAS_RES_F32><<<dim3(4, 128, 1), 256, 0, stream>>>(
      t1, 256, Wf2T, 0, 0, 0, bf2, x2, nullptr, nullptr, nullptr, x3, nullptr, 256);
  k_ln<<<NTOK / 4, 256, 0, stream>>>(x3, lng, lnb, h);
  // p1o = gelu(h @ P1T + pvec*P1L)
  k_gemm<256, E_RANK1_GELU><<<dim3(4, 128, 1), 256, 0, stream>>>(
      h, 256, P1T, 0, 0, 0, nullptr, nullptr, nullptr, P1L, pvec, nullptr, p1o, 256);
  k_gemm<256, E_GELU><<<dim3(4, 128, 1), 256, 0, stream>>>(
      p1o, 256, P2T, 0, 0, 0, nullptr, nullptr, nullptr, nullptr, nullptr, nullptr, p2o, 256);
  // zp = p2o @ P3T + x3
  k_gemm<256, E_RES_BOTH><<<dim3(4, 128, 1), 256, 0, stream>>>(
      p2o, 256, P3T, 0, 0, 0, nullptr, x3, nullptr, nullptr, nullptr, zp, zpb, 256);
  // q2 token-major; k2/v2 transposed (+ k2 stats, row 4 of sS)
  k_gemm<256, E_BF16><<<dim3(4, 128, 1), 256, 0, stream>>>(
      zpb, 256, WqkvT, 0, 0, 0, nullptr, nullptr, nullptr, nullptr, nullptr, nullptr, q2b, 256);
  k_gemmT<256><<<dim3(8, 128), 256, 0, stream>>>(zpb, 256, WqkvT + 65536, k2t, v2t, 256, 1,
                                                 sS + 4 * 16384, sS2 + 4 * 16384);
  k_rotq<<<NTOK / 4, 256, 0, stream>>>(q2b, q2b, cs);
  k_rotnorm<<<dim3(128, 8), 256, 0, stream>>>(k2t, sS + 4 * 16384, sS2 + 4 * 16384, csT, 0);
  k_atb2<2><<<dim3(4, 4, 8), 256, 0, stream>>>(v2t, k2t, dots2T, 1.f / 2048.f);
  // att = q2' @ dots2T[b]
  k_gemm<256, E_BF16><<<dim3(4, 128, 1), 256, 0, stream>>>(
      q2b, 256, dots2T, 65536L, 0, 0, nullptr, nullptr, nullptr, nullptr, nullptr,
      nullptr, att, 256);
  // zd = att @ WodaT + boda + zp
  k_gemm<256, E_BIAS_RES_F32><<<dim3(4, 128, 1), 256, 0, stream>>>(
      att, 256, WodaT, 0, 0, 0, boda, zp, nullptr, nullptr, nullptr, zd, nullptr, 256);
  k_ln<<<NTOK / 4, 256, 0, stream>>>(zd, ln2g, ln2b, h2);
  k_gemm<256, E_GELU><<<dim3(4, 128, 1), 256, 0, stream>>>(
      h2, 256, D1T, 0, 0, 0, nullptr, nullptr, nullptr, nullptr, nullptr, nullptr, g1, 256);
  k_gemm<256, E_GELU><<<dim3(2, 128, 1), 256, 0, stream>>>(
      g1, 256, D2T, 0, 0, 0, nullptr, nullptr, nullptr, nullptr, nullptr, nullptr, g2, 128);
  k_final<<<NTOK / 4, 256, 0, stream>>>(g2, D3, b3, u);
}

// Round 6
// 476.648 us; speedup vs baseline: 3.3545x; 1.0010x over previous
//
#include <hip/hip_runtime.h>
#include <hip/hip_bf16.h>

using bf16 = __hip_bfloat16;
typedef __attribute__((ext_vector_type(8))) short short8;
typedef __attribute__((ext_vector_type(4))) short short4v;
typedef __attribute__((ext_vector_type(4))) float f32x4;

constexpr int BB = 8;
constexpr int NN = 2048;
constexpr int CC = 256;
constexpr int NTOK = BB * NN;  // 16384
constexpr float TWO_PI = 6.283185307179586f;
constexpr float LOG2_1E4 = 13.287712379549449f;

__device__ __forceinline__ float gelu_f(float x) {
  return 0.5f * x * (1.0f + erff(x * 0.7071067811865475f));
}

template <int T>
__device__ __forceinline__ void stats_rows(const float (*buf)[CC], float* mu, float* rs, float eps) {
  __syncthreads();
  int w = threadIdx.x >> 6, l = threadIdx.x & 63;
  if (w < T) {
    float s = 0.f, s2 = 0.f;
#pragma unroll
    for (int j = 0; j < 4; ++j) { float v = buf[w][l + 64 * j]; s += v; s2 += v * v; }
#pragma unroll
    for (int o = 32; o; o >>= 1) { s += __shfl_down(s, o); s2 += __shfl_down(s2, o); }
    if (l == 0) {
      float m = s * (1.f / 256.f);
      float var = fmaxf(s2 * (1.f / 256.f) - m * m, 0.f);
      mu[w] = m; rs[w] = rsqrtf(var + eps);
    }
  }
  __syncthreads();
}

// ---------------- shared MFMA GEMM core: out += A[BMx64] * Bt[64x64]^T ------
// XOR-swizzled LDS (T2): dest stays linear for global_load_lds; the global
// SOURCE column is pre-swizzled by (row&7)*8, and ds_reads apply the same
// XOR. Reads then hit 8 distinct 4-bank groups (2-way = free) instead of the
// old row-stride-128B 16-way conflict.
#define GLD16(src, dst)                                                       \
  __builtin_amdgcn_global_load_lds(                                           \
      (const __attribute__((address_space(1))) void*)(src),                   \
      (__attribute__((address_space(3))) void*)(dst), 16, 0, 0)

template <int K, int MI>
__device__ __forceinline__ void gemm_core(
    const bf16* __restrict__ Ap, int lda, const bf16* __restrict__ Bp,
    bf16 (&As)[MI * 32 * 64], bf16 (&Bs)[64 * 64], f32x4 (&acc)[MI][2]) {
  const int tid = threadIdx.x;
  const int w = tid >> 6, l = tid & 63;
  const int srow = l >> 3;
  const int scol = ((l & 7) ^ srow) * 8;  // swizzled source col
  const int rsw = (l & 7) * 8;            // read-side XOR (row&7 == l&7)
  const int wm = w >> 1, wn = w & 1;
  for (int kt = 0; kt < K; kt += 64) {
#pragma unroll
    for (int i = 0; i < MI; ++i) {
      int r = (w * MI + i) * 8 + srow;
      GLD16(Ap + (long)r * lda + kt + scol, &As[(w * MI + i) * 512 + l * 8]);
    }
#pragma unroll
    for (int i = 0; i < 2; ++i) {
      int r = (w * 2 + i) * 8 + srow;
      GLD16(Bp + (long)r * K + kt + scol, &Bs[(w * 2 + i) * 512 + l * 8]);
    }
    __syncthreads();
    short8 bfr[2][2];
#pragma unroll
    for (int ni = 0; ni < 2; ++ni)
#pragma unroll
      for (int ks = 0; ks < 2; ++ks)
        bfr[ni][ks] = *(const short8*)&Bs[(wn * 32 + ni * 16 + (l & 15)) * 64 +
                                          ((ks * 32 + (l >> 4) * 8) ^ rsw)];
#pragma unroll
    for (int mi = 0; mi < MI; ++mi) {
#pragma unroll
      for (int ks = 0; ks < 2; ++ks) {
        short8 afr = *(const short8*)&As[(wm * (MI * 16) + mi * 16 + (l & 15)) * 64 +
                                         ((ks * 32 + (l >> 4) * 8) ^ rsw)];
#pragma unroll
        for (int ni = 0; ni < 2; ++ni)
          acc[mi][ni] = __builtin_amdgcn_mfma_f32_16x16x32_bf16(afr, bfr[ni][ks], acc[mi][ni], 0, 0, 0);
      }
    }
    __syncthreads();
  }
}

// ---------------- k_gemm with fused epilogues (BM=128, BN=64) ---------------
enum { E_BF16 = 0, E_BIAS_RESB_BOTH, E_BIAS_GELU, E_BIAS_RES_F32,
       E_RANK1_GELU, E_GELU, E_RES_BOTH };

template <int K, int EPI>
__global__ void __launch_bounds__(256) k_gemm(
    const bf16* __restrict__ A, int lda, const bf16* __restrict__ Bt,
    long bstride, long zstride, int nOffZ,
    const float* __restrict__ bias, const float* __restrict__ res,
    const bf16* __restrict__ resB, const float* __restrict__ rank1,
    const float* __restrict__ pvec,
    float* __restrict__ outF, bf16* __restrict__ outB, int ldo) {
  __shared__ bf16 As[128 * 64];
  __shared__ bf16 Bs[64 * 64];
  const int tid = threadIdx.x;
  const int w = tid >> 6, l = tid & 63;
  const int m0 = blockIdx.y * 128, n0 = blockIdx.x * 64;
  const int bidx = m0 >> 11;
  const bf16* Bp = Bt + (long)bidx * bstride + (long)blockIdx.z * zstride + (long)n0 * K;
  f32x4 acc[4][2] = {};
  gemm_core<K, 4>(A + (long)m0 * lda, lda, Bp, As, Bs, acc);
  const int wm = w >> 1, wn = w & 1;
  const int zoff = blockIdx.z * nOffZ;
#pragma unroll
  for (int mi = 0; mi < 4; ++mi) {
#pragma unroll
    for (int ni = 0; ni < 2; ++ni) {
      const int bcol = n0 + wn * 32 + ni * 16 + (l & 15);
      const int ocol = bcol + zoff;
#pragma unroll
      for (int r = 0; r < 4; ++r) {
        const int row = m0 + wm * 64 + mi * 16 + (l >> 4) * 4 + r;
        float v = acc[mi][ni][r];
        const long oidx = (long)row * ldo + ocol;
        if constexpr (EPI == E_BF16) { outB[oidx] = __float2bfloat16(v); }
        else if constexpr (EPI == E_BIAS_RESB_BOTH) {
          v += bias[bcol] + __bfloat162float(resB[oidx]);
          outF[oidx] = v; outB[oidx] = __float2bfloat16(v);
        } else if constexpr (EPI == E_BIAS_GELU) {
          v = gelu_f(v + bias[bcol]); outB[oidx] = __float2bfloat16(v);
        } else if constexpr (EPI == E_BIAS_RES_F32) {
          v += bias[bcol] + res[oidx]; outF[oidx] = v;
        } else if constexpr (EPI == E_RANK1_GELU) {
          v = gelu_f(v + pvec[row] * rank1[bcol]); outB[oidx] = __float2bfloat16(v);
        } else if constexpr (EPI == E_GELU) {
          v = gelu_f(v); outB[oidx] = __float2bfloat16(v);
        } else {  // E_RES_BOTH
          v += res[oidx]; outF[oidx] = v; outB[oidx] = __float2bfloat16(v);
        }
      }
    }
  }
}

// ---------------- k_gemmT: GEMM with TRANSPOSED per-matrix output ----------
// (no fused stats: the round-5 version cost 20 VGPR -> occupancy 28%)
template <int K>
__global__ void __launch_bounds__(256) k_gemmT(
    const bf16* __restrict__ A, int lda, const bf16* __restrict__ Bt,
    bf16* __restrict__ T0, bf16* __restrict__ T1, int thresh, int matsPerB) {
  __shared__ union {
    struct { bf16 A[128 * 64]; bf16 B[64 * 64]; } ab;
    bf16 stage[64 * 132];  // stride 132: u32-packed writes conflict-free
  } sm;
  const int tid = threadIdx.x;
  const int w = tid >> 6, l = tid & 63;
  const int m0 = blockIdx.y * 128, n0 = blockIdx.x * 64;
  f32x4 acc[4][2] = {};
  gemm_core<K, 4>(A + (long)m0 * lda, lda, Bt + (long)n0 * K, sm.ab.A, sm.ab.B, acc);
  const int wm = w >> 1, wn = w & 1;
  // stage acc tile transposed into LDS (packed u32 writes)
#pragma unroll
  for (int mi = 0; mi < 4; ++mi)
#pragma unroll
    for (int ni = 0; ni < 2; ++ni) {
      int c = wn * 32 + ni * 16 + (l & 15);
      int row0 = wm * 64 + mi * 16 + (l >> 4) * 4;
#pragma unroll
      for (int q = 0; q < 2; ++q) {
        bf16 b0 = __float2bfloat16(acc[mi][ni][2 * q]);
        bf16 b1 = __float2bfloat16(acc[mi][ni][2 * q + 1]);
        unsigned u = (unsigned)*(unsigned short*)&b0 |
                     ((unsigned)*(unsigned short*)&b1 << 16);
        *(unsigned*)&sm.stage[c * 132 + row0 + 2 * q] = u;
      }
    }
  __syncthreads();
  const int b = m0 >> 11, nbase = m0 & 2047;
  const int part = (n0 >= thresh) ? 1 : 0;
  const int cT0 = n0 - (part ? thresh : 0);
  bf16* dst = (part ? T1 : T0) + ((long)(b * matsPerB + (cT0 >> 8))) * 524288
            + (long)(cT0 & 255) * 2048;
  const int c = tid >> 2, ns = tid & 3;
  bf16* rowp = dst + (long)c * 2048 + nbase + ns * 32;
#pragma unroll
  for (int j = 0; j < 4; ++j) {
    short4v lo = *(const short4v*)&sm.stage[c * 132 + ns * 32 + j * 8];
    short4v hi = *(const short4v*)&sm.stage[c * 132 + ns * 32 + j * 8 + 4];
    short8 v;
    v[0] = lo[0]; v[1] = lo[1]; v[2] = lo[2]; v[3] = lo[3];
    v[4] = hi[0]; v[5] = hi[1]; v[6] = hi[2]; v[7] = hi[3];
    *(short8*)&rowp[j * 8] = v;
  }
}

// ---------------- k_atb2: D[mat] = A[mat] * B[mat]^T (both [256][2048]) -----
template <int MI>
__global__ void __launch_bounds__(256) k_atb2(
    const bf16* __restrict__ A0, const bf16* __restrict__ B0,
    bf16* __restrict__ D0, float scale) {
  __shared__ bf16 As[MI * 32 * 64];
  __shared__ bf16 Bs[64 * 64];
  const int tid = threadIdx.x;
  const int w = tid >> 6, l = tid & 63;
  const int mat = blockIdx.z;
  const int m0 = blockIdx.y * (MI * 32), n0 = blockIdx.x * 64;
  const bf16* Ap = A0 + (long)mat * 524288 + (long)m0 * 2048;
  const bf16* Bp = B0 + (long)mat * 524288 + (long)n0 * 2048;
  f32x4 acc[MI][2] = {};
  gemm_core<2048, MI>(Ap, 2048, Bp, As, Bs, acc);
  bf16* D = D0 + (long)mat * 65536;
  const int wm = w >> 1, wn = w & 1;
#pragma unroll
  for (int mi = 0; mi < MI; ++mi)
#pragma unroll
    for (int ni = 0; ni < 2; ++ni) {
      int col = n0 + wn * 32 + ni * 16 + (l & 15);
#pragma unroll
      for (int r = 0; r < 4; ++r) {
        int row = m0 + wm * (MI * 16) + mi * 16 + (l >> 4) * 4 + r;
        D[(long)row * 256 + col] = __float2bfloat16(acc[mi][ni][r] * scale);
      }
    }
}

// ---------------- stats over channels of transposed tiles -------------------
// Kt[mat][256][2048]; per (mat, n): mean/rsqrt-var over 256 channels.
__global__ void __launch_bounds__(256) k_stats(
    const bf16* __restrict__ Kt, float* __restrict__ mu, float* __restrict__ rs) {
  const int mat = blockIdx.y;
  const int n = blockIdx.x * 256 + threadIdx.x;
  const bf16* base = Kt + (long)mat * 524288 + n;
  float s = 0.f, s2 = 0.f;
#pragma unroll 4
  for (int c = 0; c < 256; ++c) {
    float v = __bfloat162float(base[(long)c * 2048]);
    s += v; s2 += v * v;
  }
  float m = s * (1.f / 256.f);
  mu[(long)mat * 2048 + n] = m;
  rs[(long)mat * 2048 + n] = rsqrtf(fmaxf(s2 * (1.f / 256.f) - m * m, 0.f) + 1e-5f);
}

// norm + rotary in place on row pair (c, c+128) of Kt[mat]
__global__ void __launch_bounds__(256) k_rotnorm(
    bf16* __restrict__ Kt, const float* __restrict__ mu, const float* __restrict__ rs,
    const bf16* __restrict__ csT, int hshift) {
  const int mat = blockIdx.y, c = blockIdx.x;  // c in 0..127
  const int n = threadIdx.x * 8;
  const int b = mat >> hshift;
  bf16* r0 = Kt + (long)mat * 524288 + (long)c * 2048 + n;
  bf16* r1 = r0 + 128 * 2048;
  const long tok = (long)b * 2048 + n;
  const bf16* cop = csT + ((long)c * 2) * 16384 + tok;
  const bf16* sip = cop + 16384;
  const float* mup = mu + (long)mat * 2048 + n;
  const float* rsp = rs + (long)mat * 2048 + n;
  short8 v0 = *(const short8*)r0, v1 = *(const short8*)r1;
  short8 co8 = *(const short8*)cop, si8 = *(const short8*)sip;
  short8 o0, o1;
#pragma unroll
  for (int e = 0; e < 8; ++e) {
    float m = mup[e], r = rsp[e];
    float a = (__uint_as_float(((unsigned)(unsigned short)v0[e]) << 16) - m) * r;
    float bb = (__uint_as_float(((unsigned)(unsigned short)v1[e]) << 16) - m) * r;
    float co = __uint_as_float(((unsigned)(unsigned short)co8[e]) << 16);
    float si = __uint_as_float(((unsigned)(unsigned short)si8[e]) << 16);
    bf16 t0 = __float2bfloat16(a * co - bb * si);
    bf16 t1 = __float2bfloat16(bb * co + a * si);
    o0[e] = *(short*)&t0; o1[e] = *(short*)&t1;
  }
  *(short8*)r0 = o0;
  *(short8*)r1 = o1;
}

// token-major instnorm + rotary (4 tokens/block); in may equal out
__global__ void __launch_bounds__(256) k_rotq(
    const bf16* __restrict__ in, bf16* __restrict__ out, const bf16* __restrict__ cs) {
  __shared__ float xr[4][CC];
  __shared__ float mu[4], rs[4];
  int tid = threadIdx.x;
  long tok0 = (long)blockIdx.x * 4;
#pragma unroll
  for (int t = 0; t < 4; ++t) xr[t][tid] = __bfloat162float(in[(tok0 + t) * 256 + tid]);
  stats_rows<4>(xr, mu, rs, 1e-5f);
  int i = tid & 127;
#pragma unroll
  for (int t = 0; t < 4; ++t) {
    float co = __bfloat162float(cs[(tok0 + t) * 256 + i]);
    float si = __bfloat162float(cs[(tok0 + t) * 256 + 128 + i]);
    float n0 = (xr[t][tid] - mu[t]) * rs[t];
    float n1 = (xr[t][tid ^ 128] - mu[t]) * rs[t];
    float o = (tid < 128) ? (n0 * co - n1 * si) : (n0 * co + n1 * si);
    out[(tok0 + t) * 256 + tid] = __float2bfloat16(o);
  }
}

// ---------------- weight prep: 12 transposes, one kernel --------------------
struct WEnt { const float* s; bf16* d; int K; int N; int blk0; };
struct WTab { WEnt e[12]; };

__global__ void __launch_bounds__(256) k_wprep(WTab t) {
  int bid = blockIdx.x;
  int ei = 0;
#pragma unroll
  for (int i = 1; i < 12; ++i)
    if (bid >= t.e[i].blk0) ei = i;
  WEnt e = t.e[ei];
  int local = (bid - e.blk0) * 256 + threadIdx.x;
  if (local < e.K * e.N) {
    int n = local / e.K, k = local - n * e.K;
    e.d[local] = __float2bfloat16(e.s[(long)k * e.N + n]);
  }
}

// ---------------- k_pre: fourier feats, cos/sin tables, pvec, z->bf16, P1L --
__global__ void __launch_bounds__(256) k_pre(
    const float* __restrict__ pos, const float* __restrict__ Bf,
    const float* __restrict__ z, const float* __restrict__ P1,
    bf16* __restrict__ gf, bf16* __restrict__ cs, bf16* __restrict__ csT,
    float* __restrict__ pvec, bf16* __restrict__ zb, float* __restrict__ P1L) {
  int tid = threadIdx.x;
  long tok0 = (long)blockIdx.x * 4;
  if (blockIdx.x == 0) P1L[tid] = P1[65536 + tid];
  float p[4];
#pragma unroll
  for (int t = 0; t < 4; ++t) p[t] = pos[tok0 + t];
  if (tid < 4) pvec[tok0 + tid] = p[tid] * 0.0625f;
  float bfc = Bf[tid];
#pragma unroll
  for (int t = 0; t < 4; ++t) {
    float xp = TWO_PI * (p[t] * 0.0625f) * bfc;
    float s, c; sincosf(xp, &s, &c);
    gf[(tok0 + t) * 512 + tid] = __float2bfloat16(gelu_f(s));
    gf[(tok0 + t) * 512 + 256 + tid] = __float2bfloat16(gelu_f(c));
    zb[(tok0 + t) * 256 + tid] = __float2bfloat16(z[(tok0 + t) * 256 + tid]);
  }
  if (tid < 128) {
    float inv = exp2f(-((float)tid * (1.f / 128.f)) * LOG2_1E4);
#pragma unroll
    for (int t = 0; t < 4; ++t) {
      float fh = p[t] * 2048.f * inv;
      float s, c; sincosf(fh, &s, &c);
      bf16 cb = __float2bfloat16(c), sb = __float2bfloat16(s);
      cs[(tok0 + t) * 256 + tid] = cb;
      cs[(tok0 + t) * 256 + 128 + tid] = sb;
      csT[(long)(tid * 2) * 16384 + tok0 + t] = cb;
      csT[(long)(tid * 2 + 1) * 16384 + tok0 + t] = sb;
    }
  }
}

__global__ void __launch_bounds__(256) k_ln(
    const float* __restrict__ xin, const float* __restrict__ g,
    const float* __restrict__ b, bf16* __restrict__ hout) {
  __shared__ float xr[4][CC];
  __shared__ float mu[4], rs[4];
  int tid = threadIdx.x;
  long tok0 = (long)blockIdx.x * 4;
#pragma unroll
  for (int t = 0; t < 4; ++t) xr[t][tid] = xin[(tok0 + t) * 256 + tid];
  stats_rows<4>(xr, mu, rs, 1e-5f);
  float gv = g[tid], bv = b[tid];
#pragma unroll
  for (int t = 0; t < 4; ++t)
    hout[(tok0 + t) * 256 + tid] = __float2bfloat16((xr[t][tid] - mu[t]) * rs[t] * gv + bv);
}

__global__ void __launch_bounds__(256) k_final(
    const bf16* __restrict__ g2, const float* __restrict__ D3,
    const float* __restrict__ b3, float* __restrict__ u) {
  int w = threadIdx.x >> 6, l = threadIdx.x & 63;
  long tok = (long)blockIdx.x * 4 + w;
  float s = __bfloat162float(g2[tok * 128 + l]) * D3[l]
          + __bfloat162float(g2[tok * 128 + 64 + l]) * D3[64 + l];
#pragma unroll
  for (int o = 32; o; o >>= 1) s += __shfl_down(s, o);
  if (l == 0) u[tok] = s + b3[0];
}

// ======================= launcher ===========================================
extern "C" void kernel_launch(void* const* d_in, const int* in_sizes, int n_in,
                              void* d_out, int out_size, void* d_ws, size_t ws_size,
                              hipStream_t stream) {
  const float* z    = (const float*)d_in[0];
  const float* pos  = (const float*)d_in[1];
  const float* Bf   = (const float*)d_in[2];
  const float* Wc   = (const float*)d_in[3];
  const float* Wkv  = (const float*)d_in[4];
  const float* Woca = (const float*)d_in[5];
  const float* boca = (const float*)d_in[6];
  const float* Wf1  = (const float*)d_in[7];
  const float* bf1  = (const float*)d_in[8];
  const float* Wf2  = (const float*)d_in[9];
  const float* bf2  = (const float*)d_in[10];
  const float* lng  = (const float*)d_in[11];
  const float* lnb  = (const float*)d_in[12];
  const float* P1   = (const float*)d_in[13];
  const float* P2   = (const float*)d_in[14];
  const float* P3   = (const float*)d_in[15];
  const float* Wqkv = (const float*)d_in[16];
  const float* Woda = (const float*)d_in[17];
  const float* boda = (const float*)d_in[18];
  const float* ln2g = (const float*)d_in[19];
  const float* ln2b = (const float*)d_in[20];
  const float* D1   = (const float*)d_in[21];
  const float* D2   = (const float*)d_in[22];
  const float* D3   = (const float*)d_in[23];
  const float* b3   = (const float*)d_in[24];

  float* u  = (float*)d_out;
  float* zp = (float*)d_out + NTOK;

  const long MB = 1048576L;
  char* ws = (char*)d_ws;
  // ---- static region [0, 24MB) ----
  bf16*  cs   = (bf16*)(ws);                    // 8 MB token-major cos/sin
  bf16*  csT  = (bf16*)(ws + 8 * MB);           // 8 MB [128][2][16384]
  float* pvec = (float*)(ws + 16 * MB);         // 64 KB
  long wo = 16 * MB + 65536;
  bf16* WcT   = (bf16*)(ws + wo);               wo += 262144;
  bf16* WkvT  = (bf16*)(ws + wo);               wo += 1048576;
  bf16* WocaT = (bf16*)(ws + wo);               wo += 524288;
  bf16* Wf1T  = (bf16*)(ws + wo);               wo += 131072;
  bf16* Wf2T  = (bf16*)(ws + wo);               wo += 131072;
  bf16* P1T   = (bf16*)(ws + wo);               wo += 131072;
  bf16* P2T   = (bf16*)(ws + wo);               wo += 131072;
  bf16* P3T   = (bf16*)(ws + wo);               wo += 131072;
  bf16* WqkvT = (bf16*)(ws + wo);               wo += 393216;
  bf16* WodaT = (bf16*)(ws + wo);               wo += 131072;
  bf16* D1T   = (bf16*)(ws + wo);               wo += 131072;
  bf16* D2T   = (bf16*)(ws + wo);               wo += 65536;
  float* P1L  = (float*)(ws + wo);              wo += 1024;
  float* muB  = (float*)(ws + wo);              wo += 32 * 2048 * 4;  // mu [32][2048]
  float* rsB  = (float*)(ws + wo);              wo += 32 * 2048 * 4;  // rs
  // ---- dynamic arena at 24 MB (lifetime-audited, W=writer step R=last read) ----
  char* AR = ws + 24 * MB;
  bf16*  xb     = (bf16*)(AR);             // [0,8)   W3  -> R9
  bf16*  zb     = (bf16*)(AR + 8 * MB);    // [8,16)  W2  -> R4
  bf16*  gf     = (bf16*)(AR + 48 * MB);   // [48,64) W2  -> R3 (Vt overwrites after)
  bf16*  Kt     = (bf16*)(AR + 16 * MB);   // [16,48) W4/5 -> R6
  bf16*  Vt     = (bf16*)(AR + 48 * MB);   // [48,80) W4  -> R6
  bf16*  dotsT  = (bf16*)(AR + 8 * MB);    // [8,12)  W6  -> R8
  bf16*  qrot   = (bf16*)(AR + 16 * MB);   // [16,24) W7  -> R8
  bf16*  merged = (bf16*)(AR + 24 * MB);   // [24,56) W8  -> R9
  float* x2     = (float*)(AR + 56 * MB);  // [56,72) W9  -> R11 (f32)
  bf16*  x2b    = (bf16*)(AR + 72 * MB);   // [72,80) W9  -> R10
  bf16*  t1     = (bf16*)(AR + 8 * MB);    // [8,16)  W10 -> R11
  float* x3     = (float*)(AR + 16 * MB);  // [16,32) W11 -> R15 (f32)
  bf16*  h      = (bf16*)(AR + 32 * MB);   // [32,40) W12 -> R13
  bf16*  p1o    = (bf16*)(AR + 40 * MB);   // [40,48) W13 -> R14
  bf16*  p2o    = (bf16*)(AR + 48 * MB);   // [48,56) W14 -> R15
  bf16*  zpb    = (bf16*)(AR + 56 * MB);   // [56,64) W15 -> R17
  bf16*  q2b    = (bf16*)(AR + 64 * MB);   // [64,72) W16/18 -> R21
  bf16*  k2t    = (bf16*)(AR + 72 * MB);   // [72,80) W17/19 -> R20
  bf16*  v2t    = (bf16*)(AR + 8 * MB);    // [8,16)  W17 -> R20
  bf16*  dots2T = (bf16*)(AR + 16 * MB);   // [16,17) W20 -> R21
  bf16*  att    = (bf16*)(AR + 24 * MB);   // [24,32) W21 -> R22
  float* zd     = (float*)(AR + 32 * MB);  // [32,48) W22 -> R23 (f32)
  bf16*  h2     = (bf16*)(AR + 8 * MB);    // [8,16)  W23 -> R24
  bf16*  g1     = (bf16*)(AR + 16 * MB);   // [16,24) W24 -> R25
  bf16*  g2     = (bf16*)(AR + 24 * MB);   // [24,28) W25 -> R26

  // ---- weight-prep table ----
  WTab tab;
  int nb = 0;
  auto add = [&](int i, const float* s, bf16* d, int K_, int N_) {
    tab.e[i].s = s; tab.e[i].d = d; tab.e[i].K = K_; tab.e[i].N = N_;
    tab.e[i].blk0 = nb; nb += (K_ * N_) / 256;
  };
  add(0, Wc, WcT, 512, 256);
  add(1, Wkv, WkvT, 256, 2048);
  add(2, Woca, WocaT, 1024, 256);
  add(3, Wf1, Wf1T, 256, 256);
  add(4, Wf2, Wf2T, 256, 256);
  add(5, P1, P1T, 256, 256);
  add(6, P2, P2T, 256, 256);
  add(7, P3, P3T, 256, 256);
  add(8, Wqkv, WqkvT, 256, 768);
  add(9, Woda, WodaT, 256, 256);
  add(10, D1, D1T, 256, 256);
  add(11, D2, D2T, 256, 128);
  k_wprep<<<nb, 256, 0, stream>>>(tab);

  k_pre<<<NTOK / 4, 256, 0, stream>>>(pos, Bf, z, P1, gf, cs, csT, pvec, zb, P1L);
  // x = gelu(fourier) @ WcT
  k_gemm<512, E_BF16><<<dim3(4, 128, 1), 256, 0, stream>>>(
      gf, 512, WcT, 0, 0, 0, nullptr, nullptr, nullptr, nullptr, nullptr, nullptr, xb, 256);
  // Kt/Vt = (z @ Wkv) transposed per (b,h)
  k_gemmT<256><<<dim3(32, 128), 256, 0, stream>>>(zb, 256, WkvT, Kt, Vt, 1024, 4);
  k_stats<<<dim3(8, 32), 256, 0, stream>>>(Kt, muB, rsB);
  k_rotnorm<<<dim3(128, 32), 256, 0, stream>>>(Kt, muB, rsB, csT, 2);
  // dotsT[mat] = Vt[mat] * Kt[mat]^T / n
  k_atb2<4><<<dim3(4, 2, 32), 256, 0, stream>>>(Vt, Kt, dotsT, 1.f / 2048.f);
  k_rotq<<<NTOK / 4, 256, 0, stream>>>(xb, qrot, cs);
  // merged[:, h*256:] = qrot @ dotsT[b,h]
  k_gemm<256, E_BF16><<<dim3(4, 128, 4), 256, 0, stream>>>(
      qrot, 256, dotsT, 262144L, 65536L, 256, nullptr, nullptr, nullptr, nullptr, nullptr,
      nullptr, merged, 1024);
  // x2 = merged @ WocaT + boca + x
  k_gemm<1024, E_BIAS_RESB_BOTH><<<dim3(4, 128, 1), 256, 0, stream>>>(
      merged, 1024, WocaT, 0, 0, 0, boca, nullptr, xb, nullptr, nullptr, x2, x2b, 256);
  // t1 = gelu(x2 @ Wf1 + bf1)
  k_gemm<256, E_BIAS_GELU><<<dim3(4, 128, 1), 256, 0, stream>>>(
      x2b, 256, Wf1T, 0, 0, 0, bf1, nullptr, nullptr, nullptr, nullptr, nullptr, t1, 256);
  // x3 = t1 @ Wf2 + bf2 + x2
  k_gemm<256, E_BIAS_RES_F32><<<dim3(4, 128, 1), 256, 0, stream>>>(
      t1, 256, Wf2T, 0, 0, 0, bf2, x2, nullptr, nullptr, nullptr, x3, nullptr, 256);
  k_ln<<<NTOK / 4, 256, 0, stream>>>(x3, lng, lnb, h);
  // p1o = gelu(h @ P1T + pvec*P1L)
  k_gemm<256, E_RANK1_GELU><<<dim3(4, 128, 1), 256, 0, stream>>>(
      h, 256, P1T, 0, 0, 0, nullptr, nullptr, nullptr, P1L, pvec, nullptr, p1o, 256);
  k_gemm<256, E_GELU><<<dim3(4, 128, 1), 256, 0, stream>>>(
      p1o, 256, P2T, 0, 0, 0, nullptr, nullptr, nullptr, nullptr, nullptr, nullptr, p2o, 256);
  // zp = p2o @ P3T + x3
  k_gemm<256, E_RES_BOTH><<<dim3(4, 128, 1), 256, 0, stream>>>(
      p2o, 256, P3T, 0, 0, 0, nullptr, x3, nullptr, nullptr, nullptr, zp, zpb, 256);
  // q2 token-major; k2/v2 transposed
  k_gemm<256, E_BF16><<<dim3(4, 128, 1), 256, 0, stream>>>(
      zpb, 256, WqkvT, 0, 0, 0, nullptr, nullptr, nullptr, nullptr, nullptr, nullptr, q2b, 256);
  k_gemmT<256><<<dim3(8, 128), 256, 0, stream>>>(zpb, 256, WqkvT + 65536, k2t, v2t, 256, 1);
  k_rotq<<<NTOK / 4, 256, 0, stream>>>(q2b, q2b, cs);
  k_stats<<<dim3(8, 8), 256, 0, stream>>>(k2t, muB, rsB);
  k_rotnorm<<<dim3(128, 8), 256, 0, stream>>>(k2t, muB, rsB, csT, 0);
  k_atb2<2><<<dim3(4, 4, 8), 256, 0, stream>>>(v2t, k2t, dots2T, 1.f / 2048.f);
  // att = q2' @ dots2T[b]
  k_gemm<256, E_BF16><<<dim3(4, 128, 1), 256, 0, stream>>>(
      q2b, 256, dots2T, 65536L, 0, 0, nullptr, nullptr, nullptr, nullptr, nullptr,
      nullptr, att, 256);
  // zd = att @ WodaT + boda + zp
  k_gemm<256, E_BIAS_RES_F32><<<dim3(4, 128, 1), 256, 0, stream>>>(
      att, 256, WodaT, 0, 0, 0, boda, zp, nullptr, nullptr, nullptr, zd, nullptr, 256);
  k_ln<<<NTOK / 4, 256, 0, stream>>>(zd, ln2g, ln2b, h2);
  k_gemm<256, E_GELU><<<dim3(4, 128, 1), 256, 0, stream>>>(
      h2, 256, D1T, 0, 0, 0, nullptr, nullptr, nullptr, nullptr, nullptr, nullptr, g1, 256);
  k_gemm<256, E_GELU><<<dim3(2, 128, 1), 256, 0, stream>>>(
      g1, 256, D2T, 0, 0, 0, nullptr, nullptr, nullptr, nullptr, nullptr, nullptr, g2, 128);
  k_final<<<NTOK / 4, 256, 0, stream>>>(g2, D3, b3, u);
}

// Round 7
// 464.861 us; speedup vs baseline: 3.4396x; 1.0254x over previous
//
#include <hip/hip_runtime.h>
#include <hip/hip_bf16.h>

using bf16 = __hip_bfloat16;
typedef __attribute__((ext_vector_type(8))) short short8;
typedef __attribute__((ext_vector_type(4))) short short4v;
typedef __attribute__((ext_vector_type(4))) float f32x4;

constexpr int BB = 8;
constexpr int NN = 2048;
constexpr int CC = 256;
constexpr int NTOK = BB * NN;  // 16384
constexpr float TWO_PI = 6.283185307179586f;
constexpr float LOG2_1E4 = 13.287712379549449f;

__device__ __forceinline__ float gelu_f(float x) {
  return 0.5f * x * (1.0f + erff(x * 0.7071067811865475f));
}

template <int T>
__device__ __forceinline__ void stats_rows(const float (*buf)[CC], float* mu, float* rs, float eps) {
  __syncthreads();
  int w = threadIdx.x >> 6, l = threadIdx.x & 63;
  if (w < T) {
    float s = 0.f, s2 = 0.f;
#pragma unroll
    for (int j = 0; j < 4; ++j) { float v = buf[w][l + 64 * j]; s += v; s2 += v * v; }
#pragma unroll
    for (int o = 32; o; o >>= 1) { s += __shfl_down(s, o); s2 += __shfl_down(s2, o); }
    if (l == 0) {
      float m = s * (1.f / 256.f);
      float var = fmaxf(s2 * (1.f / 256.f) - m * m, 0.f);
      mu[w] = m; rs[w] = rsqrtf(var + eps);
    }
  }
  __syncthreads();
}

// ---------------- shared MFMA GEMM core (2-phase, double-buffered) ----------
// T2 XOR-swizzled LDS (source-side pre-swizzle for global_load_lds + same XOR
// on ds_read). T3 minimum 2-phase: stage(t+1) issued before compute(t); raw
// s_barrier + manual vmcnt(0) keep the prefetch in flight across compute.
#define GLD16(src, dst)                                                       \
  __builtin_amdgcn_global_load_lds(                                           \
      (const __attribute__((address_space(1))) void*)(src),                   \
      (__attribute__((address_space(3))) void*)(dst), 16, 0, 0)

template <int K, int MI>
__device__ __forceinline__ void gemm_core(
    const bf16* __restrict__ Ap, int lda, const bf16* __restrict__ Bp,
    bf16 (&As)[2][MI * 32 * 64], bf16 (&Bs)[2][64 * 64], f32x4 (&acc)[MI][2]) {
  const int tid = threadIdx.x;
  const int w = tid >> 6, l = tid & 63;
  const int srow = l >> 3;
  const int scol = ((l & 7) ^ srow) * 8;  // swizzled source col
  const int rsw = (l & 7) * 8;            // read-side XOR (row&7 == l&7)
  const int wm = w >> 1, wn = w & 1;

  auto stage_tile = [&](int buf, int kt) {
#pragma unroll
    for (int i = 0; i < MI; ++i) {
      int r = (w * MI + i) * 8 + srow;
      GLD16(Ap + (long)r * lda + kt + scol, &As[buf][(w * MI + i) * 512 + l * 8]);
    }
#pragma unroll
    for (int i = 0; i < 2; ++i) {
      int r = (w * 2 + i) * 8 + srow;
      GLD16(Bp + (long)r * K + kt + scol, &Bs[buf][(w * 2 + i) * 512 + l * 8]);
    }
  };

  stage_tile(0, 0);
  asm volatile("s_waitcnt vmcnt(0)" ::: "memory");
  __builtin_amdgcn_s_barrier();

  int cur = 0;
  for (int kt = 0; kt < K; kt += 64) {
    const bool more = (kt + 64 < K);
    if (more) stage_tile(cur ^ 1, kt + 64);   // prefetch next tile
    short8 bfr[2][2];
#pragma unroll
    for (int ni = 0; ni < 2; ++ni)
#pragma unroll
      for (int ks = 0; ks < 2; ++ks)
        bfr[ni][ks] = *(const short8*)&Bs[cur][(wn * 32 + ni * 16 + (l & 15)) * 64 +
                                               ((ks * 32 + (l >> 4) * 8) ^ rsw)];
#pragma unroll
    for (int mi = 0; mi < MI; ++mi) {
#pragma unroll
      for (int ks = 0; ks < 2; ++ks) {
        short8 afr = *(const short8*)&As[cur][(wm * (MI * 16) + mi * 16 + (l & 15)) * 64 +
                                              ((ks * 32 + (l >> 4) * 8) ^ rsw)];
#pragma unroll
        for (int ni = 0; ni < 2; ++ni)
          acc[mi][ni] = __builtin_amdgcn_mfma_f32_16x16x32_bf16(afr, bfr[ni][ks], acc[mi][ni], 0, 0, 0);
      }
    }
    if (more) asm volatile("s_waitcnt vmcnt(0)" ::: "memory");
    __builtin_amdgcn_s_barrier();
    cur ^= 1;
  }
}

// ---------------- k_gemm with fused epilogues (BM=128, BN=64) ---------------
enum { E_BF16 = 0, E_BIAS_RESB_BOTH, E_BIAS_GELU, E_BIAS_RES_F32,
       E_RANK1_GELU, E_GELU, E_RES_BOTH };

template <int K, int EPI>
__global__ void __launch_bounds__(256) k_gemm(
    const bf16* __restrict__ A, int lda, const bf16* __restrict__ Bt,
    long bstride, long zstride, int nOffZ,
    const float* __restrict__ bias, const float* __restrict__ res,
    const bf16* __restrict__ resB, const float* __restrict__ rank1,
    const float* __restrict__ pvec,
    float* __restrict__ outF, bf16* __restrict__ outB, int ldo) {
  __shared__ bf16 As[2][128 * 64];
  __shared__ bf16 Bs[2][64 * 64];
  const int tid = threadIdx.x;
  const int w = tid >> 6, l = tid & 63;
  const int m0 = blockIdx.y * 128, n0 = blockIdx.x * 64;
  const int bidx = m0 >> 11;
  const bf16* Bp = Bt + (long)bidx * bstride + (long)blockIdx.z * zstride + (long)n0 * K;
  f32x4 acc[4][2] = {};
  gemm_core<K, 4>(A + (long)m0 * lda, lda, Bp, As, Bs, acc);
  const int wm = w >> 1, wn = w & 1;
  const int zoff = blockIdx.z * nOffZ;
#pragma unroll
  for (int mi = 0; mi < 4; ++mi) {
#pragma unroll
    for (int ni = 0; ni < 2; ++ni) {
      const int bcol = n0 + wn * 32 + ni * 16 + (l & 15);
      const int ocol = bcol + zoff;
#pragma unroll
      for (int r = 0; r < 4; ++r) {
        const int row = m0 + wm * 64 + mi * 16 + (l >> 4) * 4 + r;
        float v = acc[mi][ni][r];
        const long oidx = (long)row * ldo + ocol;
        if constexpr (EPI == E_BF16) { outB[oidx] = __float2bfloat16(v); }
        else if constexpr (EPI == E_BIAS_RESB_BOTH) {
          v += bias[bcol] + __bfloat162float(resB[oidx]);
          outF[oidx] = v; outB[oidx] = __float2bfloat16(v);
        } else if constexpr (EPI == E_BIAS_GELU) {
          v = gelu_f(v + bias[bcol]); outB[oidx] = __float2bfloat16(v);
        } else if constexpr (EPI == E_BIAS_RES_F32) {
          v += bias[bcol] + res[oidx]; outF[oidx] = v;
        } else if constexpr (EPI == E_RANK1_GELU) {
          v = gelu_f(v + pvec[row] * rank1[bcol]); outB[oidx] = __float2bfloat16(v);
        } else if constexpr (EPI == E_GELU) {
          v = gelu_f(v); outB[oidx] = __float2bfloat16(v);
        } else {  // E_RES_BOTH
          v += res[oidx]; outF[oidx] = v; outB[oidx] = __float2bfloat16(v);
        }
      }
    }
  }
}

// ---------------- k_gemmT: GEMM with TRANSPOSED per-matrix output ----------
template <int K>
__global__ void __launch_bounds__(256) k_gemmT(
    const bf16* __restrict__ A, int lda, const bf16* __restrict__ Bt,
    bf16* __restrict__ T0, bf16* __restrict__ T1, int thresh, int matsPerB) {
  __shared__ union {
    struct { bf16 A[2][128 * 64]; bf16 B[2][64 * 64]; } ab;
    bf16 stage[64 * 132];  // stride 132: u32-packed writes conflict-free
  } sm;
  const int tid = threadIdx.x;
  const int w = tid >> 6, l = tid & 63;
  const int m0 = blockIdx.y * 128, n0 = blockIdx.x * 64;
  f32x4 acc[4][2] = {};
  gemm_core<K, 4>(A + (long)m0 * lda, lda, Bt + (long)n0 * K, sm.ab.A, sm.ab.B, acc);
  const int wm = w >> 1, wn = w & 1;
  // stage acc tile transposed into LDS (packed u32 writes)
#pragma unroll
  for (int mi = 0; mi < 4; ++mi)
#pragma unroll
    for (int ni = 0; ni < 2; ++ni) {
      int c = wn * 32 + ni * 16 + (l & 15);
      int row0 = wm * 64 + mi * 16 + (l >> 4) * 4;
#pragma unroll
      for (int q = 0; q < 2; ++q) {
        bf16 b0 = __float2bfloat16(acc[mi][ni][2 * q]);
        bf16 b1 = __float2bfloat16(acc[mi][ni][2 * q + 1]);
        unsigned u = (unsigned)*(unsigned short*)&b0 |
                     ((unsigned)*(unsigned short*)&b1 << 16);
        *(unsigned*)&sm.stage[c * 132 + row0 + 2 * q] = u;
      }
    }
  __syncthreads();
  const int b = m0 >> 11, nbase = m0 & 2047;
  const int part = (n0 >= thresh) ? 1 : 0;
  const int cT0 = n0 - (part ? thresh : 0);
  bf16* dst = (part ? T1 : T0) + ((long)(b * matsPerB + (cT0 >> 8))) * 524288
            + (long)(cT0 & 255) * 2048;
  const int c = tid >> 2, ns = tid & 3;
  bf16* rowp = dst + (long)c * 2048 + nbase + ns * 32;
#pragma unroll
  for (int j = 0; j < 4; ++j) {
    short4v lo = *(const short4v*)&sm.stage[c * 132 + ns * 32 + j * 8];
    short4v hi = *(const short4v*)&sm.stage[c * 132 + ns * 32 + j * 8 + 4];
    short8 v;
    v[0] = lo[0]; v[1] = lo[1]; v[2] = lo[2]; v[3] = lo[3];
    v[4] = hi[0]; v[5] = hi[1]; v[6] = hi[2]; v[7] = hi[3];
    *(short8*)&rowp[j * 8] = v;
  }
}

// ---------------- k_atb2: D[mat] = A[mat] * B[mat]^T (both [256][2048]) -----
template <int MI>
__global__ void __launch_bounds__(256) k_atb2(
    const bf16* __restrict__ A0, const bf16* __restrict__ B0,
    bf16* __restrict__ D0, float scale) {
  __shared__ bf16 As[2][MI * 32 * 64];
  __shared__ bf16 Bs[2][64 * 64];
  const int tid = threadIdx.x;
  const int w = tid >> 6, l = tid & 63;
  const int mat = blockIdx.z;
  const int m0 = blockIdx.y * (MI * 32), n0 = blockIdx.x * 64;
  const bf16* Ap = A0 + (long)mat * 524288 + (long)m0 * 2048;
  const bf16* Bp = B0 + (long)mat * 524288 + (long)n0 * 2048;
  f32x4 acc[MI][2] = {};
  gemm_core<2048, MI>(Ap, 2048, Bp, As, Bs, acc);
  bf16* D = D0 + (long)mat * 65536;
  const int wm = w >> 1, wn = w & 1;
#pragma unroll
  for (int mi = 0; mi < MI; ++mi)
#pragma unroll
    for (int ni = 0; ni < 2; ++ni) {
      int col = n0 + wn * 32 + ni * 16 + (l & 15);
#pragma unroll
      for (int r = 0; r < 4; ++r) {
        int row = m0 + wm * (MI * 16) + mi * 16 + (l >> 4) * 4 + r;
        D[(long)row * 256 + col] = __float2bfloat16(acc[mi][ni][r] * scale);
      }
    }
}

// ---------------- stats over channels of transposed tiles -------------------
__global__ void __launch_bounds__(256) k_stats(
    const bf16* __restrict__ Kt, float* __restrict__ mu, float* __restrict__ rs) {
  const int mat = blockIdx.y;
  const int n = blockIdx.x * 256 + threadIdx.x;
  const bf16* base = Kt + (long)mat * 524288 + n;
  float s = 0.f, s2 = 0.f;
#pragma unroll 4
  for (int c = 0; c < 256; ++c) {
    float v = __bfloat162float(base[(long)c * 2048]);
    s += v; s2 += v * v;
  }
  float m = s * (1.f / 256.f);
  mu[(long)mat * 2048 + n] = m;
  rs[(long)mat * 2048 + n] = rsqrtf(fmaxf(s2 * (1.f / 256.f) - m * m, 0.f) + 1e-5f);
}

// norm + rotary in place on row pair (c, c+128) of Kt[mat]
__global__ void __launch_bounds__(256) k_rotnorm(
    bf16* __restrict__ Kt, const float* __restrict__ mu, const float* __restrict__ rs,
    const bf16* __restrict__ csT, int hshift) {
  const int mat = blockIdx.y, c = blockIdx.x;  // c in 0..127
  const int n = threadIdx.x * 8;
  const int b = mat >> hshift;
  bf16* r0 = Kt + (long)mat * 524288 + (long)c * 2048 + n;
  bf16* r1 = r0 + 128 * 2048;
  const long tok = (long)b * 2048 + n;
  const bf16* cop = csT + ((long)c * 2) * 16384 + tok;
  const bf16* sip = cop + 16384;
  const float* mup = mu + (long)mat * 2048 + n;
  const float* rsp = rs + (long)mat * 2048 + n;
  short8 v0 = *(const short8*)r0, v1 = *(const short8*)r1;
  short8 co8 = *(const short8*)cop, si8 = *(const short8*)sip;
  short8 o0, o1;
#pragma unroll
  for (int e = 0; e < 8; ++e) {
    float m = mup[e], r = rsp[e];
    float a = (__uint_as_float(((unsigned)(unsigned short)v0[e]) << 16) - m) * r;
    float bb = (__uint_as_float(((unsigned)(unsigned short)v1[e]) << 16) - m) * r;
    float co = __uint_as_float(((unsigned)(unsigned short)co8[e]) << 16);
    float si = __uint_as_float(((unsigned)(unsigned short)si8[e]) << 16);
    bf16 t0 = __float2bfloat16(a * co - bb * si);
    bf16 t1 = __float2bfloat16(bb * co + a * si);
    o0[e] = *(short*)&t0; o1[e] = *(short*)&t1;
  }
  *(short8*)r0 = o0;
  *(short8*)r1 = o1;
}

// token-major instnorm + rotary (4 tokens/block); in may equal out
__global__ void __launch_bounds__(256) k_rotq(
    const bf16* __restrict__ in, bf16* __restrict__ out, const bf16* __restrict__ cs) {
  __shared__ float xr[4][CC];
  __shared__ float mu[4], rs[4];
  int tid = threadIdx.x;
  long tok0 = (long)blockIdx.x * 4;
#pragma unroll
  for (int t = 0; t < 4; ++t) xr[t][tid] = __bfloat162float(in[(tok0 + t) * 256 + tid]);
  stats_rows<4>(xr, mu, rs, 1e-5f);
  int i = tid & 127;
#pragma unroll
  for (int t = 0; t < 4; ++t) {
    float co = __bfloat162float(cs[(tok0 + t) * 256 + i]);
    float si = __bfloat162float(cs[(tok0 + t) * 256 + 128 + i]);
    float n0 = (xr[t][tid] - mu[t]) * rs[t];
    float n1 = (xr[t][tid ^ 128] - mu[t]) * rs[t];
    float o = (tid < 128) ? (n0 * co - n1 * si) : (n0 * co + n1 * si);
    out[(tok0 + t) * 256 + tid] = __float2bfloat16(o);
  }
}

// ---------------- weight prep: 12 transposes, one kernel --------------------
struct WEnt { const float* s; bf16* d; int K; int N; int blk0; };
struct WTab { WEnt e[12]; };

__global__ void __launch_bounds__(256) k_wprep(WTab t) {
  int bid = blockIdx.x;
  int ei = 0;
#pragma unroll
  for (int i = 1; i < 12; ++i)
    if (bid >= t.e[i].blk0) ei = i;
  WEnt e = t.e[ei];
  int local = (bid - e.blk0) * 256 + threadIdx.x;
  if (local < e.K * e.N) {
    int n = local / e.K, k = local - n * e.K;
    e.d[local] = __float2bfloat16(e.s[(long)k * e.N + n]);
  }
}

// ---------------- k_csT: transposed cos/sin table, COALESCED writes ---------
// csT[c*2][n]=cos, csT[c*2+1][n]=sin for freq c, token n. Row-major writes.
__global__ void __launch_bounds__(256) k_csT(
    const float* __restrict__ pos, bf16* __restrict__ csT) {
  const int c = blockIdx.y;                       // 0..127
  const int n = blockIdx.x * 256 + threadIdx.x;   // token
  float inv = exp2f(-((float)c * (1.f / 128.f)) * LOG2_1E4);
  float fh = pos[n] * 2048.f * inv;
  float s, co; sincosf(fh, &s, &co);
  csT[(long)(c * 2) * 16384 + n] = __float2bfloat16(co);
  csT[(long)(c * 2 + 1) * 16384 + n] = __float2bfloat16(s);
}

// ---------------- k_pre: fourier feats, token-major cos/sin, pvec, z->bf16 --
__global__ void __launch_bounds__(256) k_pre(
    const float* __restrict__ pos, const float* __restrict__ Bf,
    const float* __restrict__ z, const float* __restrict__ P1,
    bf16* __restrict__ gf, bf16* __restrict__ cs,
    float* __restrict__ pvec, bf16* __restrict__ zb, float* __restrict__ P1L) {
  int tid = threadIdx.x;
  long tok0 = (long)blockIdx.x * 4;
  if (blockIdx.x == 0) P1L[tid] = P1[65536 + tid];
  float p[4];
#pragma unroll
  for (int t = 0; t < 4; ++t) p[t] = pos[tok0 + t];
  if (tid < 4) pvec[tok0 + tid] = p[tid] * 0.0625f;
  float bfc = Bf[tid];
#pragma unroll
  for (int t = 0; t < 4; ++t) {
    float xp = TWO_PI * (p[t] * 0.0625f) * bfc;
    float s, c; sincosf(xp, &s, &c);
    gf[(tok0 + t) * 512 + tid] = __float2bfloat16(gelu_f(s));
    gf[(tok0 + t) * 512 + 256 + tid] = __float2bfloat16(gelu_f(c));
    zb[(tok0 + t) * 256 + tid] = __float2bfloat16(z[(tok0 + t) * 256 + tid]);
  }
  if (tid < 128) {
    float inv = exp2f(-((float)tid * (1.f / 128.f)) * LOG2_1E4);
#pragma unroll
    for (int t = 0; t < 4; ++t) {
      float fh = p[t] * 2048.f * inv;
      float s, c; sincosf(fh, &s, &c);
      cs[(tok0 + t) * 256 + tid] = __float2bfloat16(c);
      cs[(tok0 + t) * 256 + 128 + tid] = __float2bfloat16(s);
    }
  }
}

__global__ void __launch_bounds__(256) k_ln(
    const float* __restrict__ xin, const float* __restrict__ g,
    const float* __restrict__ b, bf16* __restrict__ hout) {
  __shared__ float xr[4][CC];
  __shared__ float mu[4], rs[4];
  int tid = threadIdx.x;
  long tok0 = (long)blockIdx.x * 4;
#pragma unroll
  for (int t = 0; t < 4; ++t) xr[t][tid] = xin[(tok0 + t) * 256 + tid];
  stats_rows<4>(xr, mu, rs, 1e-5f);
  float gv = g[tid], bv = b[tid];
#pragma unroll
  for (int t = 0; t < 4; ++t)
    hout[(tok0 + t) * 256 + tid] = __float2bfloat16((xr[t][tid] - mu[t]) * rs[t] * gv + bv);
}

__global__ void __launch_bounds__(256) k_final(
    const bf16* __restrict__ g2, const float* __restrict__ D3,
    const float* __restrict__ b3, float* __restrict__ u) {
  int w = threadIdx.x >> 6, l = threadIdx.x & 63;
  long tok = (long)blockIdx.x * 4 + w;
  float s = __bfloat162float(g2[tok * 128 + l]) * D3[l]
          + __bfloat162float(g2[tok * 128 + 64 + l]) * D3[64 + l];
#pragma unroll
  for (int o = 32; o; o >>= 1) s += __shfl_down(s, o);
  if (l == 0) u[tok] = s + b3[0];
}

// ======================= launcher ===========================================
extern "C" void kernel_launch(void* const* d_in, const int* in_sizes, int n_in,
                              void* d_out, int out_size, void* d_ws, size_t ws_size,
                              hipStream_t stream) {
  const float* z    = (const float*)d_in[0];
  const float* pos  = (const float*)d_in[1];
  const float* Bf   = (const float*)d_in[2];
  const float* Wc   = (const float*)d_in[3];
  const float* Wkv  = (const float*)d_in[4];
  const float* Woca = (const float*)d_in[5];
  const float* boca = (const float*)d_in[6];
  const float* Wf1  = (const float*)d_in[7];
  const float* bf1  = (const float*)d_in[8];
  const float* Wf2  = (const float*)d_in[9];
  const float* bf2  = (const float*)d_in[10];
  const float* lng  = (const float*)d_in[11];
  const float* lnb  = (const float*)d_in[12];
  const float* P1   = (const float*)d_in[13];
  const float* P2   = (const float*)d_in[14];
  const float* P3   = (const float*)d_in[15];
  const float* Wqkv = (const float*)d_in[16];
  const float* Woda = (const float*)d_in[17];
  const float* boda = (const float*)d_in[18];
  const float* ln2g = (const float*)d_in[19];
  const float* ln2b = (const float*)d_in[20];
  const float* D1   = (const float*)d_in[21];
  const float* D2   = (const float*)d_in[22];
  const float* D3   = (const float*)d_in[23];
  const float* b3   = (const float*)d_in[24];

  float* u  = (float*)d_out;
  float* zp = (float*)d_out + NTOK;

  const long MB = 1048576L;
  char* ws = (char*)d_ws;
  // ---- static region [0, 24MB) ----
  bf16*  cs   = (bf16*)(ws);                    // 8 MB token-major cos/sin
  bf16*  csT  = (bf16*)(ws + 8 * MB);           // 8 MB [128][2][16384]
  float* pvec = (float*)(ws + 16 * MB);         // 64 KB
  long wo = 16 * MB + 65536;
  bf16* WcT   = (bf16*)(ws + wo);               wo += 262144;
  bf16* WkvT  = (bf16*)(ws + wo);               wo += 1048576;
  bf16* WocaT = (bf16*)(ws + wo);               wo += 524288;
  bf16* Wf1T  = (bf16*)(ws + wo);               wo += 131072;
  bf16* Wf2T  = (bf16*)(ws + wo);               wo += 131072;
  bf16* P1T   = (bf16*)(ws + wo);               wo += 131072;
  bf16* P2T   = (bf16*)(ws + wo);               wo += 131072;
  bf16* P3T   = (bf16*)(ws + wo);               wo += 131072;
  bf16* WqkvT = (bf16*)(ws + wo);               wo += 393216;
  bf16* WodaT = (bf16*)(ws + wo);               wo += 131072;
  bf16* D1T   = (bf16*)(ws + wo);               wo += 131072;
  bf16* D2T   = (bf16*)(ws + wo);               wo += 65536;
  float* P1L  = (float*)(ws + wo);              wo += 1024;
  float* muB  = (float*)(ws + wo);              wo += 32 * 2048 * 4;  // mu [32][2048]
  float* rsB  = (float*)(ws + wo);              wo += 32 * 2048 * 4;  // rs
  // ---- dynamic arena at 24 MB (lifetime-audited, W=writer step R=last read) ----
  char* AR = ws + 24 * MB;
  bf16*  xb     = (bf16*)(AR);             // [0,8)   W3  -> R9
  bf16*  zb     = (bf16*)(AR + 8 * MB);    // [8,16)  W2  -> R4
  bf16*  gf     = (bf16*)(AR + 48 * MB);   // [48,64) W2  -> R3 (Vt overwrites after)
  bf16*  Kt     = (bf16*)(AR + 16 * MB);   // [16,48) W4/5 -> R6
  bf16*  Vt     = (bf16*)(AR + 48 * MB);   // [48,80) W4  -> R6
  bf16*  dotsT  = (bf16*)(AR + 8 * MB);    // [8,12)  W6  -> R8
  bf16*  qrot   = (bf16*)(AR + 16 * MB);   // [16,24) W7  -> R8
  bf16*  merged = (bf16*)(AR + 24 * MB);   // [24,56) W8  -> R9
  float* x2     = (float*)(AR + 56 * MB);  // [56,72) W9  -> R11 (f32)
  bf16*  x2b    = (bf16*)(AR + 72 * MB);   // [72,80) W9  -> R10
  bf16*  t1     = (bf16*)(AR + 8 * MB);    // [8,16)  W10 -> R11
  float* x3     = (float*)(AR + 16 * MB);  // [16,32) W11 -> R15 (f32)
  bf16*  h      = (bf16*)(AR + 32 * MB);   // [32,40) W12 -> R13
  bf16*  p1o    = (bf16*)(AR + 40 * MB);   // [40,48) W13 -> R14
  bf16*  p2o    = (bf16*)(AR + 48 * MB);   // [48,56) W14 -> R15
  bf16*  zpb    = (bf16*)(AR + 56 * MB);   // [56,64) W15 -> R17
  bf16*  q2b    = (bf16*)(AR + 64 * MB);   // [64,72) W16/18 -> R21
  bf16*  k2t    = (bf16*)(AR + 72 * MB);   // [72,80) W17/19 -> R20
  bf16*  v2t    = (bf16*)(AR + 8 * MB);    // [8,16)  W17 -> R20
  bf16*  dots2T = (bf16*)(AR + 16 * MB);   // [16,17) W20 -> R21
  bf16*  att    = (bf16*)(AR + 24 * MB);   // [24,32) W21 -> R22
  float* zd     = (float*)(AR + 32 * MB);  // [32,48) W22 -> R23 (f32)
  bf16*  h2     = (bf16*)(AR + 8 * MB);    // [8,16)  W23 -> R24
  bf16*  g1     = (bf16*)(AR + 16 * MB);   // [16,24) W24 -> R25
  bf16*  g2     = (bf16*)(AR + 24 * MB);   // [24,28) W25 -> R26

  // ---- weight-prep table ----
  WTab tab;
  int nb = 0;
  auto add = [&](int i, const float* s, bf16* d, int K_, int N_) {
    tab.e[i].s = s; tab.e[i].d = d; tab.e[i].K = K_; tab.e[i].N = N_;
    tab.e[i].blk0 = nb; nb += (K_ * N_) / 256;
  };
  add(0, Wc, WcT, 512, 256);
  add(1, Wkv, WkvT, 256, 2048);
  add(2, Woca, WocaT, 1024, 256);
  add(3, Wf1, Wf1T, 256, 256);
  add(4, Wf2, Wf2T, 256, 256);
  add(5, P1, P1T, 256, 256);
  add(6, P2, P2T, 256, 256);
  add(7, P3, P3T, 256, 256);
  add(8, Wqkv, WqkvT, 256, 768);
  add(9, Woda, WodaT, 256, 256);
  add(10, D1, D1T, 256, 256);
  add(11, D2, D2T, 256, 128);
  k_wprep<<<nb, 256, 0, stream>>>(tab);

  k_pre<<<NTOK / 4, 256, 0, stream>>>(pos, Bf, z, P1, gf, cs, pvec, zb, P1L);
  k_csT<<<dim3(NTOK / 256, 128), 256, 0, stream>>>(pos, csT);
  // x = gelu(fourier) @ WcT
  k_gemm<512, E_BF16><<<dim3(4, 128, 1), 256, 0, stream>>>(
      gf, 512, WcT, 0, 0, 0, nullptr, nullptr, nullptr, nullptr, nullptr, nullptr, xb, 256);
  // Kt/Vt = (z @ Wkv) transposed per (b,h)
  k_gemmT<256><<<dim3(32, 128), 256, 0, stream>>>(zb, 256, WkvT, Kt, Vt, 1024, 4);
  k_stats<<<dim3(8, 32), 256, 0, stream>>>(Kt, muB, rsB);
  k_rotnorm<<<dim3(128, 32), 256, 0, stream>>>(Kt, muB, rsB, csT, 2);
  // dotsT[mat] = Vt[mat] * Kt[mat]^T / n
  k_atb2<4><<<dim3(4, 2, 32), 256, 0, stream>>>(Vt, Kt, dotsT, 1.f / 2048.f);
  k_rotq<<<NTOK / 4, 256, 0, stream>>>(xb, qrot, cs);
  // merged[:, h*256:] = qrot @ dotsT[b,h]
  k_gemm<256, E_BF16><<<dim3(4, 128, 4), 256, 0, stream>>>(
      qrot, 256, dotsT, 262144L, 65536L, 256, nullptr, nullptr, nullptr, nullptr, nullptr,
      nullptr, merged, 1024);
  // x2 = merged @ WocaT + boca + x
  k_gemm<1024, E_BIAS_RESB_BOTH><<<dim3(4, 128, 1), 256, 0, stream>>>(
      merged, 1024, WocaT, 0, 0, 0, boca, nullptr, xb, nullptr, nullptr, x2, x2b, 256);
  // t1 = gelu(x2 @ Wf1 + bf1)
  k_gemm<256, E_BIAS_GELU><<<dim3(4, 128, 1), 256, 0, stream>>>(
      x2b, 256, Wf1T, 0, 0, 0, bf1, nullptr, nullptr, nullptr, nullptr, nullptr, t1, 256);
  // x3 = t1 @ Wf2 + bf2 + x2
  k_gemm<256, E_BIAS_RES_F32><<<dim3(4, 128, 1), 256, 0, stream>>>(
      t1, 256, Wf2T, 0, 0, 0, bf2, x2, nullptr, nullptr, nullptr, x3, nullptr, 256);
  k_ln<<<NTOK / 4, 256, 0, stream>>>(x3, lng, lnb, h);
  // p1o = gelu(h @ P1T + pvec*P1L)
  k_gemm<256, E_RANK1_GELU><<<dim3(4, 128, 1), 256, 0, stream>>>(
      h, 256, P1T, 0, 0, 0, nullptr, nullptr, nullptr, P1L, pvec, nullptr, p1o, 256);
  k_gemm<256, E_GELU><<<dim3(4, 128, 1), 256, 0, stream>>>(
      p1o, 256, P2T, 0, 0, 0, nullptr, nullptr, nullptr, nullptr, nullptr, nullptr, p2o, 256);
  // zp = p2o @ P3T + x3
  k_gemm<256, E_RES_BOTH><<<dim3(4, 128, 1), 256, 0, stream>>>(
      p2o, 256, P3T, 0, 0, 0, nullptr, x3, nullptr, nullptr, nullptr, zp, zpb, 256);
  // q2 token-major; k2/v2 transposed
  k_gemm<256, E_BF16><<<dim3(4, 128, 1), 256, 0, stream>>>(
      zpb, 256, WqkvT, 0, 0, 0, nullptr, nullptr, nullptr, nullptr, nullptr, nullptr, q2b, 256);
  k_gemmT<256><<<dim3(8, 128), 256, 0, stream>>>(zpb, 256, WqkvT + 65536, k2t, v2t, 256, 1);
  k_rotq<<<NTOK / 4, 256, 0, stream>>>(q2b, q2b, cs);
  k_stats<<<dim3(8, 8), 256, 0, stream>>>(k2t, muB, rsB);
  k_rotnorm<<<dim3(128, 8), 256, 0, stream>>>(k2t, muB, rsB, csT, 0);
  k_atb2<2><<<dim3(4, 4, 8), 256, 0, stream>>>(v2t, k2t, dots2T, 1.f / 2048.f);
  // att = q2' @ dots2T[b]
  k_gemm<256, E_BF16><<<dim3(4, 128, 1), 256, 0, stream>>>(
      q2b, 256, dots2T, 65536L, 0, 0, nullptr, nullptr, nullptr, nullptr, nullptr,
      nullptr, att, 256);
  // zd = att @ WodaT + boda + zp
  k_gemm<256, E_BIAS_RES_F32><<<dim3(4, 128, 1), 256, 0, stream>>>(
      att, 256, WodaT, 0, 0, 0, boda, zp, nullptr, nullptr, nullptr, zd, nullptr, 256);
  k_ln<<<NTOK / 4, 256, 0, stream>>>(zd, ln2g, ln2b, h2);
  k_gemm<256, E_GELU><<<dim3(4, 128, 1), 256, 0, stream>>>(
      h2, 256, D1T, 0, 0, 0, nullptr, nullptr, nullptr, nullptr, nullptr, nullptr, g1, 256);
  k_gemm<256, E_GELU><<<dim3(2, 128, 1), 256, 0, stream>>>(
      g1, 256, D2T, 0, 0, 0, nullptr, nullptr, nullptr, nullptr, nullptr, nullptr, g2, 128);
  k_final<<<NTOK / 4, 256, 0, stream>>>(g2, D3, b3, u);
}

// Round 10
// 424.935 us; speedup vs baseline: 3.7627x; 1.0940x over previous
//
#include <hip/hip_runtime.h>
#include <hip/hip_bf16.h>

using bf16 = __hip_bfloat16;
typedef __attribute__((ext_vector_type(8))) short short8;
typedef __attribute__((ext_vector_type(4))) short short4v;
typedef __attribute__((ext_vector_type(4))) float f32x4;

constexpr int BB = 8;
constexpr int NN = 2048;
constexpr int CC = 256;
constexpr int NTOK = BB * NN;  // 16384
constexpr float TWO_PI = 6.283185307179586f;
constexpr float LOG2_1E4 = 13.287712379549449f;

__device__ __forceinline__ float gelu_f(float x) {
  return 0.5f * x * (1.0f + erff(x * 0.7071067811865475f));
}
__device__ __forceinline__ float us2f(unsigned short u) {
  return __uint_as_float(((unsigned)u) << 16);
}

template <int T>
__device__ __forceinline__ void stats_rows(const float (*buf)[CC], float* mu, float* rs, float eps) {
  __syncthreads();
  int w = threadIdx.x >> 6, l = threadIdx.x & 63;
  if (w < T) {
    float s = 0.f, s2 = 0.f;
#pragma unroll
    for (int j = 0; j < 4; ++j) { float v = buf[w][l + 64 * j]; s += v; s2 += v * v; }
#pragma unroll
    for (int o = 32; o; o >>= 1) { s += __shfl_down(s, o); s2 += __shfl_down(s2, o); }
    if (l == 0) {
      float m = s * (1.f / 256.f);
      float var = fmaxf(s2 * (1.f / 256.f) - m * m, 0.f);
      mu[w] = m; rs[w] = rsqrtf(var + eps);
    }
  }
  __syncthreads();
}

// ---------------- shared MFMA GEMM core (2-phase dbuf, XOR-swizzled) --------
#define GLD16(src, dst)                                                       \
  __builtin_amdgcn_global_load_lds(                                           \
      (const __attribute__((address_space(1))) void*)(src),                   \
      (__attribute__((address_space(3))) void*)(dst), 16, 0, 0)

template <int K, int MI>
__device__ __forceinline__ void gemm_core(
    const bf16* __restrict__ Ap, int lda, const bf16* __restrict__ Bp,
    bf16 (&As)[2][MI * 32 * 64], bf16 (&Bs)[2][64 * 64], f32x4 (&acc)[MI][2]) {
  const int tid = threadIdx.x;
  const int w = tid >> 6, l = tid & 63;
  const int srow = l >> 3;
  const int scol = ((l & 7) ^ srow) * 8;  // swizzled source col
  const int rsw = (l & 7) * 8;            // read-side XOR (row&7 == l&7)
  const int wm = w >> 1, wn = w & 1;

  auto stage_tile = [&](int buf, int kt) {
#pragma unroll
    for (int i = 0; i < MI; ++i) {
      int r = (w * MI + i) * 8 + srow;
      GLD16(Ap + (long)r * lda + kt + scol, &As[buf][(w * MI + i) * 512 + l * 8]);
    }
#pragma unroll
    for (int i = 0; i < 2; ++i) {
      int r = (w * 2 + i) * 8 + srow;
      GLD16(Bp + (long)r * K + kt + scol, &Bs[buf][(w * 2 + i) * 512 + l * 8]);
    }
  };

  stage_tile(0, 0);
  asm volatile("s_waitcnt vmcnt(0)" ::: "memory");
  __builtin_amdgcn_s_barrier();

  int cur = 0;
  for (int kt = 0; kt < K; kt += 64) {
    const bool more = (kt + 64 < K);
    if (more) stage_tile(cur ^ 1, kt + 64);
    short8 bfr[2][2];
#pragma unroll
    for (int ni = 0; ni < 2; ++ni)
#pragma unroll
      for (int ks = 0; ks < 2; ++ks)
        bfr[ni][ks] = *(const short8*)&Bs[cur][(wn * 32 + ni * 16 + (l & 15)) * 64 +
                                               ((ks * 32 + (l >> 4) * 8) ^ rsw)];
#pragma unroll
    for (int mi = 0; mi < MI; ++mi) {
#pragma unroll
      for (int ks = 0; ks < 2; ++ks) {
        short8 afr = *(const short8*)&As[cur][(wm * (MI * 16) + mi * 16 + (l & 15)) * 64 +
                                              ((ks * 32 + (l >> 4) * 8) ^ rsw)];
#pragma unroll
        for (int ni = 0; ni < 2; ++ni)
          acc[mi][ni] = __builtin_amdgcn_mfma_f32_16x16x32_bf16(afr, bfr[ni][ks], acc[mi][ni], 0, 0, 0);
      }
    }
    if (more) asm volatile("s_waitcnt vmcnt(0)" ::: "memory");
    __builtin_amdgcn_s_barrier();
    cur ^= 1;
  }
}

// ---------------- k_gemm with fused epilogues (BM=128, BN=64) ---------------
enum { E_BF16 = 0, E_BIAS_RESB_BOTH, E_BIAS_GELU, E_BIAS_RES_F32,
       E_RANK1_GELU, E_GELU, E_RES_BOTH };

template <int K, int EPI>
__global__ void __launch_bounds__(256) k_gemm(
    const bf16* __restrict__ A, int lda, const bf16* __restrict__ Bt,
    long bstride, long zstride, int nOffZ,
    const float* __restrict__ bias, const float* __restrict__ res,
    const bf16* __restrict__ resB, const float* __restrict__ rank1,
    const float* __restrict__ pvec,
    float* __restrict__ outF, bf16* __restrict__ outB, int ldo) {
  __shared__ bf16 As[2][128 * 64];
  __shared__ bf16 Bs[2][64 * 64];
  const int tid = threadIdx.x;
  const int w = tid >> 6, l = tid & 63;
  const int m0 = blockIdx.y * 128, n0 = blockIdx.x * 64;
  const int bidx = m0 >> 11;
  const bf16* Bp = Bt + (long)bidx * bstride + (long)blockIdx.z * zstride + (long)n0 * K;
  f32x4 acc[4][2] = {};
  gemm_core<K, 4>(A + (long)m0 * lda, lda, Bp, As, Bs, acc);
  const int wm = w >> 1, wn = w & 1;
  const int zoff = blockIdx.z * nOffZ;
#pragma unroll
  for (int mi = 0; mi < 4; ++mi) {
#pragma unroll
    for (int ni = 0; ni < 2; ++ni) {
      const int bcol = n0 + wn * 32 + ni * 16 + (l & 15);
      const int ocol = bcol + zoff;
#pragma unroll
      for (int r = 0; r < 4; ++r) {
        const int row = m0 + wm * 64 + mi * 16 + (l >> 4) * 4 + r;
        float v = acc[mi][ni][r];
        const long oidx = (long)row * ldo + ocol;
        if constexpr (EPI == E_BF16) { outB[oidx] = __float2bfloat16(v); }
        else if constexpr (EPI == E_BIAS_RESB_BOTH) {
          v += bias[bcol] + __bfloat162float(resB[oidx]);
          outF[oidx] = v; outB[oidx] = __float2bfloat16(v);
        } else if constexpr (EPI == E_BIAS_GELU) {
          v = gelu_f(v + bias[bcol]); outB[oidx] = __float2bfloat16(v);
        } else if constexpr (EPI == E_BIAS_RES_F32) {
          v += bias[bcol] + res[oidx]; outF[oidx] = v;
        } else if constexpr (EPI == E_RANK1_GELU) {
          v = gelu_f(v + pvec[row] * rank1[bcol]); outB[oidx] = __float2bfloat16(v);
        } else if constexpr (EPI == E_GELU) {
          v = gelu_f(v); outB[oidx] = __float2bfloat16(v);
        } else {  // E_RES_BOTH
          v += res[oidx]; outF[oidx] = v; outB[oidx] = __float2bfloat16(v);
        }
      }
    }
  }
}

// ---------------- k_gemmT: GEMM with TRANSPOSED per-matrix output ----------
template <int K>
__global__ void __launch_bounds__(256) k_gemmT(
    const bf16* __restrict__ A, int lda, const bf16* __restrict__ Bt,
    bf16* __restrict__ T0, bf16* __restrict__ T1, int thresh, int matsPerB) {
  __shared__ union {
    struct { bf16 A[2][128 * 64]; bf16 B[2][64 * 64]; } ab;
    bf16 stage[64 * 132];  // stride 132: u32-packed writes conflict-free
  } sm;
  const int tid = threadIdx.x;
  const int w = tid >> 6, l = tid & 63;
  const int m0 = blockIdx.y * 128, n0 = blockIdx.x * 64;
  f32x4 acc[4][2] = {};
  gemm_core<K, 4>(A + (long)m0 * lda, lda, Bt + (long)n0 * K, sm.ab.A, sm.ab.B, acc);
  const int wm = w >> 1, wn = w & 1;
  // stage acc tile transposed into LDS (packed u32 writes)
#pragma unroll
  for (int mi = 0; mi < 4; ++mi)
#pragma unroll
    for (int ni = 0; ni < 2; ++ni) {
      int c = wn * 32 + ni * 16 + (l & 15);
      int row0 = wm * 64 + mi * 16 + (l >> 4) * 4;
#pragma unroll
      for (int q = 0; q < 2; ++q) {
        bf16 b0 = __float2bfloat16(acc[mi][ni][2 * q]);
        bf16 b1 = __float2bfloat16(acc[mi][ni][2 * q + 1]);
        unsigned u = (unsigned)*(unsigned short*)&b0 |
                     ((unsigned)*(unsigned short*)&b1 << 16);
        *(unsigned*)&sm.stage[c * 132 + row0 + 2 * q] = u;
      }
    }
  __syncthreads();
  const int b = m0 >> 11, nbase = m0 & 2047;
  const int part = (n0 >= thresh) ? 1 : 0;
  const int cT0 = n0 - (part ? thresh : 0);
  bf16* dst = (part ? T1 : T0) + ((long)(b * matsPerB + (cT0 >> 8))) * 524288
            + (long)(cT0 & 255) * 2048;
  const int c = tid >> 2, ns = tid & 3;
  bf16* rowp = dst + (long)c * 2048 + nbase + ns * 32;
#pragma unroll
  for (int j = 0; j < 4; ++j) {
    short4v lo = *(const short4v*)&sm.stage[c * 132 + ns * 32 + j * 8];
    short4v hi = *(const short4v*)&sm.stage[c * 132 + ns * 32 + j * 8 + 4];
    short8 v;
    v[0] = lo[0]; v[1] = lo[1]; v[2] = lo[2]; v[3] = lo[3];
    v[4] = hi[0]; v[5] = hi[1]; v[6] = hi[2]; v[7] = hi[3];
    *(short8*)&rowp[j * 8] = v;
  }
}

// ---------------- k_atb2: D[mat] = A[mat] * B[mat]^T (both [256][2048]) -----
template <int MI>
__global__ void __launch_bounds__(256) k_atb2(
    const bf16* __restrict__ A0, const bf16* __restrict__ B0,
    bf16* __restrict__ D0, float scale) {
  __shared__ bf16 As[2][MI * 32 * 64];
  __shared__ bf16 Bs[2][64 * 64];
  const int tid = threadIdx.x;
  const int w = tid >> 6, l = tid & 63;
  const int mat = blockIdx.z;
  const int m0 = blockIdx.y * (MI * 32), n0 = blockIdx.x * 64;
  const bf16* Ap = A0 + (long)mat * 524288 + (long)m0 * 2048;
  const bf16* Bp = B0 + (long)mat * 524288 + (long)n0 * 2048;
  f32x4 acc[MI][2] = {};
  gemm_core<2048, MI>(Ap, 2048, Bp, As, Bs, acc);
  bf16* D = D0 + (long)mat * 65536;
  const int wm = w >> 1, wn = w & 1;
#pragma unroll
  for (int mi = 0; mi < MI; ++mi)
#pragma unroll
    for (int ni = 0; ni < 2; ++ni) {
      int col = n0 + wn * 32 + ni * 16 + (l & 15);
#pragma unroll
      for (int r = 0; r < 4; ++r) {
        int row = m0 + wm * (MI * 16) + mi * 16 + (l >> 4) * 4 + r;
        D[(long)row * 256 + col] = __float2bfloat16(acc[mi][ni][r] * scale);
      }
    }
}

// ---------------- k_normrot: FUSED stats + norm + rotary on Kt[mat] ---------
// Replaces k_stats (full 32MB re-read) + k_rotnorm. One block owns a
// (64-token, mat) column slab: load once to LDS, stats, norm+rot, write back.
__global__ void __launch_bounds__(256) k_normrot(
    bf16* __restrict__ Kt, const bf16* __restrict__ csT, int hshift) {
  __shared__ bf16 tile[256][68];
  __shared__ float ps[4][64], ps2[4][64];
  __shared__ float smu[64], srs[64];
  const int mat = blockIdx.y;
  const int tok0 = blockIdx.x * 64;
  const int b = mat >> hshift;
  const int tid = threadIdx.x;
  bf16* base = Kt + (long)mat * 524288 + tok0;
  const int cr = tid >> 3;          // 0..31
  const int cj = (tid & 7) * 8;     // token offset 0..56
#pragma unroll
  for (int g = 0; g < 8; ++g) {
    int c = g * 32 + cr;
    *(short8*)&tile[c][cj] = *(const short8*)&base[(long)c * 2048 + cj];
  }
  __syncthreads();
  {
    const int tk = tid & 63, q = tid >> 6;
    float s = 0.f, s2 = 0.f;
#pragma unroll 8
    for (int cc = 0; cc < 64; ++cc) {
      float v = us2f(*(const unsigned short*)&tile[q * 64 + cc][tk]);
      s += v; s2 += v * v;
    }
    ps[q][tk] = s; ps2[q][tk] = s2;
  }
  __syncthreads();
  if (tid < 64) {
    float s = ps[0][tid] + ps[1][tid] + ps[2][tid] + ps[3][tid];
    float s2 = ps2[0][tid] + ps2[1][tid] + ps2[2][tid] + ps2[3][tid];
    float m = s * (1.f / 256.f);
    smu[tid] = m;
    srs[tid] = rsqrtf(fmaxf(s2 * (1.f / 256.f) - m * m, 0.f) + 1e-5f);
  }
  __syncthreads();
  const long ctok = (long)b * 2048 + tok0 + cj;
#pragma unroll
  for (int g = 0; g < 4; ++g) {
    int c = g * 32 + cr;
    short8 v0 = *(const short8*)&tile[c][cj];
    short8 v1 = *(const short8*)&tile[c + 128][cj];
    const bf16* cop = csT + (long)(c * 2) * 16384 + ctok;
    short8 co8 = *(const short8*)cop;
    short8 si8 = *(const short8*)(cop + 16384);
    short8 o0, o1;
#pragma unroll
    for (int e = 0; e < 8; ++e) {
      float m = smu[cj + e], r = srs[cj + e];
      float a = (us2f((unsigned short)v0[e]) - m) * r;
      float bb = (us2f((unsigned short)v1[e]) - m) * r;
      float co = us2f((unsigned short)co8[e]);
      float si = us2f((unsigned short)si8[e]);
      bf16 t0 = __float2bfloat16(a * co - bb * si);
      bf16 t1 = __float2bfloat16(bb * co + a * si);
      o0[e] = *(short*)&t0; o1[e] = *(short*)&t1;
    }
    *(short8*)&base[(long)c * 2048 + cj] = o0;
    *(short8*)&base[(long)(c + 128) * 2048 + cj] = o1;
  }
}

// token-major instnorm + rotary (4 tokens/block); in may equal out
__global__ void __launch_bounds__(256) k_rotq(
    const bf16* __restrict__ in, bf16* __restrict__ out, const bf16* __restrict__ cs) {
  __shared__ float xr[4][CC];
  __shared__ float mu[4], rs[4];
  int tid = threadIdx.x;
  long tok0 = (long)blockIdx.x * 4;
#pragma unroll
  for (int t = 0; t < 4; ++t) xr[t][tid] = __bfloat162float(in[(tok0 + t) * 256 + tid]);
  stats_rows<4>(xr, mu, rs, 1e-5f);
  int i = tid & 127;
#pragma unroll
  for (int t = 0; t < 4; ++t) {
    float co = __bfloat162float(cs[(tok0 + t) * 256 + i]);
    float si = __bfloat162float(cs[(tok0 + t) * 256 + 128 + i]);
    float n0 = (xr[t][tid] - mu[t]) * rs[t];
    float n1 = (xr[t][tid ^ 128] - mu[t]) * rs[t];
    float o = (tid < 128) ? (n0 * co - n1 * si) : (n0 * co + n1 * si);
    out[(tok0 + t) * 256 + tid] = __float2bfloat16(o);
  }
}

// ---------------- weight prep: 12 transposes, one kernel --------------------
struct WEnt { const float* s; bf16* d; int K; int N; int blk0; };
struct WTab { WEnt e[12]; };

__global__ void __launch_bounds__(256) k_wprep(WTab t) {
  int bid = blockIdx.x;
  int ei = 0;
#pragma unroll
  for (int i = 1; i < 12; ++i)
    if (bid >= t.e[i].blk0) ei = i;
  WEnt e = t.e[ei];
  int local = (bid - e.blk0) * 256 + threadIdx.x;
  if (local < e.K * e.N) {
    int n = local / e.K, k = local - n * e.K;
    e.d[local] = __float2bfloat16(e.s[(long)k * e.N + n]);
  }
}

// ---------------- k_csT: transposed cos/sin table, coalesced writes ---------
__global__ void __launch_bounds__(256) k_csT(
    const float* __restrict__ pos, bf16* __restrict__ csT) {
  const int c = blockIdx.y;
  const int n = blockIdx.x * 256 + threadIdx.x;
  float inv = exp2f(-((float)c * (1.f / 128.f)) * LOG2_1E4);
  float fh = pos[n] * 2048.f * inv;
  float s, co; sincosf(fh, &s, &co);
  csT[(long)(c * 2) * 16384 + n] = __float2bfloat16(co);
  csT[(long)(c * 2 + 1) * 16384 + n] = __float2bfloat16(s);
}

// ---------------- k_pre: fourier feats, token-major cos/sin, pvec, z->bf16 --
__global__ void __launch_bounds__(256) k_pre(
    const float* __restrict__ pos, const float* __restrict__ Bf,
    const float* __restrict__ z, const float* __restrict__ P1,
    bf16* __restrict__ gf, bf16* __restrict__ cs,
    float* __restrict__ pvec, bf16* __restrict__ zb, float* __restrict__ P1L) {
  int tid = threadIdx.x;
  long tok0 = (long)blockIdx.x * 4;
  if (blockIdx.x == 0) P1L[tid] = P1[65536 + tid];
  float p[4];
#pragma unroll
  for (int t = 0; t < 4; ++t) p[t] = pos[tok0 + t];
  if (tid < 4) pvec[tok0 + tid] = p[tid] * 0.0625f;
  float bfc = Bf[tid];
#pragma unroll
  for (int t = 0; t < 4; ++t) {
    float xp = TWO_PI * (p[t] * 0.0625f) * bfc;
    float s, c; sincosf(xp, &s, &c);
    gf[(tok0 + t) * 512 + tid] = __float2bfloat16(gelu_f(s));
    gf[(tok0 + t) * 512 + 256 + tid] = __float2bfloat16(gelu_f(c));
    zb[(tok0 + t) * 256 + tid] = __float2bfloat16(z[(tok0 + t) * 256 + tid]);
  }
  if (tid < 128) {
    float inv = exp2f(-((float)tid * (1.f / 128.f)) * LOG2_1E4);
#pragma unroll
    for (int t = 0; t < 4; ++t) {
      float fh = p[t] * 2048.f * inv;
      float s, c; sincosf(fh, &s, &c);
      cs[(tok0 + t) * 256 + tid] = __float2bfloat16(c);
      cs[(tok0 + t) * 256 + 128 + tid] = __float2bfloat16(s);
    }
  }
}

__global__ void __launch_bounds__(256) k_ln(
    const float* __restrict__ xin, const float* __restrict__ g,
    const float* __restrict__ b, bf16* __restrict__ hout) {
  __shared__ float xr[4][CC];
  __shared__ float mu[4], rs[4];
  int tid = threadIdx.x;
  long tok0 = (long)blockIdx.x * 4;
#pragma unroll
  for (int t = 0; t < 4; ++t) xr[t][tid] = xin[(tok0 + t) * 256 + tid];
  stats_rows<4>(xr, mu, rs, 1e-5f);
  float gv = g[tid], bv = b[tid];
#pragma unroll
  for (int t = 0; t < 4; ++t)
    hout[(tok0 + t) * 256 + tid] = __float2bfloat16((xr[t][tid] - mu[t]) * rs[t] * gv + bv);
}

__global__ void __launch_bounds__(256) k_final(
    const bf16* __restrict__ g2, const float* __restrict__ D3,
    const float* __restrict__ b3, float* __restrict__ u) {
  int w = threadIdx.x >> 6, l = threadIdx.x & 63;
  long tok = (long)blockIdx.x * 4 + w;
  float s = __bfloat162float(g2[tok * 128 + l]) * D3[l]
          + __bfloat162float(g2[tok * 128 + 64 + l]) * D3[64 + l];
#pragma unroll
  for (int o = 32; o; o >>= 1) s += __shfl_down(s, o);
  if (l == 0) u[tok] = s + b3[0];
}

// ======================= launcher ===========================================
extern "C" void kernel_launch(void* const* d_in, const int* in_sizes, int n_in,
                              void* d_out, int out_size, void* d_ws, size_t ws_size,
                              hipStream_t stream) {
  const float* z    = (const float*)d_in[0];
  const float* pos  = (const float*)d_in[1];
  const float* Bf   = (const float*)d_in[2];
  const float* Wc   = (const float*)d_in[3];
  const float* Wkv  = (const float*)d_in[4];
  const float* Woca = (const float*)d_in[5];
  const float* boca = (const float*)d_in[6];
  const float* Wf1  = (const float*)d_in[7];
  const float* bf1  = (const float*)d_in[8];
  const float* Wf2  = (const float*)d_in[9];
  const float* bf2  = (const float*)d_in[10];
  const float* lng  = (const float*)d_in[11];
  const float* lnb  = (const float*)d_in[12];
  const float* P1   = (const float*)d_in[13];
  const float* P2   = (const float*)d_in[14];
  const float* P3   = (const float*)d_in[15];
  const float* Wqkv = (const float*)d_in[16];
  const float* Woda = (const float*)d_in[17];
  const float* boda = (const float*)d_in[18];
  const float* ln2g = (const float*)d_in[19];
  const float* ln2b = (const float*)d_in[20];
  const float* D1   = (const float*)d_in[21];
  const float* D2   = (const float*)d_in[22];
  const float* D3   = (const float*)d_in[23];
  const float* b3   = (const float*)d_in[24];

  float* u  = (float*)d_out;
  float* zp = (float*)d_out + NTOK;

  const long MB = 1048576L;
  char* ws = (char*)d_ws;
  // ---- static region [0, 24MB) ----
  bf16*  cs   = (bf16*)(ws);                    // 8 MB token-major cos/sin
  bf16*  csT  = (bf16*)(ws + 8 * MB);           // 8 MB [128][2][16384]
  float* pvec = (float*)(ws + 16 * MB);         // 64 KB
  long wo = 16 * MB + 65536;
  bf16* WcT   = (bf16*)(ws + wo);               wo += 262144;
  bf16* WkvT  = (bf16*)(ws + wo);               wo += 1048576;
  bf16* WocaT = (bf16*)(ws + wo);               wo += 524288;
  bf16* Wf1T  = (bf16*)(ws + wo);               wo += 131072;
  bf16* Wf2T  = (bf16*)(ws + wo);               wo += 131072;
  bf16* P1T   = (bf16*)(ws + wo);               wo += 131072;
  bf16* P2T   = (bf16*)(ws + wo);               wo += 131072;
  bf16* P3T   = (bf16*)(ws + wo);               wo += 131072;
  bf16* WqkvT = (bf16*)(ws + wo);               wo += 393216;
  bf16* WodaT = (bf16*)(ws + wo);               wo += 131072;
  bf16* D1T   = (bf16*)(ws + wo);               wo += 131072;
  bf16* D2T   = (bf16*)(ws + wo);               wo += 65536;
  float* P1L  = (float*)(ws + wo);              wo += 1024;
  // ---- dynamic arena at 24 MB (round-7 layout; all overlaps are across
  //      sequential launches — no within-launch read/write overlap) ----
  char* AR = ws + 24 * MB;
  bf16*  xb     = (bf16*)(AR);             // [0,8)   W4  -> R10
  bf16*  zb     = (bf16*)(AR + 8 * MB);    // [8,16)  W2  -> R5
  bf16*  gf     = (bf16*)(AR + 48 * MB);   // [48,64) W2  -> R4 (Vt W5 after)
  bf16*  Kt     = (bf16*)(AR + 16 * MB);   // [16,48) W5/6 -> R7
  bf16*  Vt     = (bf16*)(AR + 48 * MB);   // [48,80) W5  -> R7
  bf16*  dotsT  = (bf16*)(AR + 8 * MB);    // [8,12)  W7  -> R9
  bf16*  qrot   = (bf16*)(AR + 16 * MB);   // [16,24) W8  -> R9
  bf16*  merged = (bf16*)(AR + 24 * MB);   // [24,56) W9  -> R10
  float* x2     = (float*)(AR + 56 * MB);  // [56,72) W10 -> R12 (f32)
  bf16*  x2b    = (bf16*)(AR + 72 * MB);   // [72,80) W10 -> R11
  bf16*  t1     = (bf16*)(AR + 8 * MB);    // [8,16)  W11 -> R12
  float* x3     = (float*)(AR + 16 * MB);  // [16,32) W12 -> R16 (f32)
  bf16*  h      = (bf16*)(AR + 32 * MB);   // [32,40) W13 -> R14
  bf16*  p1o    = (bf16*)(AR + 40 * MB);   // [40,48) W14 -> R15
  bf16*  p2o    = (bf16*)(AR + 48 * MB);   // [48,56) W15 -> R16
  bf16*  zpb    = (bf16*)(AR + 56 * MB);   // [56,64) W16 -> R18
  bf16*  q2b    = (bf16*)(AR + 64 * MB);   // [64,72) W17/19 -> R22
  bf16*  k2t    = (bf16*)(AR + 72 * MB);   // [72,80) W18/20 -> R21
  bf16*  v2t    = (bf16*)(AR + 8 * MB);    // [8,16)  W18 -> R21
  bf16*  dots2T = (bf16*)(AR + 16 * MB);   // [16,17) W21 -> R22
  bf16*  att    = (bf16*)(AR + 24 * MB);   // [24,32) W22 -> R23
  float* zd     = (float*)(AR + 32 * MB);  // [32,48) W23 -> R24 (f32)
  bf16*  h2     = (bf16*)(AR + 8 * MB);    // [8,16)  W24 -> R25
  bf16*  g1     = (bf16*)(AR + 16 * MB);   // [16,24) W25 -> R26
  bf16*  g2     = (bf16*)(AR + 24 * MB);   // [24,28) W26 -> R27

  // ---- weight-prep table ----
  WTab tab;
  int nb = 0;
  auto add = [&](int i, const float* s, bf16* d, int K_, int N_) {
    tab.e[i].s = s; tab.e[i].d = d; tab.e[i].K = K_; tab.e[i].N = N_;
    tab.e[i].blk0 = nb; nb += (K_ * N_) / 256;
  };
  add(0, Wc, WcT, 512, 256);
  add(1, Wkv, WkvT, 256, 2048);
  add(2, Woca, WocaT, 1024, 256);
  add(3, Wf1, Wf1T, 256, 256);
  add(4, Wf2, Wf2T, 256, 256);
  add(5, P1, P1T, 256, 256);
  add(6, P2, P2T, 256, 256);
  add(7, P3, P3T, 256, 256);
  add(8, Wqkv, WqkvT, 256, 768);
  add(9, Woda, WodaT, 256, 256);
  add(10, D1, D1T, 256, 256);
  add(11, D2, D2T, 256, 128);
  k_wprep<<<nb, 256, 0, stream>>>(tab);

  k_pre<<<NTOK / 4, 256, 0, stream>>>(pos, Bf, z, P1, gf, cs, pvec, zb, P1L);
  k_csT<<<dim3(NTOK / 256, 128), 256, 0, stream>>>(pos, csT);
  // x = gelu(fourier) @ WcT
  k_gemm<512, E_BF16><<<dim3(4, 128, 1), 256, 0, stream>>>(
      gf, 512, WcT, 0, 0, 0, nullptr, nullptr, nullptr, nullptr, nullptr, nullptr, xb, 256);
  // Kt/Vt = (z @ Wkv) transposed per (b,h)
  k_gemmT<256><<<dim3(32, 128), 256, 0, stream>>>(zb, 256, WkvT, Kt, Vt, 1024, 4);
  // fused instnorm stats + norm + rotary on Kt (in place)
  k_normrot<<<dim3(32, 32), 256, 0, stream>>>(Kt, csT, 2);
  // dotsT[mat] = Vt[mat] * Kt[mat]^T / n
  k_atb2<4><<<dim3(4, 2, 32), 256, 0, stream>>>(Vt, Kt, dotsT, 1.f / 2048.f);
  k_rotq<<<NTOK / 4, 256, 0, stream>>>(xb, qrot, cs);
  // merged[:, h*256:] = qrot @ dotsT[b,h]
  k_gemm<256, E_BF16><<<dim3(4, 128, 4), 256, 0, stream>>>(
      qrot, 256, dotsT, 262144L, 65536L, 256, nullptr, nullptr, nullptr, nullptr, nullptr,
      nullptr, merged, 1024);
  // x2 = merged @ WocaT + boca + x
  k_gemm<1024, E_BIAS_RESB_BOTH><<<dim3(4, 128, 1), 256, 0, stream>>>(
      merged, 1024, WocaT, 0, 0, 0, boca, nullptr, xb, nullptr, nullptr, x2, x2b, 256);
  // t1 = gelu(x2 @ Wf1 + bf1)
  k_gemm<256, E_BIAS_GELU><<<dim3(4, 128, 1), 256, 0, stream>>>(
      x2b, 256, Wf1T, 0, 0, 0, bf1, nullptr, nullptr, nullptr, nullptr, nullptr, t1, 256);
  // x3 = t1 @ Wf2 + bf2 + x2
  k_gemm<256, E_BIAS_RES_F32><<<dim3(4, 128, 1), 256, 0, stream>>>(
      t1, 256, Wf2T, 0, 0, 0, bf2, x2, nullptr, nullptr, nullptr, x3, nullptr, 256);
  k_ln<<<NTOK / 4, 256, 0, stream>>>(x3, lng, lnb, h);
  // p1o = gelu(h @ P1T + pvec*P1L)
  k_gemm<256, E_RANK1_GELU><<<dim3(4, 128, 1), 256, 0, stream>>>(
      h, 256, P1T, 0, 0, 0, nullptr, nullptr, nullptr, P1L, pvec, nullptr, p1o, 256);
  k_gemm<256, E_GELU><<<dim3(4, 128, 1), 256, 0, stream>>>(
      p1o, 256, P2T, 0, 0, 0, nullptr, nullptr, nullptr, nullptr, nullptr, nullptr, p2o, 256);
  // zp = p2o @ P3T + x3
  k_gemm<256, E_RES_BOTH><<<dim3(4, 128, 1), 256, 0, stream>>>(
      p2o, 256, P3T, 0, 0, 0, nullptr, x3, nullptr, nullptr, nullptr, zp, zpb, 256);
  // q2 token-major; k2/v2 transposed
  k_gemm<256, E_BF16><<<dim3(4, 128, 1), 256, 0, stream>>>(
      zpb, 256, WqkvT, 0, 0, 0, nullptr, nullptr, nullptr, nullptr, nullptr, nullptr, q2b, 256);
  k_gemmT<256><<<dim3(8, 128), 256, 0, stream>>>(zpb, 256, WqkvT + 65536, k2t, v2t, 256, 1);
  k_rotq<<<NTOK / 4, 256, 0, stream>>>(q2b, q2b, cs);
  k_normrot<<<dim3(32, 8), 256, 0, stream>>>(k2t, csT, 0);
  k_atb2<2><<<dim3(4, 4, 8), 256, 0, stream>>>(v2t, k2t, dots2T, 1.f / 2048.f);
  // att = q2' @ dots2T[b]
  k_gemm<256, E_BF16><<<dim3(4, 128, 1), 256, 0, stream>>>(
      q2b, 256, dots2T, 65536L, 0, 0, nullptr, nullptr, nullptr, nullptr, nullptr,
      nullptr, att, 256);
  // zd = att @ WodaT + boda + zp
  k_gemm<256, E_BIAS_RES_F32><<<dim3(4, 128, 1), 256, 0, stream>>>(
      att, 256, WodaT, 0, 0, 0, boda, zp, nullptr, nullptr, nullptr, zd, nullptr, 256);
  k_ln<<<NTOK / 4, 256, 0, stream>>>(zd, ln2g, ln2b, h2);
  k_gemm<256, E_GELU><<<dim3(4, 128, 1), 256, 0, stream>>>(
      h2, 256, D1T, 0, 0, 0, nullptr, nullptr, nullptr, nullptr, nullptr, nullptr, g1, 256);
  k_gemm<256, E_GELU><<<dim3(2, 128, 1), 256, 0, stream>>>(
      g1, 256, D2T, 0, 0, 0, nullptr, nullptr, nullptr, nullptr, nullptr, nullptr, g2, 128);
  k_final<<<NTOK / 4, 256, 0, stream>>>(g2, D3, b3, u);
}